// Round 6
// baseline (258.798 us; speedup 1.0000x reference)
//
#include <hip/hip_runtime.h>
#include <math.h>

#define N_   4
#define C_   128
#define H_   128
#define W_   128
#define HW_  16384
#define SCALE_ 0.17677669529663687f   // 32^-0.5

typedef unsigned short u16;
typedef unsigned int   u32;
typedef __bf16 bf16x8 __attribute__((ext_vector_type(8)));
typedef float  f32x4  __attribute__((ext_vector_type(4)));

#define MFMA(a, b, c) __builtin_amdgcn_mfma_f32_16x16x32_bf16((a), (b), (c), 0, 0, 0)

// ---- ws float offsets -------------------------------------------------------
#define QB_OFF   0            // 4,194,304 floats (8,388,608 u16 bf16 q)
#define Y4_OFF   4194304      // 1,048,576 (head4 conv out only)
#define KB_OFF   5242880      //   409,600 floats (819,200 u16 bf16 K)
#define VT_OFF   5652480      //   409,600 floats (819,200 u16 bf16 V^T)
#define PART_OFF 6062080      // 3,145,728
#define WSP_OFF  9207808      //   868,352 floats (2 x 868,352 u16 hi+lo)
#define INH_OFF  10076160     // 4,194,304 floats (8,388,608 u16)
#define INL_OFF  14270464     // 4,194,304 floats
// total 18,464,768 floats = 73.9 MB

// split-weight region offsets (u16 units, within hi or lo half)
#define OQW 0
#define OPW 16384
#define OS1 32768
#define OS2 557056
#define OS3 688128
#define OS4 819200
#define OKV 851968
#define TOTW 868352

#define GS 520   // A-LDS kgroup stride in u16

// ---------------------------------------------------------------------------
__device__ __forceinline__ u16 f2bf_rne(float x) {
  unsigned u = __float_as_uint(x);
  return (u16)((u + 0x7FFFu + ((u >> 16) & 1u)) >> 16);
}
__device__ __forceinline__ void split2(float v, u16& h, u16& l) {
  unsigned u = __float_as_uint(v);
  unsigned hb = (u + 0x7FFFu + ((u >> 16) & 1u)) & 0xFFFF0000u;
  h = (u16)(hb >> 16);
  float lf = v - __uint_as_float(hb);
  l = f2bf_rne(lf);
}
__device__ __forceinline__ void split4(float4 v, ushort4& h, ushort4& l) {
  split2(v.x, h.x, l.x); split2(v.y, h.y, l.y);
  split2(v.z, h.z, l.z); split2(v.w, h.w, l.w);
}

// ---------------------------------------------------------------------------
// split weights fp32 -> bf16 hi/lo (all 10 weight matrices, concatenated)
// ---------------------------------------------------------------------------
__global__ __launch_bounds__(256) void split_w_kernel(
    const float* __restrict__ qw, const float* __restrict__ pw,
    const float* __restrict__ s1, const float* __restrict__ s2,
    const float* __restrict__ s3, const float* __restrict__ s4,
    const float* __restrict__ kv1, const float* __restrict__ kv2,
    const float* __restrict__ kv3, const float* __restrict__ kv4,
    u16* __restrict__ hi, u16* __restrict__ lo) {
  int idx = blockIdx.x * 256 + threadIdx.x;   // grid sized exactly TOTW/256
  const float* src; int off;
  if      (idx < OPW)  { src = qw; off = idx; }
  else if (idx < OS1)  { src = pw; off = idx - OPW; }
  else if (idx < OS2)  { src = s1; off = idx - OS1; }
  else if (idx < OS3)  { src = s2; off = idx - OS2; }
  else if (idx < OS4)  { src = s3; off = idx - OS3; }
  else if (idx < OKV)  { src = s4; off = idx - OS4; }
  else {
    int j = idx - OKV;
    int h = j >> 12; off = j & 4095;
    src = (h == 0) ? kv1 : (h == 1) ? kv2 : (h == 2) ? kv3 : kv4;
  }
  u16 h, l; split2(src[off], h, l);
  hi[idx] = h; lo[idx] = l;
}

// ---------------------------------------------------------------------------
// pre-split input fp32 -> bf16 hi/lo (memory-bound pass)
// ---------------------------------------------------------------------------
__global__ __launch_bounds__(256) void presplit_kernel(
    const float* __restrict__ inp, u16* __restrict__ h, u16* __restrict__ l) {
  int idx = blockIdx.x * 256 + threadIdx.x;   // float4 units; grid = 8192
  float4 v = *(const float4*)&inp[(size_t)idx * 4];
  ushort4 h4, l4; split4(v, h4, l4);
  *(ushort4*)&h[(size_t)idx * 4] = h4;
  *(ushort4*)&l[(size_t)idx * 4] = l4;
}

// ---------------------------------------------------------------------------
// fused LayerNorm(128) + Q-projection via bf16x3 MFMA -> bf16 q out
// ---------------------------------------------------------------------------
__global__ __launch_bounds__(256) void lnq_mfma_kernel(
    const float* __restrict__ inp, const float* __restrict__ nw,
    const float* __restrict__ nb, const u16* __restrict__ wh,
    const u16* __restrict__ wl, const float* __restrict__ qb,
    u16* __restrict__ q) {
  __shared__ float xs[128 * 65];
  __shared__ float ps[4][64], ps2[4][64];
  __shared__ float mu[64], rs[64];
  __shared__ __align__(16) u16 xsh[16 * GS];
  __shared__ __align__(16) u16 xsl[16 * GS];
  int bid = blockIdx.x, n = bid >> 8, t0 = (bid & 255) * 64;
  const float* xb = inp + (size_t)n * C_ * HW_;
  for (int idx = threadIdx.x; idx < 8192; idx += 256) {
    int c = idx >> 6, tt = idx & 63;
    xs[c * 65 + tt] = xb[c * HW_ + t0 + tt];
  }
  __syncthreads();
  {
    int tt = threadIdx.x & 63, part = threadIdx.x >> 6;
    float s = 0.f, s2 = 0.f;
    for (int c = part * 32; c < part * 32 + 32; ++c) {
      float v = xs[c * 65 + tt];
      s += v; s2 += v * v;
    }
    ps[part][tt] = s; ps2[part][tt] = s2;
  }
  __syncthreads();
  if (threadIdx.x < 64) {
    int tt = threadIdx.x;
    float s  = ps[0][tt] + ps[1][tt] + ps[2][tt] + ps[3][tt];
    float s2 = ps2[0][tt] + ps2[1][tt] + ps2[2][tt] + ps2[3][tt];
    float m = s * (1.0f / 128.0f);
    float v = s2 * (1.0f / 128.0f) - m * m;
    mu[tt] = m; rs[tt] = rsqrtf(v + 1e-5f);
  }
  __syncthreads();
  for (int idx = threadIdx.x; idx < 8192; idx += 256) {
    int c = idx & 127, tt = idx >> 7;
    float v = (xs[c * 65 + tt] - mu[tt]) * rs[tt] * nw[c] + nb[c];
    u16 h, l; split2(v, h, l);
    int o = (c >> 3) * GS + tt * 8 + (c & 7);
    xsh[o] = h; xsl[o] = l;
  }
  __syncthreads();
  int wid = threadIdx.x >> 6, lane = threadIdx.x & 63;
  int r = lane & 15, g = lane >> 4;
  f32x4 acc[8] = {};
  #pragma unroll
  for (int kk = 0; kk < 4; ++kk) {
    bf16x8 ah = *(const bf16x8*)&xsh[(kk * 4 + g) * GS + (wid * 16 + r) * 8];
    bf16x8 al = *(const bf16x8*)&xsl[(kk * 4 + g) * GS + (wid * 16 + r) * 8];
    #pragma unroll
    for (int ct = 0; ct < 8; ++ct) {
      int o = ct * 16 + r;
      bf16x8 bh = *(const bf16x8*)&wh[o * 128 + kk * 32 + g * 8];
      bf16x8 bl = *(const bf16x8*)&wl[o * 128 + kk * 32 + g * 8];
      acc[ct] = MFMA(ah, bh, acc[ct]);
      acc[ct] = MFMA(ah, bl, acc[ct]);
      acc[ct] = MFMA(al, bh, acc[ct]);
    }
  }
  #pragma unroll
  for (int ct = 0; ct < 8; ++ct) {
    int col = ct * 16 + r;
    #pragma unroll
    for (int reg = 0; reg < 4; ++reg) {
      int row = wid * 16 + g * 4 + reg;
      q[((size_t)n * HW_ + t0 + row) * 128 + col] = f2bf_rne(acc[ct][reg] + qb[col]);
    }
  }
}

// ---------------------------------------------------------------------------
// generic 128-K GEMM via bf16x3 MFMA (final projection, in-place safe)
// ---------------------------------------------------------------------------
__global__ __launch_bounds__(256) void gemm128_mfma_kernel(
    const float* __restrict__ x, const u16* __restrict__ wh,
    const u16* __restrict__ wl, const float* __restrict__ b,
    float* __restrict__ out) {
  __shared__ __align__(16) u16 xsh[16 * GS];
  __shared__ __align__(16) u16 xsl[16 * GS];
  int r0 = blockIdx.x * 64;
  #pragma unroll
  for (int it = 0; it < 8; ++it) {
    int idx4 = it * 256 + threadIdx.x;       // 2048 float4s
    int row = idx4 >> 5, cg = idx4 & 31;
    float4 v = *(const float4*)&x[(size_t)(r0 + row) * 128 + cg * 4];
    ushort4 h4, l4; split4(v, h4, l4);
    int o = (cg >> 1) * GS + row * 8 + (cg & 1) * 4;
    *(ushort4*)&xsh[o] = h4; *(ushort4*)&xsl[o] = l4;
  }
  __syncthreads();
  int wid = threadIdx.x >> 6, lane = threadIdx.x & 63;
  int r = lane & 15, g = lane >> 4;
  f32x4 acc[8] = {};
  #pragma unroll
  for (int kk = 0; kk < 4; ++kk) {
    bf16x8 ah = *(const bf16x8*)&xsh[(kk * 4 + g) * GS + (wid * 16 + r) * 8];
    bf16x8 al = *(const bf16x8*)&xsl[(kk * 4 + g) * GS + (wid * 16 + r) * 8];
    #pragma unroll
    for (int ct = 0; ct < 8; ++ct) {
      int o = ct * 16 + r;
      bf16x8 bh = *(const bf16x8*)&wh[o * 128 + kk * 32 + g * 8];
      bf16x8 bl = *(const bf16x8*)&wl[o * 128 + kk * 32 + g * 8];
      acc[ct] = MFMA(ah, bh, acc[ct]);
      acc[ct] = MFMA(ah, bl, acc[ct]);
      acc[ct] = MFMA(al, bh, acc[ct]);
    }
  }
  #pragma unroll
  for (int ct = 0; ct < 8; ++ct) {
    int col = ct * 16 + r;
    #pragma unroll
    for (int reg = 0; reg < 4; ++reg) {
      int row = r0 + wid * 16 + g * 4 + reg;
      out[(size_t)row * 128 + col] = acc[ct][reg] + b[col];
    }
  }
}

// ---------------------------------------------------------------------------
// conv-as-GEMM, bf16x3 MFMA, pre-split input, LDS-staged weights, pipelined.
// ---------------------------------------------------------------------------
template <int P, int NW, int SEG>
__device__ __forceinline__ void conv_body(
    int mblk, int seg, const u16* __restrict__ inph, const u16* __restrict__ inpl,
    const u16* __restrict__ wh, const u16* __restrict__ wl,
    float* __restrict__ dst, const float* __restrict__ bias,
    u16* ash, u16* asl, u16* wsh, u16* wsl) {
  constexpr int K    = 128 * P * P;
  constexpr int KSEG = K / SEG;
  constexpr int NT   = KSEG / 32;
  constexpr int HWIN = H_ / NW;
  constexpr int G    = HWIN / P;
  constexpr int L    = G * G;
  constexpr int M    = 4 * NW * NW * L;
  constexpr int LGL  = (L == 256) ? 8 : 6;
  constexpr int LGG  = (G == 16) ? 4 : 3;
  constexpr int LGNW = (NW == 8) ? 3 : (NW == 4) ? 2 : (NW == 2) ? 1 : 0;
  constexpr int LGP  = (P == 8) ? 3 : (P == 4) ? 2 : 1;
  constexpr int LGP2 = 2 * LGP;
  int tid = threadIdx.x, wid = tid >> 6, lane = tid & 63;
  int r = lane & 15, g = lane >> 4;
  int t0 = mblk * 64;
  int kq = tid & 7;
  int kbase = seg * KSEG;

  size_t rbase[2];
  #pragma unroll
  for (int hh = 0; hh < 2; ++hh) {
    int row = (tid >> 3) + hh * 32;
    int tglob = t0 + row;
    int bwin = tglob >> LGL;
    int loc  = tglob & (L - 1);
    int n    = bwin >> (2 * LGNW);
    int wrem = bwin & (NW * NW - 1);
    int wy = wrem >> LGNW, wx = wrem & (NW - 1);
    int oh = loc >> LGG,   ow = loc & (G - 1);
    rbase[hh] = (size_t)n * C_ * HW_ + (size_t)(wy * HWIN + oh * P) * W_ +
                wx * HWIN + ow * P;
  }
  int ldso = (kq >> 1) * GS + (tid >> 3) * 8 + (kq & 1) * 4;
  int wo = tid >> 2, wpart = tid & 3;
  const u16* wrowh = wh + (size_t)wo * K + kbase + wpart * 8;
  const u16* wrowl = wl + (size_t)wo * K + kbase + wpart * 8;
  int wlo_ = wo * 40 + wpart * 8;

  f32x4 acc[4] = {};
  ushort4 avh[2], avl[2];
  uint4 wvh, wvl;

  auto LOADSTEP = [&](int kt) {
    int k = kbase + kt * 32 + kq * 4;
    int ci = k >> LGP2;
    int wp = k & (P * P - 1);
    if constexpr (P >= 4) {
      int kh = wp >> LGP, kw = wp & (P - 1);
      size_t koff = (size_t)ci * HW_ + kh * W_ + kw;
      #pragma unroll
      for (int hh = 0; hh < 2; ++hh) {
        avh[hh] = *(const ushort4*)&inph[rbase[hh] + koff];
        avl[hh] = *(const ushort4*)&inpl[rbase[hh] + koff];
      }
    } else {
      size_t koff = (size_t)ci * HW_;
      #pragma unroll
      for (int hh = 0; hh < 2; ++hh) {
        union { uint2 u; ushort4 s; } cv;
        cv.u.x = *(const u32*)&inph[rbase[hh] + koff];
        cv.u.y = *(const u32*)&inph[rbase[hh] + koff + W_];
        avh[hh] = cv.s;
        cv.u.x = *(const u32*)&inpl[rbase[hh] + koff];
        cv.u.y = *(const u32*)&inpl[rbase[hh] + koff + W_];
        avl[hh] = cv.s;
      }
    }
    wvh = *(const uint4*)(wrowh + kt * 32);
    wvl = *(const uint4*)(wrowl + kt * 32);
  };

  LOADSTEP(0);
  for (int kt = 0; kt < NT; ++kt) {
    __syncthreads();
    *(ushort4*)&ash[ldso]       = avh[0];
    *(ushort4*)&ash[ldso + 256] = avh[1];
    *(ushort4*)&asl[ldso]       = avl[0];
    *(ushort4*)&asl[ldso + 256] = avl[1];
    *(uint4*)&wsh[wlo_] = wvh;
    *(uint4*)&wsl[wlo_] = wvl;
    __syncthreads();
    if (kt + 1 < NT) LOADSTEP(kt + 1);
    bf16x8 ahf = *(const bf16x8*)&ash[g * GS + (wid * 16 + r) * 8];
    bf16x8 alf = *(const bf16x8*)&asl[g * GS + (wid * 16 + r) * 8];
    #pragma unroll
    for (int ct = 0; ct < 4; ++ct) {
      bf16x8 bh = *(const bf16x8*)&wsh[(ct * 16 + r) * 40 + g * 8];
      bf16x8 bl = *(const bf16x8*)&wsl[(ct * 16 + r) * 40 + g * 8];
      acc[ct] = MFMA(ahf, bh, acc[ct]);
      acc[ct] = MFMA(ahf, bl, acc[ct]);
      acc[ct] = MFMA(alf, bh, acc[ct]);
    }
  }
  #pragma unroll
  for (int ct = 0; ct < 4; ++ct) {
    int o = ct * 16 + r;
    #pragma unroll
    for (int reg = 0; reg < 4; ++reg) {
      int row = t0 + wid * 16 + g * 4 + reg;
      if constexpr (SEG == 1) dst[(size_t)row * 64 + o] = acc[ct][reg] + bias[o];
      else                    dst[((size_t)seg * M + row) * 64 + o] = acc[ct][reg];
    }
  }
}

__global__ __launch_bounds__(256) void conv_mfma_kernel(
    const u16* __restrict__ inph, const u16* __restrict__ inpl,
    const u16* __restrict__ wsh_g, const u16* __restrict__ wsl_g,
    const float* __restrict__ b4, float* __restrict__ part,
    float* __restrict__ y4) {
  __shared__ __align__(16) u16 ash[4 * GS];
  __shared__ __align__(16) u16 asl[4 * GS];
  __shared__ __align__(16) u16 wsh[64 * 40];
  __shared__ __align__(16) u16 wsl[64 * 40];
  int bid = blockIdx.x;
  if (bid < 256) {            // head1: 16 mblk x 16 seg
    conv_body<8, 1, 16>(bid & 15, bid >> 4, inph, inpl, wsh_g + OS1, wsl_g + OS1,
                        part, nullptr, ash, asl, wsh, wsl);
  } else if (bid < 512) {     // head2: 64 mblk x 4 seg
    int lb = bid - 256;
    conv_body<4, 2, 4>(lb & 63, lb >> 6, inph, inpl, wsh_g + OS2, wsl_g + OS2,
                       part + 1048576, nullptr, ash, asl, wsh, wsl);
  } else if (bid < 768) {     // head3: 64 mblk x 4 seg
    int lb = bid - 512;
    conv_body<4, 4, 4>(lb & 63, lb >> 6, inph, inpl, wsh_g + OS3, wsl_g + OS3,
                       part + 2097152, nullptr, ash, asl, wsh, wsl);
  } else {                    // head4: 256 mblk, direct to y4
    conv_body<2, 8, 1>(bid - 768, 0, inph, inpl, wsh_g + OS4, wsl_g + OS4,
                       y4, b4, ash, asl, wsh, wsl);
  }
}

// ---------------------------------------------------------------------------
// fused: K-split reduce + conv bias + LN(64) + exact GELU + KV proj (MFMA).
// 64 tokens / block, 400 blocks. K out bf16 [token][32]; V out bf16 [d][k].
// ---------------------------------------------------------------------------
struct LnkvArgs { const float* lnw[4]; const float* lnb[4];
                  const float* kvb[4]; const float* cb[3]; };

__global__ __launch_bounds__(256) void lnkv_mfma_kernel(
    const float* __restrict__ part, const float* __restrict__ y4,
    const u16* __restrict__ kvwh, const u16* __restrict__ kvwl,
    LnkvArgs a, u16* __restrict__ kb, u16* __restrict__ vbT) {
  __shared__ float ych[64 * 68];
  __shared__ __align__(16) u16 ash[8 * GS];
  __shared__ __align__(16) u16 asl[8 * GS];
  int bid = blockIdx.x, tid = threadIdx.x;
  int tb = bid * 64;
  int h  = (tb < 1024) ? 0 : (tb < 5120) ? 1 : (tb < 9216) ? 2 : 3;
  int hb = (h == 0) ? 0 : (h == 1) ? 1024 : (h == 2) ? 5120 : 9216;
  int u0 = tb - hb;
  // stage (+ fused K-split reduce + conv bias for heads 0-2)
  if (h == 3) {
    #pragma unroll
    for (int it = 0; it < 16; ++it) {
      int idx = it * 256 + tid; int row = idx >> 6, ch = idx & 63;
      ych[row * 68 + ch] = y4[(size_t)(u0 + row) * 64 + ch];
    }
  } else {
    const float* pb_; int Mh, SEG;
    if (h == 0)      { pb_ = part;           Mh = 1024; SEG = 16; }
    else if (h == 1) { pb_ = part + 1048576; Mh = 4096; SEG = 4; }
    else             { pb_ = part + 2097152; Mh = 4096; SEG = 4; }
    const float* cb = a.cb[h];
    #pragma unroll
    for (int it = 0; it < 16; ++it) {
      int idx = it * 256 + tid; int row = idx >> 6, ch = idx & 63;
      float s = cb[ch];
      for (int sg = 0; sg < SEG; ++sg)
        s += pb_[((size_t)sg * Mh + u0 + row) * 64 + ch];
      ych[row * 68 + ch] = s;
    }
  }
  __syncthreads();
  // LN + GELU, 4 threads per token, split to A-frag LDS
  {
    int tt = tid >> 2, p = tid & 3;
    const float* xr = &ych[tt * 68 + p * 16];
    float s = 0.f, s2 = 0.f;
    #pragma unroll
    for (int i = 0; i < 16; ++i) { float v = xr[i]; s += v; s2 += v * v; }
    s  += __shfl_xor(s, 1, 64);  s  += __shfl_xor(s, 2, 64);
    s2 += __shfl_xor(s2, 1, 64); s2 += __shfl_xor(s2, 2, 64);
    float mean = s * (1.0f / 64.0f);
    float var  = s2 * (1.0f / 64.0f) - mean * mean;
    float rstd = rsqrtf(var + 1e-5f);
    const float* lnw = a.lnw[h];
    const float* lnb = a.lnb[h];
    #pragma unroll
    for (int i = 0; i < 16; ++i) {
      int ch = p * 16 + i;
      float xn = (xr[i] - mean) * rstd * lnw[ch] + lnb[ch];
      float gg = 0.5f * xn * (1.0f + erff(xn * 0.70710678118654752f));
      u16 hh, ll; split2(gg, hh, ll);
      int o = (ch >> 3) * GS + tt * 8 + (ch & 7);
      ash[o] = hh; asl[o] = ll;
    }
  }
  __syncthreads();
  int wid = tid >> 6, lane = tid & 63, r = lane & 15, g = lane >> 4;
  const u16* wbh = kvwh + h * 4096;
  const u16* wbl = kvwl + h * 4096;
  f32x4 acc[4] = {};
  #pragma unroll
  for (int kk = 0; kk < 2; ++kk) {
    bf16x8 ah = *(const bf16x8*)&ash[(kk * 4 + g) * GS + (wid * 16 + r) * 8];
    bf16x8 al = *(const bf16x8*)&asl[(kk * 4 + g) * GS + (wid * 16 + r) * 8];
    #pragma unroll
    for (int ct = 0; ct < 4; ++ct) {
      bf16x8 bh = *(const bf16x8*)&wbh[(ct * 16 + r) * 64 + kk * 32 + g * 8];
      bf16x8 bl = *(const bf16x8*)&wbl[(ct * 16 + r) * 64 + kk * 32 + g * 8];
      acc[ct] = MFMA(ah, bh, acc[ct]);
      acc[ct] = MFMA(ah, bl, acc[ct]);
      acc[ct] = MFMA(al, bh, acc[ct]);
    }
  }
  const float* kvb = a.kvb[h];
  int lk = (h < 2) ? 256 : 64;
  #pragma unroll
  for (int ct = 0; ct < 4; ++ct) {
    int o = ct * 16 + r;
    float bias = kvb[o];
    #pragma unroll
    for (int reg = 0; reg < 4; ++reg) {
      int row = wid * 16 + g * 4 + reg;
      int tg  = tb + row;
      float v = acc[ct][reg] + bias;
      if (o < 32) {
        kb[(size_t)tg * 32 + o] = f2bf_rne(v);
      } else {
        int dd = o - 32;
        int kl = (tg - hb) & (lk - 1);
        int wstart = tg - kl;
        vbT[(size_t)wstart * 32 + dd * lk + kl] = f2bf_rne(v);
      }
    }
  }
}

// ---------------------------------------------------------------------------
// MFMA attention: per wave one 16-q tile vs full window key set (exact softmax)
// ---------------------------------------------------------------------------
template <int NW, int LK>
__device__ __forceinline__ void attn_mfma_body(
    int bid, int head, int head_off, const u16* __restrict__ q,
    const u16* __restrict__ kb, const u16* __restrict__ vbT,
    float* __restrict__ cbuf) {
  constexpr int HWIN = H_ / NW;
  constexpr int LQ   = HWIN * HWIN;
  constexpr int BPW  = LQ / 64;
  constexpr int NCT  = LK / 16;
  constexpr int NST  = LK / 32;
  constexpr int PS   = LK + 8;
  extern __shared__ __align__(16) u16 plds[];
  int wid = threadIdx.x >> 6, lane = threadIdx.x & 63;
  int g = lane >> 4, c = lane & 15;
  int win  = bid / BPW;
  int tIdx = (bid % BPW) * 4 + wid;
  int n = win / (NW * NW);
  int wrem = win % (NW * NW);
  int wy = wrem / NW, wx = wrem % NW;
  int kstart = head_off + win * LK;
  u16* pw_ = plds + wid * 16 * PS;

  int j = tIdx * 16 + c;
  int ih = j / HWIN, iw = j % HWIN;
  int t = (wy * HWIN + ih) * W_ + wx * HWIN + iw;
  bf16x8 qa = *(const bf16x8*)&q[((size_t)n * HW_ + t) * 128 + head * 32 + g * 8];

  f32x4 sacc[NCT];
  #pragma unroll
  for (int ct = 0; ct < NCT; ++ct) {
    sacc[ct] = f32x4{0.f, 0.f, 0.f, 0.f};
    bf16x8 kf = *(const bf16x8*)&kb[(size_t)(kstart + ct * 16 + c) * 32 + g * 8];
    sacc[ct] = MFMA(qa, kf, sacc[ct]);
  }
  #pragma unroll
  for (int ct = 0; ct < NCT; ++ct)
    #pragma unroll
    for (int reg = 0; reg < 4; ++reg) sacc[ct][reg] *= SCALE_;
  #pragma unroll
  for (int reg = 0; reg < 4; ++reg) {
    float mx = -1e30f;
    #pragma unroll
    for (int ct = 0; ct < NCT; ++ct) mx = fmaxf(mx, sacc[ct][reg]);
    mx = fmaxf(mx, __shfl_xor(mx, 1, 64));
    mx = fmaxf(mx, __shfl_xor(mx, 2, 64));
    mx = fmaxf(mx, __shfl_xor(mx, 4, 64));
    mx = fmaxf(mx, __shfl_xor(mx, 8, 64));
    float sm = 0.f;
    #pragma unroll
    for (int ct = 0; ct < NCT; ++ct) {
      float e = __expf(sacc[ct][reg] - mx);
      sacc[ct][reg] = e;
      sm += e;
    }
    sm += __shfl_xor(sm, 1, 64);
    sm += __shfl_xor(sm, 2, 64);
    sm += __shfl_xor(sm, 4, 64);
    sm += __shfl_xor(sm, 8, 64);
    float inv = 1.0f / sm;
    #pragma unroll
    for (int ct = 0; ct < NCT; ++ct) sacc[ct][reg] *= inv;
  }
  #pragma unroll
  for (int ct = 0; ct < NCT; ++ct)
    #pragma unroll
    for (int reg = 0; reg < 4; ++reg)
      pw_[(g * 4 + reg) * PS + ct * 16 + c] = f2bf_rne(sacc[ct][reg]);
  f32x4 oacc[2] = {};
  #pragma unroll
  for (int st = 0; st < NST; ++st) {
    bf16x8 pa = *(const bf16x8*)&pw_[c * PS + st * 32 + g * 8];
    #pragma unroll
    for (int dt = 0; dt < 2; ++dt) {
      bf16x8 vf = *(const bf16x8*)&vbT[(size_t)kstart * 32 +
                                       (dt * 16 + c) * LK + st * 32 + g * 8];
      oacc[dt] = MFMA(pa, vf, oacc[dt]);
    }
  }
  #pragma unroll
  for (int reg = 0; reg < 4; ++reg) {
    int jo = tIdx * 16 + g * 4 + reg;
    int iho = jo / HWIN, iwo = jo % HWIN;
    int to = (wy * HWIN + iho) * W_ + wx * HWIN + iwo;
    float* op = cbuf + ((size_t)n * HW_ + to) * 128 + head * 32;
    op[c]      = oacc[0][reg];
    op[16 + c] = oacc[1][reg];
  }
}

__global__ __launch_bounds__(256) void attn_kernel(
    const u16* __restrict__ q, const u16* __restrict__ kb,
    const u16* __restrict__ vbT, float* __restrict__ cbuf) {
  int bid = blockIdx.x;
  if      (bid < 1024) attn_mfma_body<1, 256>(bid,        0, 0,    q, kb, vbT, cbuf);
  else if (bid < 2048) attn_mfma_body<2, 256>(bid - 1024, 1, 1024, q, kb, vbT, cbuf);
  else if (bid < 3072) attn_mfma_body<4, 64 >(bid - 2048, 2, 5120, q, kb, vbT, cbuf);
  else                 attn_mfma_body<8, 64 >(bid - 3072, 3, 9216, q, kb, vbT, cbuf);
}

// ---------------------------------------------------------------------------
extern "C" void kernel_launch(void* const* d_in, const int* in_sizes, int n_in,
                              void* d_out, int out_size, void* d_ws, size_t ws_size,
                              hipStream_t stream) {
  const float* inp = (const float*)d_in[0];
  const float* nw  = (const float*)d_in[1];
  const float* nb  = (const float*)d_in[2];
  const float* qw  = (const float*)d_in[3];
  const float* qb  = (const float*)d_in[4];
  const float* pw  = (const float*)d_in[29];
  const float* pb  = (const float*)d_in[30];

  float* ws   = (float*)d_ws;
  u16*   qb16 = (u16*)(ws + QB_OFF);
  float* y4   = ws + Y4_OFF;
  u16*   kb   = (u16*)(ws + KB_OFF);
  u16*   vbT  = (u16*)(ws + VT_OFF);
  float* part = ws + PART_OFF;
  u16*   wsp  = (u16*)(ws + WSP_OFF);
  u16*   whi  = wsp;
  u16*   wlo  = wsp + TOTW;
  u16*   inph = (u16*)(ws + INH_OFF);
  u16*   inpl = (u16*)(ws + INL_OFF);
  float* cbuf = (float*)d_out;

  // 0) split weights + input to bf16 hi/lo
  split_w_kernel<<<TOTW / 256, 256, 0, stream>>>(
      qw, pw, (const float*)d_in[5], (const float*)d_in[11],
      (const float*)d_in[17], (const float*)d_in[23],
      (const float*)d_in[9], (const float*)d_in[15],
      (const float*)d_in[21], (const float*)d_in[27], whi, wlo);
  presplit_kernel<<<8192, 256, 0, stream>>>(inp, inph, inpl);

  // 1) fused LN + Q projection (MFMA) -> bf16 q
  lnq_mfma_kernel<<<1024, 256, 0, stream>>>(inp, nw, nb, whi + OQW, wlo + OQW,
                                            qb, qb16);

  // 2) all 4 patch-embed convs in one launch (MFMA)
  conv_mfma_kernel<<<1024, 256, 0, stream>>>(inph, inpl, whi, wlo,
                                             (const float*)d_in[24], part, y4);

  // 3) fused reduce + LN + GELU + KV projection (MFMA)
  LnkvArgs la;
  la.lnw[0] = (const float*)d_in[7];  la.lnb[0] = (const float*)d_in[8];
  la.kvb[0] = (const float*)d_in[10];
  la.lnw[1] = (const float*)d_in[13]; la.lnb[1] = (const float*)d_in[14];
  la.kvb[1] = (const float*)d_in[16];
  la.lnw[2] = (const float*)d_in[19]; la.lnb[2] = (const float*)d_in[20];
  la.kvb[2] = (const float*)d_in[22];
  la.lnw[3] = (const float*)d_in[25]; la.lnb[3] = (const float*)d_in[26];
  la.kvb[3] = (const float*)d_in[28];
  la.cb[0] = (const float*)d_in[6];
  la.cb[1] = (const float*)d_in[12];
  la.cb[2] = (const float*)d_in[18];
  lnkv_mfma_kernel<<<400, 256, 0, stream>>>(part, y4, whi + OKV, wlo + OKV,
                                            la, kb, vbT);

  // 4) MFMA attention (per-wave P tile in LDS: 4 * 16 * 264 * 2 = 33792 B)
  attn_kernel<<<4096, 256, 33792, stream>>>(qb16, kb, vbT, cbuf);

  // 5) final projection, in place on d_out (MFMA)
  gemm128_mfma_kernel<<<1024, 256, 0, stream>>>(cbuf, whi + OPW, wlo + OPW, pb,
                                                (float*)d_out);
}

// Round 7
// 204.938 us; speedup vs baseline: 1.2628x; 1.2628x over previous
//
#include <hip/hip_runtime.h>
#include <math.h>

#define N_   4
#define C_   128
#define H_   128
#define W_   128
#define HW_  16384
#define SCALE_ 0.17677669529663687f   // 32^-0.5

typedef unsigned short u16;
typedef unsigned int   u32;
typedef __bf16 bf16x8 __attribute__((ext_vector_type(8)));
typedef float  f32x4  __attribute__((ext_vector_type(4)));

#define MFMA(a, b, c) __builtin_amdgcn_mfma_f32_16x16x32_bf16((a), (b), (c), 0, 0, 0)

// ---- ws float offsets -------------------------------------------------------
#define QB_OFF   0            // 4,194,304 floats (8,388,608 u16 bf16 q)
#define Y_OFF    4194304      // 1,638,400 (all heads, post-reduce + bias)
#define KB_OFF   5832704      //   409,600 floats (819,200 u16 bf16 K)
#define VT_OFF   6242304      //   409,600 floats (819,200 u16 bf16 V^T)
#define PART_OFF 6651904      // 3,145,728
#define WSP_OFF  9797632      //   868,352 floats (2 x 868,352 u16 hi+lo)
#define INH_OFF  10665984     // 4,194,304 floats (8,388,608 u16)
#define INL_OFF  14860288     // 4,194,304 floats
// total 19,054,592 floats = 76.2 MB

// split-weight region offsets (u16 units, within hi or lo half)
#define OQW 0
#define OPW 16384
#define OS1 32768
#define OS2 557056
#define OS3 688128
#define OS4 819200
#define OKV 851968
#define TOTW 868352

#define GS 520   // A-LDS kgroup stride in u16

// ---------------------------------------------------------------------------
__device__ __forceinline__ u16 f2bf_rne(float x) {
  unsigned u = __float_as_uint(x);
  return (u16)((u + 0x7FFFu + ((u >> 16) & 1u)) >> 16);
}
__device__ __forceinline__ void split2(float v, u16& h, u16& l) {
  unsigned u = __float_as_uint(v);
  unsigned hb = (u + 0x7FFFu + ((u >> 16) & 1u)) & 0xFFFF0000u;
  h = (u16)(hb >> 16);
  float lf = v - __uint_as_float(hb);
  l = f2bf_rne(lf);
}
__device__ __forceinline__ void split4(float4 v, ushort4& h, ushort4& l) {
  split2(v.x, h.x, l.x); split2(v.y, h.y, l.y);
  split2(v.z, h.z, l.z); split2(v.w, h.w, l.w);
}

// ---------------------------------------------------------------------------
// split weights fp32 -> bf16 hi/lo (all 10 weight matrices, concatenated)
// ---------------------------------------------------------------------------
__global__ __launch_bounds__(256) void split_w_kernel(
    const float* __restrict__ qw, const float* __restrict__ pw,
    const float* __restrict__ s1, const float* __restrict__ s2,
    const float* __restrict__ s3, const float* __restrict__ s4,
    const float* __restrict__ kv1, const float* __restrict__ kv2,
    const float* __restrict__ kv3, const float* __restrict__ kv4,
    u16* __restrict__ hi, u16* __restrict__ lo) {
  int idx = blockIdx.x * 256 + threadIdx.x;   // grid sized exactly TOTW/256
  const float* src; int off;
  if      (idx < OPW)  { src = qw; off = idx; }
  else if (idx < OS1)  { src = pw; off = idx - OPW; }
  else if (idx < OS2)  { src = s1; off = idx - OS1; }
  else if (idx < OS3)  { src = s2; off = idx - OS2; }
  else if (idx < OS4)  { src = s3; off = idx - OS3; }
  else if (idx < OKV)  { src = s4; off = idx - OS4; }
  else {
    int j = idx - OKV;
    int h = j >> 12; off = j & 4095;
    src = (h == 0) ? kv1 : (h == 1) ? kv2 : (h == 2) ? kv3 : kv4;
  }
  u16 h, l; split2(src[off], h, l);
  hi[idx] = h; lo[idx] = l;
}

// ---------------------------------------------------------------------------
// pre-split input fp32 -> bf16 hi/lo (memory-bound pass)
// ---------------------------------------------------------------------------
__global__ __launch_bounds__(256) void presplit_kernel(
    const float* __restrict__ inp, u16* __restrict__ h, u16* __restrict__ l) {
  int idx = blockIdx.x * 256 + threadIdx.x;   // float4 units; grid = 8192
  float4 v = *(const float4*)&inp[(size_t)idx * 4];
  ushort4 h4, l4; split4(v, h4, l4);
  *(ushort4*)&h[(size_t)idx * 4] = h4;
  *(ushort4*)&l[(size_t)idx * 4] = l4;
}

// ---------------------------------------------------------------------------
// fused LayerNorm(128) + Q-projection via bf16x3 MFMA -> bf16 q out
// ---------------------------------------------------------------------------
__global__ __launch_bounds__(256) void lnq_mfma_kernel(
    const float* __restrict__ inp, const float* __restrict__ nw,
    const float* __restrict__ nb, const u16* __restrict__ wh,
    const u16* __restrict__ wl, const float* __restrict__ qb,
    u16* __restrict__ q) {
  __shared__ float xs[128 * 65];
  __shared__ float ps[4][64], ps2[4][64];
  __shared__ float mu[64], rs[64];
  __shared__ __align__(16) u16 xsh[16 * GS];
  __shared__ __align__(16) u16 xsl[16 * GS];
  int bid = blockIdx.x, n = bid >> 8, t0 = (bid & 255) * 64;
  const float* xb = inp + (size_t)n * C_ * HW_;
  for (int idx = threadIdx.x; idx < 8192; idx += 256) {
    int c = idx >> 6, tt = idx & 63;
    xs[c * 65 + tt] = xb[c * HW_ + t0 + tt];
  }
  __syncthreads();
  {
    int tt = threadIdx.x & 63, part = threadIdx.x >> 6;
    float s = 0.f, s2 = 0.f;
    for (int c = part * 32; c < part * 32 + 32; ++c) {
      float v = xs[c * 65 + tt];
      s += v; s2 += v * v;
    }
    ps[part][tt] = s; ps2[part][tt] = s2;
  }
  __syncthreads();
  if (threadIdx.x < 64) {
    int tt = threadIdx.x;
    float s  = ps[0][tt] + ps[1][tt] + ps[2][tt] + ps[3][tt];
    float s2 = ps2[0][tt] + ps2[1][tt] + ps2[2][tt] + ps2[3][tt];
    float m = s * (1.0f / 128.0f);
    float v = s2 * (1.0f / 128.0f) - m * m;
    mu[tt] = m; rs[tt] = rsqrtf(v + 1e-5f);
  }
  __syncthreads();
  for (int idx = threadIdx.x; idx < 8192; idx += 256) {
    int c = idx & 127, tt = idx >> 7;
    float v = (xs[c * 65 + tt] - mu[tt]) * rs[tt] * nw[c] + nb[c];
    u16 h, l; split2(v, h, l);
    int o = (c >> 3) * GS + tt * 8 + (c & 7);
    xsh[o] = h; xsl[o] = l;
  }
  __syncthreads();
  int wid = threadIdx.x >> 6, lane = threadIdx.x & 63;
  int r = lane & 15, g = lane >> 4;
  f32x4 acc[8] = {};
  #pragma unroll
  for (int kk = 0; kk < 4; ++kk) {
    bf16x8 ah = *(const bf16x8*)&xsh[(kk * 4 + g) * GS + (wid * 16 + r) * 8];
    bf16x8 al = *(const bf16x8*)&xsl[(kk * 4 + g) * GS + (wid * 16 + r) * 8];
    #pragma unroll
    for (int ct = 0; ct < 8; ++ct) {
      int o = ct * 16 + r;
      bf16x8 bh = *(const bf16x8*)&wh[o * 128 + kk * 32 + g * 8];
      bf16x8 bl = *(const bf16x8*)&wl[o * 128 + kk * 32 + g * 8];
      acc[ct] = MFMA(ah, bh, acc[ct]);
      acc[ct] = MFMA(ah, bl, acc[ct]);
      acc[ct] = MFMA(al, bh, acc[ct]);
    }
  }
  #pragma unroll
  for (int ct = 0; ct < 8; ++ct) {
    int col = ct * 16 + r;
    #pragma unroll
    for (int reg = 0; reg < 4; ++reg) {
      int row = wid * 16 + g * 4 + reg;
      q[((size_t)n * HW_ + t0 + row) * 128 + col] = f2bf_rne(acc[ct][reg] + qb[col]);
    }
  }
}

// ---------------------------------------------------------------------------
// generic 128-K GEMM via bf16x3 MFMA (final projection, in-place safe)
// ---------------------------------------------------------------------------
__global__ __launch_bounds__(256) void gemm128_mfma_kernel(
    const float* __restrict__ x, const u16* __restrict__ wh,
    const u16* __restrict__ wl, const float* __restrict__ b,
    float* __restrict__ out) {
  __shared__ __align__(16) u16 xsh[16 * GS];
  __shared__ __align__(16) u16 xsl[16 * GS];
  int r0 = blockIdx.x * 64;
  #pragma unroll
  for (int it = 0; it < 8; ++it) {
    int idx4 = it * 256 + threadIdx.x;       // 2048 float4s
    int row = idx4 >> 5, cg = idx4 & 31;
    float4 v = *(const float4*)&x[(size_t)(r0 + row) * 128 + cg * 4];
    ushort4 h4, l4; split4(v, h4, l4);
    int o = (cg >> 1) * GS + row * 8 + (cg & 1) * 4;
    *(ushort4*)&xsh[o] = h4; *(ushort4*)&xsl[o] = l4;
  }
  __syncthreads();
  int wid = threadIdx.x >> 6, lane = threadIdx.x & 63;
  int r = lane & 15, g = lane >> 4;
  f32x4 acc[8] = {};
  #pragma unroll
  for (int kk = 0; kk < 4; ++kk) {
    bf16x8 ah = *(const bf16x8*)&xsh[(kk * 4 + g) * GS + (wid * 16 + r) * 8];
    bf16x8 al = *(const bf16x8*)&xsl[(kk * 4 + g) * GS + (wid * 16 + r) * 8];
    #pragma unroll
    for (int ct = 0; ct < 8; ++ct) {
      int o = ct * 16 + r;
      bf16x8 bh = *(const bf16x8*)&wh[o * 128 + kk * 32 + g * 8];
      bf16x8 bl = *(const bf16x8*)&wl[o * 128 + kk * 32 + g * 8];
      acc[ct] = MFMA(ah, bh, acc[ct]);
      acc[ct] = MFMA(ah, bl, acc[ct]);
      acc[ct] = MFMA(al, bh, acc[ct]);
    }
  }
  #pragma unroll
  for (int ct = 0; ct < 8; ++ct) {
    int col = ct * 16 + r;
    #pragma unroll
    for (int reg = 0; reg < 4; ++reg) {
      int row = r0 + wid * 16 + g * 4 + reg;
      out[(size_t)row * 128 + col] = acc[ct][reg] + b[col];
    }
  }
}

// ---------------------------------------------------------------------------
// conv-as-GEMM, bf16x3 MFMA, pre-split input, LDS-staged weights, pipelined.
// ---------------------------------------------------------------------------
template <int P, int NW, int SEG>
__device__ __forceinline__ void conv_body(
    int mblk, int seg, const u16* __restrict__ inph, const u16* __restrict__ inpl,
    const u16* __restrict__ wh, const u16* __restrict__ wl,
    float* __restrict__ dst, const float* __restrict__ bias,
    u16* ash, u16* asl, u16* wsh, u16* wsl) {
  constexpr int K    = 128 * P * P;
  constexpr int KSEG = K / SEG;
  constexpr int NT   = KSEG / 32;
  constexpr int HWIN = H_ / NW;
  constexpr int G    = HWIN / P;
  constexpr int L    = G * G;
  constexpr int M    = 4 * NW * NW * L;
  constexpr int LGL  = (L == 256) ? 8 : 6;
  constexpr int LGG  = (G == 16) ? 4 : 3;
  constexpr int LGNW = (NW == 8) ? 3 : (NW == 4) ? 2 : (NW == 2) ? 1 : 0;
  constexpr int LGP  = (P == 8) ? 3 : (P == 4) ? 2 : 1;
  constexpr int LGP2 = 2 * LGP;
  int tid = threadIdx.x, wid = tid >> 6, lane = tid & 63;
  int r = lane & 15, g = lane >> 4;
  int t0 = mblk * 64;
  int kq = tid & 7;
  int kbase = seg * KSEG;

  size_t rbase[2];
  #pragma unroll
  for (int hh = 0; hh < 2; ++hh) {
    int row = (tid >> 3) + hh * 32;
    int tglob = t0 + row;
    int bwin = tglob >> LGL;
    int loc  = tglob & (L - 1);
    int n    = bwin >> (2 * LGNW);
    int wrem = bwin & (NW * NW - 1);
    int wy = wrem >> LGNW, wx = wrem & (NW - 1);
    int oh = loc >> LGG,   ow = loc & (G - 1);
    rbase[hh] = (size_t)n * C_ * HW_ + (size_t)(wy * HWIN + oh * P) * W_ +
                wx * HWIN + ow * P;
  }
  int ldso = (kq >> 1) * GS + (tid >> 3) * 8 + (kq & 1) * 4;
  int wo = tid >> 2, wpart = tid & 3;
  const u16* wrowh = wh + (size_t)wo * K + kbase + wpart * 8;
  const u16* wrowl = wl + (size_t)wo * K + kbase + wpart * 8;
  int wlo_ = wo * 40 + wpart * 8;

  f32x4 acc[4] = {};
  ushort4 avh[2], avl[2];
  uint4 wvh, wvl;

  auto LOADSTEP = [&](int kt) {
    int k = kbase + kt * 32 + kq * 4;
    int ci = k >> LGP2;
    int wp = k & (P * P - 1);
    if constexpr (P >= 4) {
      int kh = wp >> LGP, kw = wp & (P - 1);
      size_t koff = (size_t)ci * HW_ + kh * W_ + kw;
      #pragma unroll
      for (int hh = 0; hh < 2; ++hh) {
        avh[hh] = *(const ushort4*)&inph[rbase[hh] + koff];
        avl[hh] = *(const ushort4*)&inpl[rbase[hh] + koff];
      }
    } else {
      size_t koff = (size_t)ci * HW_;
      #pragma unroll
      for (int hh = 0; hh < 2; ++hh) {
        union { uint2 u; ushort4 s; } cv;
        cv.u.x = *(const u32*)&inph[rbase[hh] + koff];
        cv.u.y = *(const u32*)&inph[rbase[hh] + koff + W_];
        avh[hh] = cv.s;
        cv.u.x = *(const u32*)&inpl[rbase[hh] + koff];
        cv.u.y = *(const u32*)&inpl[rbase[hh] + koff + W_];
        avl[hh] = cv.s;
      }
    }
    wvh = *(const uint4*)(wrowh + kt * 32);
    wvl = *(const uint4*)(wrowl + kt * 32);
  };

  LOADSTEP(0);
  for (int kt = 0; kt < NT; ++kt) {
    __syncthreads();
    *(ushort4*)&ash[ldso]       = avh[0];
    *(ushort4*)&ash[ldso + 256] = avh[1];
    *(ushort4*)&asl[ldso]       = avl[0];
    *(ushort4*)&asl[ldso + 256] = avl[1];
    *(uint4*)&wsh[wlo_] = wvh;
    *(uint4*)&wsl[wlo_] = wvl;
    __syncthreads();
    if (kt + 1 < NT) LOADSTEP(kt + 1);
    bf16x8 ahf = *(const bf16x8*)&ash[g * GS + (wid * 16 + r) * 8];
    bf16x8 alf = *(const bf16x8*)&asl[g * GS + (wid * 16 + r) * 8];
    #pragma unroll
    for (int ct = 0; ct < 4; ++ct) {
      bf16x8 bh = *(const bf16x8*)&wsh[(ct * 16 + r) * 40 + g * 8];
      bf16x8 bl = *(const bf16x8*)&wsl[(ct * 16 + r) * 40 + g * 8];
      acc[ct] = MFMA(ahf, bh, acc[ct]);
      acc[ct] = MFMA(ahf, bl, acc[ct]);
      acc[ct] = MFMA(alf, bh, acc[ct]);
    }
  }
  #pragma unroll
  for (int ct = 0; ct < 4; ++ct) {
    int o = ct * 16 + r;
    #pragma unroll
    for (int reg = 0; reg < 4; ++reg) {
      int row = t0 + wid * 16 + g * 4 + reg;
      if constexpr (SEG == 1) dst[(size_t)row * 64 + o] = acc[ct][reg] + bias[o];
      else                    dst[((size_t)seg * M + row) * 64 + o] = acc[ct][reg];
    }
  }
}

__global__ __launch_bounds__(256) void conv_mfma_kernel(
    const u16* __restrict__ inph, const u16* __restrict__ inpl,
    const u16* __restrict__ wsh_g, const u16* __restrict__ wsl_g,
    const float* __restrict__ b4, float* __restrict__ part,
    float* __restrict__ y) {
  __shared__ __align__(16) u16 ash[4 * GS];
  __shared__ __align__(16) u16 asl[4 * GS];
  __shared__ __align__(16) u16 wsh[64 * 40];
  __shared__ __align__(16) u16 wsl[64 * 40];
  int bid = blockIdx.x;
  if (bid < 256) {            // head1: 16 mblk x 16 seg
    conv_body<8, 1, 16>(bid & 15, bid >> 4, inph, inpl, wsh_g + OS1, wsl_g + OS1,
                        part, nullptr, ash, asl, wsh, wsl);
  } else if (bid < 512) {     // head2: 64 mblk x 4 seg
    int lb = bid - 256;
    conv_body<4, 2, 4>(lb & 63, lb >> 6, inph, inpl, wsh_g + OS2, wsl_g + OS2,
                       part + 1048576, nullptr, ash, asl, wsh, wsl);
  } else if (bid < 768) {     // head3: 64 mblk x 4 seg
    int lb = bid - 512;
    conv_body<4, 4, 4>(lb & 63, lb >> 6, inph, inpl, wsh_g + OS3, wsl_g + OS3,
                       part + 2097152, nullptr, ash, asl, wsh, wsl);
  } else {                    // head4: 256 mblk, direct to y
    conv_body<2, 8, 1>(bid - 768, 0, inph, inpl, wsh_g + OS4, wsl_g + OS4,
                       y + (size_t)9216 * 64, b4, ash, asl, wsh, wsl);
  }
}

// reduce K-split partials + conv bias for heads 1-3 -> y
__global__ __launch_bounds__(256) void reduce_kernel(
    const float* __restrict__ part, const float* __restrict__ b1,
    const float* __restrict__ b2, const float* __restrict__ b3,
    float* __restrict__ y) {
  int idx = blockIdx.x * 256 + threadIdx.x;   // grid exactly 589824/256 = 2304
  int tg = idx >> 6, o = idx & 63;
  float s;
  if (tg < 1024) {
    s = b1[o];
    #pragma unroll
    for (int sg = 0; sg < 16; ++sg) s += part[((size_t)sg * 1024 + tg) * 64 + o];
  } else if (tg < 5120) {
    int t = tg - 1024;
    const float* p2 = part + 1048576;
    s = b2[o];
    #pragma unroll
    for (int sg = 0; sg < 4; ++sg) s += p2[((size_t)sg * 4096 + t) * 64 + o];
  } else {
    int t = tg - 5120;
    const float* p3 = part + 2097152;
    s = b3[o];
    #pragma unroll
    for (int sg = 0; sg < 4; ++sg) s += p3[((size_t)sg * 4096 + t) * 64 + o];
  }
  y[(size_t)tg * 64 + o] = s;
}

// ---------------------------------------------------------------------------
// fused LN(64) + exact GELU + KV projection (MFMA). 64 tokens/block, 400 blocks.
// K out bf16 [token][32]; V out bf16 window-transposed [d][k].
// ---------------------------------------------------------------------------
struct LnkvArgs { const float* lnw[4]; const float* lnb[4]; const float* kvb[4]; };

__global__ __launch_bounds__(256) void lnkv_mfma_kernel(
    const float* __restrict__ y, const u16* __restrict__ kvwh,
    const u16* __restrict__ kvwl, LnkvArgs a,
    u16* __restrict__ kb, u16* __restrict__ vbT) {
  __shared__ float ych[64 * 65];
  __shared__ __align__(16) u16 ash[8 * GS];
  __shared__ __align__(16) u16 asl[8 * GS];
  int bid = blockIdx.x, tid = threadIdx.x;
  int tb = bid * 64;
  int h  = (tb < 1024) ? 0 : (tb < 5120) ? 1 : (tb < 9216) ? 2 : 3;
  int hb = (h == 0) ? 0 : (h == 1) ? 1024 : (h == 2) ? 5120 : 9216;
  // stage 64x64 token tile (coalesced float4)
  #pragma unroll
  for (int it = 0; it < 4; ++it) {
    int i4 = it * 256 + tid;            // 1024 float4s
    int row = i4 >> 4, cg = i4 & 15;
    float4 v = *(const float4*)&y[(size_t)(tb + row) * 64 + cg * 4];
    *(float4*)&ych[row * 65 + cg * 4] = v;
  }
  __syncthreads();
  // LN + GELU, 4 threads per token, split to A-frag LDS
  {
    int tt = tid >> 2, p = tid & 3;
    const float* xr = &ych[tt * 65 + p * 16];
    float s = 0.f, s2 = 0.f;
    #pragma unroll
    for (int i = 0; i < 16; ++i) { float v = xr[i]; s += v; s2 += v * v; }
    s  += __shfl_xor(s, 1, 64);  s  += __shfl_xor(s, 2, 64);
    s2 += __shfl_xor(s2, 1, 64); s2 += __shfl_xor(s2, 2, 64);
    float mean = s * (1.0f / 64.0f);
    float var  = s2 * (1.0f / 64.0f) - mean * mean;
    float rstd = rsqrtf(var + 1e-5f);
    const float* lnw = a.lnw[h];
    const float* lnb = a.lnb[h];
    #pragma unroll
    for (int i = 0; i < 16; ++i) {
      int ch = p * 16 + i;
      float xn = (xr[i] - mean) * rstd * lnw[ch] + lnb[ch];
      float gg = 0.5f * xn * (1.0f + erff(xn * 0.70710678118654752f));
      u16 hh, ll; split2(gg, hh, ll);
      int o = (ch >> 3) * GS + tt * 8 + (ch & 7);
      ash[o] = hh; asl[o] = ll;
    }
  }
  __syncthreads();
  int wid = tid >> 6, lane = tid & 63, r = lane & 15, g = lane >> 4;
  const u16* wbh = kvwh + h * 4096;
  const u16* wbl = kvwl + h * 4096;
  f32x4 acc[4] = {};
  #pragma unroll
  for (int kk = 0; kk < 2; ++kk) {
    bf16x8 ah = *(const bf16x8*)&ash[(kk * 4 + g) * GS + (wid * 16 + r) * 8];
    bf16x8 al = *(const bf16x8*)&asl[(kk * 4 + g) * GS + (wid * 16 + r) * 8];
    #pragma unroll
    for (int ct = 0; ct < 4; ++ct) {
      bf16x8 bh = *(const bf16x8*)&wbh[(ct * 16 + r) * 64 + kk * 32 + g * 8];
      bf16x8 bl = *(const bf16x8*)&wbl[(ct * 16 + r) * 64 + kk * 32 + g * 8];
      acc[ct] = MFMA(ah, bh, acc[ct]);
      acc[ct] = MFMA(ah, bl, acc[ct]);
      acc[ct] = MFMA(al, bh, acc[ct]);
    }
  }
  const float* kvb = a.kvb[h];
  int lk = (h < 2) ? 256 : 64;
  #pragma unroll
  for (int ct = 0; ct < 4; ++ct) {
    int o = ct * 16 + r;
    float bias = kvb[o];
    #pragma unroll
    for (int reg = 0; reg < 4; ++reg) {
      int row = wid * 16 + g * 4 + reg;
      int tg  = tb + row;
      float v = acc[ct][reg] + bias;
      if (o < 32) {
        kb[(size_t)tg * 32 + o] = f2bf_rne(v);
      } else {
        int dd = o - 32;
        int kl = (tg - hb) & (lk - 1);
        int wstart = tg - kl;
        vbT[(size_t)wstart * 32 + dd * lk + kl] = f2bf_rne(v);
      }
    }
  }
}

// ---------------------------------------------------------------------------
// MFMA attention: per wave one 16-q tile vs full window key set (exact softmax)
// ---------------------------------------------------------------------------
template <int NW, int LK>
__device__ __forceinline__ void attn_mfma_body(
    int bid, int head, int head_off, const u16* __restrict__ q,
    const u16* __restrict__ kb, const u16* __restrict__ vbT,
    float* __restrict__ cbuf) {
  constexpr int HWIN = H_ / NW;
  constexpr int LQ   = HWIN * HWIN;
  constexpr int BPW  = LQ / 64;
  constexpr int NCT  = LK / 16;
  constexpr int NST  = LK / 32;
  constexpr int PS   = LK + 8;
  extern __shared__ __align__(16) u16 plds[];
  int wid = threadIdx.x >> 6, lane = threadIdx.x & 63;
  int g = lane >> 4, c = lane & 15;
  int win  = bid / BPW;
  int tIdx = (bid % BPW) * 4 + wid;
  int n = win / (NW * NW);
  int wrem = win % (NW * NW);
  int wy = wrem / NW, wx = wrem % NW;
  int kstart = head_off + win * LK;
  u16* pw_ = plds + wid * 16 * PS;

  int j = tIdx * 16 + c;
  int ih = j / HWIN, iw = j % HWIN;
  int t = (wy * HWIN + ih) * W_ + wx * HWIN + iw;
  bf16x8 qa = *(const bf16x8*)&q[((size_t)n * HW_ + t) * 128 + head * 32 + g * 8];

  f32x4 sacc[NCT];
  #pragma unroll
  for (int ct = 0; ct < NCT; ++ct) {
    sacc[ct] = f32x4{0.f, 0.f, 0.f, 0.f};
    bf16x8 kf = *(const bf16x8*)&kb[(size_t)(kstart + ct * 16 + c) * 32 + g * 8];
    sacc[ct] = MFMA(qa, kf, sacc[ct]);
  }
  #pragma unroll
  for (int ct = 0; ct < NCT; ++ct)
    #pragma unroll
    for (int reg = 0; reg < 4; ++reg) sacc[ct][reg] *= SCALE_;
  #pragma unroll
  for (int reg = 0; reg < 4; ++reg) {
    float mx = -1e30f;
    #pragma unroll
    for (int ct = 0; ct < NCT; ++ct) mx = fmaxf(mx, sacc[ct][reg]);
    mx = fmaxf(mx, __shfl_xor(mx, 1, 64));
    mx = fmaxf(mx, __shfl_xor(mx, 2, 64));
    mx = fmaxf(mx, __shfl_xor(mx, 4, 64));
    mx = fmaxf(mx, __shfl_xor(mx, 8, 64));
    float sm = 0.f;
    #pragma unroll
    for (int ct = 0; ct < NCT; ++ct) {
      float e = __expf(sacc[ct][reg] - mx);
      sacc[ct][reg] = e;
      sm += e;
    }
    sm += __shfl_xor(sm, 1, 64);
    sm += __shfl_xor(sm, 2, 64);
    sm += __shfl_xor(sm, 4, 64);
    sm += __shfl_xor(sm, 8, 64);
    float inv = 1.0f / sm;
    #pragma unroll
    for (int ct = 0; ct < NCT; ++ct) sacc[ct][reg] *= inv;
  }
  #pragma unroll
  for (int ct = 0; ct < NCT; ++ct)
    #pragma unroll
    for (int reg = 0; reg < 4; ++reg)
      pw_[(g * 4 + reg) * PS + ct * 16 + c] = f2bf_rne(sacc[ct][reg]);
  f32x4 oacc[2] = {};
  #pragma unroll
  for (int st = 0; st < NST; ++st) {
    bf16x8 pa = *(const bf16x8*)&pw_[c * PS + st * 32 + g * 8];
    #pragma unroll
    for (int dt = 0; dt < 2; ++dt) {
      bf16x8 vf = *(const bf16x8*)&vbT[(size_t)kstart * 32 +
                                       (dt * 16 + c) * LK + st * 32 + g * 8];
      oacc[dt] = MFMA(pa, vf, oacc[dt]);
    }
  }
  #pragma unroll
  for (int reg = 0; reg < 4; ++reg) {
    int jo = tIdx * 16 + g * 4 + reg;
    int iho = jo / HWIN, iwo = jo % HWIN;
    int to = (wy * HWIN + iho) * W_ + wx * HWIN + iwo;
    float* op = cbuf + ((size_t)n * HW_ + to) * 128 + head * 32;
    op[c]      = oacc[0][reg];
    op[16 + c] = oacc[1][reg];
  }
}

__global__ __launch_bounds__(256) void attn_kernel(
    const u16* __restrict__ q, const u16* __restrict__ kb,
    const u16* __restrict__ vbT, float* __restrict__ cbuf) {
  int bid = blockIdx.x;
  if      (bid < 1024) attn_mfma_body<1, 256>(bid,        0, 0,    q, kb, vbT, cbuf);
  else if (bid < 2048) attn_mfma_body<2, 256>(bid - 1024, 1, 1024, q, kb, vbT, cbuf);
  else if (bid < 3072) attn_mfma_body<4, 64 >(bid - 2048, 2, 5120, q, kb, vbT, cbuf);
  else                 attn_mfma_body<8, 64 >(bid - 3072, 3, 9216, q, kb, vbT, cbuf);
}

// ---------------------------------------------------------------------------
extern "C" void kernel_launch(void* const* d_in, const int* in_sizes, int n_in,
                              void* d_out, int out_size, void* d_ws, size_t ws_size,
                              hipStream_t stream) {
  const float* inp = (const float*)d_in[0];
  const float* nw  = (const float*)d_in[1];
  const float* nb  = (const float*)d_in[2];
  const float* qw  = (const float*)d_in[3];
  const float* qb  = (const float*)d_in[4];
  const float* pw  = (const float*)d_in[29];
  const float* pb  = (const float*)d_in[30];

  float* ws   = (float*)d_ws;
  u16*   qb16 = (u16*)(ws + QB_OFF);
  float* y    = ws + Y_OFF;
  u16*   kb   = (u16*)(ws + KB_OFF);
  u16*   vbT  = (u16*)(ws + VT_OFF);
  float* part = ws + PART_OFF;
  u16*   wsp  = (u16*)(ws + WSP_OFF);
  u16*   whi  = wsp;
  u16*   wlo  = wsp + TOTW;
  u16*   inph = (u16*)(ws + INH_OFF);
  u16*   inpl = (u16*)(ws + INL_OFF);
  float* cbuf = (float*)d_out;

  // 0) split weights + input to bf16 hi/lo
  split_w_kernel<<<TOTW / 256, 256, 0, stream>>>(
      qw, pw, (const float*)d_in[5], (const float*)d_in[11],
      (const float*)d_in[17], (const float*)d_in[23],
      (const float*)d_in[9], (const float*)d_in[15],
      (const float*)d_in[21], (const float*)d_in[27], whi, wlo);
  presplit_kernel<<<8192, 256, 0, stream>>>(inp, inph, inpl);

  // 1) fused LN + Q projection (MFMA) -> bf16 q
  lnq_mfma_kernel<<<1024, 256, 0, stream>>>(inp, nw, nb, whi + OQW, wlo + OQW,
                                            qb, qb16);

  // 2) all 4 patch-embed convs in one launch (MFMA)
  conv_mfma_kernel<<<1024, 256, 0, stream>>>(inph, inpl, whi, wlo,
                                             (const float*)d_in[24], part, y);

  // 3) wide reduce of K-split partials + bias -> y (heads 1-3)
  reduce_kernel<<<2304, 256, 0, stream>>>(part, (const float*)d_in[6],
                                          (const float*)d_in[12],
                                          (const float*)d_in[18], y);

  // 4) fused LN + GELU + KV projection (MFMA)
  LnkvArgs la;
  la.lnw[0] = (const float*)d_in[7];  la.lnb[0] = (const float*)d_in[8];
  la.kvb[0] = (const float*)d_in[10];
  la.lnw[1] = (const float*)d_in[13]; la.lnb[1] = (const float*)d_in[14];
  la.kvb[1] = (const float*)d_in[16];
  la.lnw[2] = (const float*)d_in[19]; la.lnb[2] = (const float*)d_in[20];
  la.kvb[2] = (const float*)d_in[22];
  la.lnw[3] = (const float*)d_in[25]; la.lnb[3] = (const float*)d_in[26];
  la.kvb[3] = (const float*)d_in[28];
  lnkv_mfma_kernel<<<400, 256, 0, stream>>>(y, whi + OKV, wlo + OKV, la, kb, vbT);

  // 5) MFMA attention (per-wave P tile in LDS: 4 * 16 * 264 * 2 = 33792 B)
  attn_kernel<<<4096, 256, 33792, stream>>>(qb16, kb, vbT, cbuf);

  // 6) final projection, in place on d_out (MFMA)
  gemm128_mfma_kernel<<<1024, 256, 0, stream>>>(cbuf, whi + OPW, wlo + OPW, pb,
                                                (float*)d_out);
}

// Round 9
// 201.190 us; speedup vs baseline: 1.2863x; 1.0186x over previous
//
#include <hip/hip_runtime.h>
#include <math.h>

#define N_   4
#define C_   128
#define H_   128
#define W_   128
#define HW_  16384
#define SCALE_ 0.17677669529663687f   // 32^-0.5

typedef unsigned short u16;
typedef unsigned int   u32;
typedef __bf16 bf16x8 __attribute__((ext_vector_type(8)));
typedef float  f32x4  __attribute__((ext_vector_type(4)));

#define MFMA(a, b, c) __builtin_amdgcn_mfma_f32_16x16x32_bf16((a), (b), (c), 0, 0, 0)

// ---- ws float offsets -------------------------------------------------------
#define QB_OFF   0            // 4,194,304 floats (8,388,608 u16 bf16 q)
#define Y_OFF    4194304      // 1,638,400 (all heads, post-reduce + bias)
#define KB_OFF   5832704      //   409,600 floats (819,200 u16 bf16 K)
#define VT_OFF   6242304      //   409,600 floats (819,200 u16 bf16 V^T)
#define PART_OFF 6651904      // 3,145,728
#define WSP_OFF  9797632      //   868,352 floats (2 x 868,352 u16 hi+lo)
#define INH_OFF  10665984     // 4,194,304 floats (8,388,608 u16)
#define INL_OFF  14860288     // 4,194,304 floats
// total 19,054,592 floats = 76.2 MB

// split-weight region offsets (u16 units, within hi or lo half)
#define OQW 0
#define OPW 16384
#define OS1 32768
#define OS2 557056
#define OS3 688128
#define OS4 819200
#define OKV 851968
#define TOTW 868352

#define GS 520   // A-LDS kgroup stride in u16

// ---------------------------------------------------------------------------
__device__ __forceinline__ u16 f2bf_rne(float x) {
  unsigned u = __float_as_uint(x);
  return (u16)((u + 0x7FFFu + ((u >> 16) & 1u)) >> 16);
}
__device__ __forceinline__ void split2(float v, u16& h, u16& l) {
  unsigned u = __float_as_uint(v);
  unsigned hb = (u + 0x7FFFu + ((u >> 16) & 1u)) & 0xFFFF0000u;
  h = (u16)(hb >> 16);
  float lf = v - __uint_as_float(hb);
  l = f2bf_rne(lf);
}
__device__ __forceinline__ void split4(float4 v, ushort4& h, ushort4& l) {
  split2(v.x, h.x, l.x); split2(v.y, h.y, l.y);
  split2(v.z, h.z, l.z); split2(v.w, h.w, l.w);
}

// ---------------------------------------------------------------------------
// split weights fp32 -> bf16 hi/lo (all 10 weight matrices, concatenated)
// ---------------------------------------------------------------------------
__global__ __launch_bounds__(256) void split_w_kernel(
    const float* __restrict__ qw, const float* __restrict__ pw,
    const float* __restrict__ s1, const float* __restrict__ s2,
    const float* __restrict__ s3, const float* __restrict__ s4,
    const float* __restrict__ kv1, const float* __restrict__ kv2,
    const float* __restrict__ kv3, const float* __restrict__ kv4,
    u16* __restrict__ hi, u16* __restrict__ lo) {
  int idx = blockIdx.x * 256 + threadIdx.x;   // grid sized exactly TOTW/256
  const float* src; int off;
  if      (idx < OPW)  { src = qw; off = idx; }
  else if (idx < OS1)  { src = pw; off = idx - OPW; }
  else if (idx < OS2)  { src = s1; off = idx - OS1; }
  else if (idx < OS3)  { src = s2; off = idx - OS2; }
  else if (idx < OS4)  { src = s3; off = idx - OS3; }
  else if (idx < OKV)  { src = s4; off = idx - OS4; }
  else {
    int j = idx - OKV;
    int h = j >> 12; off = j & 4095;
    src = (h == 0) ? kv1 : (h == 1) ? kv2 : (h == 2) ? kv3 : kv4;
  }
  u16 h, l; split2(src[off], h, l);
  hi[idx] = h; lo[idx] = l;
}

// ---------------------------------------------------------------------------
// pre-split input fp32 -> bf16 hi/lo (memory-bound pass)
// ---------------------------------------------------------------------------
__global__ __launch_bounds__(256) void presplit_kernel(
    const float* __restrict__ inp, u16* __restrict__ h, u16* __restrict__ l) {
  int idx = blockIdx.x * 256 + threadIdx.x;   // float4 units; grid = 8192
  float4 v = *(const float4*)&inp[(size_t)idx * 4];
  ushort4 h4, l4; split4(v, h4, l4);
  *(ushort4*)&h[(size_t)idx * 4] = h4;
  *(ushort4*)&l[(size_t)idx * 4] = l4;
}

// ---------------------------------------------------------------------------
// fused LayerNorm(128) + Q-projection via bf16x3 MFMA -> bf16 q out
// ---------------------------------------------------------------------------
__global__ __launch_bounds__(256) void lnq_mfma_kernel(
    const float* __restrict__ inp, const float* __restrict__ nw,
    const float* __restrict__ nb, const u16* __restrict__ wh,
    const u16* __restrict__ wl, const float* __restrict__ qb,
    u16* __restrict__ q) {
  __shared__ float xs[128 * 65];
  __shared__ float ps[4][64], ps2[4][64];
  __shared__ float mu[64], rs[64];
  __shared__ __align__(16) u16 xsh[16 * GS];
  __shared__ __align__(16) u16 xsl[16 * GS];
  int bid = blockIdx.x, n = bid >> 8, t0 = (bid & 255) * 64;
  const float* xb = inp + (size_t)n * C_ * HW_;
  for (int idx = threadIdx.x; idx < 8192; idx += 256) {
    int c = idx >> 6, tt = idx & 63;
    xs[c * 65 + tt] = xb[c * HW_ + t0 + tt];
  }
  __syncthreads();
  {
    int tt = threadIdx.x & 63, part = threadIdx.x >> 6;
    float s = 0.f, s2 = 0.f;
    for (int c = part * 32; c < part * 32 + 32; ++c) {
      float v = xs[c * 65 + tt];
      s += v; s2 += v * v;
    }
    ps[part][tt] = s; ps2[part][tt] = s2;
  }
  __syncthreads();
  if (threadIdx.x < 64) {
    int tt = threadIdx.x;
    float s  = ps[0][tt] + ps[1][tt] + ps[2][tt] + ps[3][tt];
    float s2 = ps2[0][tt] + ps2[1][tt] + ps2[2][tt] + ps2[3][tt];
    float m = s * (1.0f / 128.0f);
    float v = s2 * (1.0f / 128.0f) - m * m;
    mu[tt] = m; rs[tt] = rsqrtf(v + 1e-5f);
  }
  __syncthreads();
  for (int idx = threadIdx.x; idx < 8192; idx += 256) {
    int c = idx & 127, tt = idx >> 7;
    float v = (xs[c * 65 + tt] - mu[tt]) * rs[tt] * nw[c] + nb[c];
    u16 h, l; split2(v, h, l);
    int o = (c >> 3) * GS + tt * 8 + (c & 7);
    xsh[o] = h; xsl[o] = l;
  }
  __syncthreads();
  int wid = threadIdx.x >> 6, lane = threadIdx.x & 63;
  int r = lane & 15, g = lane >> 4;
  f32x4 acc[8] = {};
  #pragma unroll
  for (int kk = 0; kk < 4; ++kk) {
    bf16x8 ah = *(const bf16x8*)&xsh[(kk * 4 + g) * GS + (wid * 16 + r) * 8];
    bf16x8 al = *(const bf16x8*)&xsl[(kk * 4 + g) * GS + (wid * 16 + r) * 8];
    #pragma unroll
    for (int ct = 0; ct < 8; ++ct) {
      int o = ct * 16 + r;
      bf16x8 bh = *(const bf16x8*)&wh[o * 128 + kk * 32 + g * 8];
      bf16x8 bl = *(const bf16x8*)&wl[o * 128 + kk * 32 + g * 8];
      acc[ct] = MFMA(ah, bh, acc[ct]);
      acc[ct] = MFMA(ah, bl, acc[ct]);
      acc[ct] = MFMA(al, bh, acc[ct]);
    }
  }
  #pragma unroll
  for (int ct = 0; ct < 8; ++ct) {
    int col = ct * 16 + r;
    #pragma unroll
    for (int reg = 0; reg < 4; ++reg) {
      int row = wid * 16 + g * 4 + reg;
      q[((size_t)n * HW_ + t0 + row) * 128 + col] = f2bf_rne(acc[ct][reg] + qb[col]);
    }
  }
}

// ---------------------------------------------------------------------------
// generic 128-K GEMM via bf16x3 MFMA (final projection, in-place safe)
// ---------------------------------------------------------------------------
__global__ __launch_bounds__(256) void gemm128_mfma_kernel(
    const float* __restrict__ x, const u16* __restrict__ wh,
    const u16* __restrict__ wl, const float* __restrict__ b,
    float* __restrict__ out) {
  __shared__ __align__(16) u16 xsh[16 * GS];
  __shared__ __align__(16) u16 xsl[16 * GS];
  int r0 = blockIdx.x * 64;
  #pragma unroll
  for (int it = 0; it < 8; ++it) {
    int idx4 = it * 256 + threadIdx.x;       // 2048 float4s
    int row = idx4 >> 5, cg = idx4 & 31;
    float4 v = *(const float4*)&x[(size_t)(r0 + row) * 128 + cg * 4];
    ushort4 h4, l4; split4(v, h4, l4);
    int o = (cg >> 1) * GS + row * 8 + (cg & 1) * 4;
    *(ushort4*)&xsh[o] = h4; *(ushort4*)&xsl[o] = l4;
  }
  __syncthreads();
  int wid = threadIdx.x >> 6, lane = threadIdx.x & 63;
  int r = lane & 15, g = lane >> 4;
  f32x4 acc[8] = {};
  #pragma unroll
  for (int kk = 0; kk < 4; ++kk) {
    bf16x8 ah = *(const bf16x8*)&xsh[(kk * 4 + g) * GS + (wid * 16 + r) * 8];
    bf16x8 al = *(const bf16x8*)&xsl[(kk * 4 + g) * GS + (wid * 16 + r) * 8];
    #pragma unroll
    for (int ct = 0; ct < 8; ++ct) {
      int o = ct * 16 + r;
      bf16x8 bh = *(const bf16x8*)&wh[o * 128 + kk * 32 + g * 8];
      bf16x8 bl = *(const bf16x8*)&wl[o * 128 + kk * 32 + g * 8];
      acc[ct] = MFMA(ah, bh, acc[ct]);
      acc[ct] = MFMA(ah, bl, acc[ct]);
      acc[ct] = MFMA(al, bh, acc[ct]);
    }
  }
  #pragma unroll
  for (int ct = 0; ct < 8; ++ct) {
    int col = ct * 16 + r;
    #pragma unroll
    for (int reg = 0; reg < 4; ++reg) {
      int row = r0 + wid * 16 + g * 4 + reg;
      out[(size_t)row * 128 + col] = acc[ct][reg] + b[col];
    }
  }
}

// ---------------------------------------------------------------------------
// conv-as-GEMM, bf16x3 MFMA, pre-split input, LDS-staged weights, pipelined.
// ---------------------------------------------------------------------------
template <int P, int NW, int SEG>
__device__ __forceinline__ void conv_body(
    int mblk, int seg, const u16* __restrict__ inph, const u16* __restrict__ inpl,
    const u16* __restrict__ wh, const u16* __restrict__ wl,
    float* __restrict__ dst, const float* __restrict__ bias,
    u16* ash, u16* asl, u16* wsh, u16* wsl) {
  constexpr int K    = 128 * P * P;
  constexpr int KSEG = K / SEG;
  constexpr int NT   = KSEG / 32;
  constexpr int HWIN = H_ / NW;
  constexpr int G    = HWIN / P;
  constexpr int L    = G * G;
  constexpr int M    = 4 * NW * NW * L;
  constexpr int LGL  = (L == 256) ? 8 : 6;
  constexpr int LGG  = (G == 16) ? 4 : 3;
  constexpr int LGNW = (NW == 8) ? 3 : (NW == 4) ? 2 : (NW == 2) ? 1 : 0;
  constexpr int LGP  = (P == 8) ? 3 : (P == 4) ? 2 : 1;
  constexpr int LGP2 = 2 * LGP;
  int tid = threadIdx.x, wid = tid >> 6, lane = tid & 63;
  int r = lane & 15, g = lane >> 4;
  int t0 = mblk * 64;
  int kq = tid & 7;
  int kbase = seg * KSEG;

  size_t rbase[2];
  #pragma unroll
  for (int hh = 0; hh < 2; ++hh) {
    int row = (tid >> 3) + hh * 32;
    int tglob = t0 + row;
    int bwin = tglob >> LGL;
    int loc  = tglob & (L - 1);
    int n    = bwin >> (2 * LGNW);
    int wrem = bwin & (NW * NW - 1);
    int wy = wrem >> LGNW, wx = wrem & (NW - 1);
    int oh = loc >> LGG,   ow = loc & (G - 1);
    rbase[hh] = (size_t)n * C_ * HW_ + (size_t)(wy * HWIN + oh * P) * W_ +
                wx * HWIN + ow * P;
  }
  int ldso = (kq >> 1) * GS + (tid >> 3) * 8 + (kq & 1) * 4;
  int wo = tid >> 2, wpart = tid & 3;
  const u16* wrowh = wh + (size_t)wo * K + kbase + wpart * 8;
  const u16* wrowl = wl + (size_t)wo * K + kbase + wpart * 8;
  int wlo_ = wo * 40 + wpart * 8;

  f32x4 acc[4] = {};
  ushort4 avh[2], avl[2];
  uint4 wvh, wvl;

  auto LOADSTEP = [&](int kt) {
    int k = kbase + kt * 32 + kq * 4;
    int ci = k >> LGP2;
    int wp = k & (P * P - 1);
    if constexpr (P >= 4) {
      int kh = wp >> LGP, kw = wp & (P - 1);
      size_t koff = (size_t)ci * HW_ + kh * W_ + kw;
      #pragma unroll
      for (int hh = 0; hh < 2; ++hh) {
        avh[hh] = *(const ushort4*)&inph[rbase[hh] + koff];
        avl[hh] = *(const ushort4*)&inpl[rbase[hh] + koff];
      }
    } else {
      size_t koff = (size_t)ci * HW_;
      #pragma unroll
      for (int hh = 0; hh < 2; ++hh) {
        union { uint2 u; ushort4 s; } cv;
        cv.u.x = *(const u32*)&inph[rbase[hh] + koff];
        cv.u.y = *(const u32*)&inph[rbase[hh] + koff + W_];
        avh[hh] = cv.s;
        cv.u.x = *(const u32*)&inpl[rbase[hh] + koff];
        cv.u.y = *(const u32*)&inpl[rbase[hh] + koff + W_];
        avl[hh] = cv.s;
      }
    }
    wvh = *(const uint4*)(wrowh + kt * 32);
    wvl = *(const uint4*)(wrowl + kt * 32);
  };

  LOADSTEP(0);
  for (int kt = 0; kt < NT; ++kt) {
    __syncthreads();
    *(ushort4*)&ash[ldso]       = avh[0];
    *(ushort4*)&ash[ldso + 256] = avh[1];
    *(ushort4*)&asl[ldso]       = avl[0];
    *(ushort4*)&asl[ldso + 256] = avl[1];
    *(uint4*)&wsh[wlo_] = wvh;
    *(uint4*)&wsl[wlo_] = wvl;
    __syncthreads();
    if (kt + 1 < NT) LOADSTEP(kt + 1);
    bf16x8 ahf = *(const bf16x8*)&ash[g * GS + (wid * 16 + r) * 8];
    bf16x8 alf = *(const bf16x8*)&asl[g * GS + (wid * 16 + r) * 8];
    #pragma unroll
    for (int ct = 0; ct < 4; ++ct) {
      bf16x8 bh = *(const bf16x8*)&wsh[(ct * 16 + r) * 40 + g * 8];
      bf16x8 bl = *(const bf16x8*)&wsl[(ct * 16 + r) * 40 + g * 8];
      acc[ct] = MFMA(ahf, bh, acc[ct]);
      acc[ct] = MFMA(ahf, bl, acc[ct]);
      acc[ct] = MFMA(alf, bh, acc[ct]);
    }
  }
  #pragma unroll
  for (int ct = 0; ct < 4; ++ct) {
    int o = ct * 16 + r;
    #pragma unroll
    for (int reg = 0; reg < 4; ++reg) {
      int row = t0 + wid * 16 + g * 4 + reg;
      if constexpr (SEG == 1) dst[(size_t)row * 64 + o] = acc[ct][reg] + bias[o];
      else                    dst[((size_t)seg * M + row) * 64 + o] = acc[ct][reg];
    }
  }
}

__global__ __launch_bounds__(256) void conv_mfma_kernel(
    const u16* __restrict__ inph, const u16* __restrict__ inpl,
    const u16* __restrict__ wsh_g, const u16* __restrict__ wsl_g,
    const float* __restrict__ b4, float* __restrict__ part,
    float* __restrict__ y) {
  __shared__ __align__(16) u16 ash[4 * GS];
  __shared__ __align__(16) u16 asl[4 * GS];
  __shared__ __align__(16) u16 wsh[64 * 40];
  __shared__ __align__(16) u16 wsl[64 * 40];
  int bid = blockIdx.x;
  if (bid < 256) {            // head1: 16 mblk x 16 seg
    conv_body<8, 1, 16>(bid & 15, bid >> 4, inph, inpl, wsh_g + OS1, wsl_g + OS1,
                        part, nullptr, ash, asl, wsh, wsl);
  } else if (bid < 512) {     // head2: 64 mblk x 4 seg
    int lb = bid - 256;
    conv_body<4, 2, 4>(lb & 63, lb >> 6, inph, inpl, wsh_g + OS2, wsl_g + OS2,
                       part + 1048576, nullptr, ash, asl, wsh, wsl);
  } else if (bid < 768) {     // head3: 64 mblk x 4 seg
    int lb = bid - 512;
    conv_body<4, 4, 4>(lb & 63, lb >> 6, inph, inpl, wsh_g + OS3, wsl_g + OS3,
                       part + 2097152, nullptr, ash, asl, wsh, wsl);
  } else {                    // head4: 256 mblk, direct to y
    conv_body<2, 8, 1>(bid - 768, 0, inph, inpl, wsh_g + OS4, wsl_g + OS4,
                       y + (size_t)9216 * 64, b4, ash, asl, wsh, wsl);
  }
}

// reduce K-split partials + conv bias for heads 1-3 -> y
__global__ __launch_bounds__(256) void reduce_kernel(
    const float* __restrict__ part, const float* __restrict__ b1,
    const float* __restrict__ b2, const float* __restrict__ b3,
    float* __restrict__ y) {
  int idx = blockIdx.x * 256 + threadIdx.x;   // grid exactly 589824/256 = 2304
  int tg = idx >> 6, o = idx & 63;
  float s;
  if (tg < 1024) {
    s = b1[o];
    #pragma unroll
    for (int sg = 0; sg < 16; ++sg) s += part[((size_t)sg * 1024 + tg) * 64 + o];
  } else if (tg < 5120) {
    int t = tg - 1024;
    const float* p2 = part + 1048576;
    s = b2[o];
    #pragma unroll
    for (int sg = 0; sg < 4; ++sg) s += p2[((size_t)sg * 4096 + t) * 64 + o];
  } else {
    int t = tg - 5120;
    const float* p3 = part + 2097152;
    s = b3[o];
    #pragma unroll
    for (int sg = 0; sg < 4; ++sg) s += p3[((size_t)sg * 4096 + t) * 64 + o];
  }
  y[(size_t)tg * 64 + o] = s;
}

// ---------------------------------------------------------------------------
// fused LN(64) + exact GELU + KV projection (MFMA). 64 tokens/block, 400 blocks.
// K out bf16 [token][32]; V out bf16 window-transposed [d][k].
// ---------------------------------------------------------------------------
struct LnkvArgs { const float* lnw[4]; const float* lnb[4]; const float* kvb[4]; };

__global__ __launch_bounds__(256) void lnkv_mfma_kernel(
    const float* __restrict__ y, const u16* __restrict__ kvwh,
    const u16* __restrict__ kvwl, LnkvArgs a,
    u16* __restrict__ kb, u16* __restrict__ vbT) {
  __shared__ float ych[64 * 65];
  __shared__ __align__(16) u16 ash[8 * GS];
  __shared__ __align__(16) u16 asl[8 * GS];
  int bid = blockIdx.x, tid = threadIdx.x;
  int tb = bid * 64;
  int h  = (tb < 1024) ? 0 : (tb < 5120) ? 1 : (tb < 9216) ? 2 : 3;
  int hb = (h == 0) ? 0 : (h == 1) ? 1024 : (h == 2) ? 5120 : 9216;
  // stage 64x64 token tile (coalesced float4)
  #pragma unroll
  for (int it = 0; it < 4; ++it) {
    int i4 = it * 256 + tid;            // 1024 float4s
    int row = i4 >> 4, cg = i4 & 15;
    float4 v = *(const float4*)&y[(size_t)(tb + row) * 64 + cg * 4];
    *(float4*)&ych[row * 65 + cg * 4] = v;
  }
  __syncthreads();
  // LN + GELU, 4 threads per token, split to A-frag LDS
  {
    int tt = tid >> 2, p = tid & 3;
    const float* xr = &ych[tt * 65 + p * 16];
    float s = 0.f, s2 = 0.f;
    #pragma unroll
    for (int i = 0; i < 16; ++i) { float v = xr[i]; s += v; s2 += v * v; }
    s  += __shfl_xor(s, 1, 64);  s  += __shfl_xor(s, 2, 64);
    s2 += __shfl_xor(s2, 1, 64); s2 += __shfl_xor(s2, 2, 64);
    float mean = s * (1.0f / 64.0f);
    float var  = s2 * (1.0f / 64.0f) - mean * mean;
    float rstd = rsqrtf(var + 1e-5f);
    const float* lnw = a.lnw[h];
    const float* lnb = a.lnb[h];
    #pragma unroll
    for (int i = 0; i < 16; ++i) {
      int ch = p * 16 + i;
      float xn = (xr[i] - mean) * rstd * lnw[ch] + lnb[ch];
      float gg = 0.5f * xn * (1.0f + erff(xn * 0.70710678118654752f));
      u16 hh, ll; split2(gg, hh, ll);
      int o = (ch >> 3) * GS + tt * 8 + (ch & 7);
      ash[o] = hh; asl[o] = ll;
    }
  }
  __syncthreads();
  int wid = tid >> 6, lane = tid & 63, r = lane & 15, g = lane >> 4;
  const u16* wbh = kvwh + h * 4096;
  const u16* wbl = kvwl + h * 4096;
  f32x4 acc[4] = {};
  #pragma unroll
  for (int kk = 0; kk < 2; ++kk) {
    bf16x8 ah = *(const bf16x8*)&ash[(kk * 4 + g) * GS + (wid * 16 + r) * 8];
    bf16x8 al = *(const bf16x8*)&asl[(kk * 4 + g) * GS + (wid * 16 + r) * 8];
    #pragma unroll
    for (int ct = 0; ct < 4; ++ct) {
      bf16x8 bh = *(const bf16x8*)&wbh[(ct * 16 + r) * 64 + kk * 32 + g * 8];
      bf16x8 bl = *(const bf16x8*)&wbl[(ct * 16 + r) * 64 + kk * 32 + g * 8];
      acc[ct] = MFMA(ah, bh, acc[ct]);
      acc[ct] = MFMA(ah, bl, acc[ct]);
      acc[ct] = MFMA(al, bh, acc[ct]);
    }
  }
  const float* kvb = a.kvb[h];
  int lk = (h < 2) ? 256 : 64;
  #pragma unroll
  for (int ct = 0; ct < 4; ++ct) {
    int o = ct * 16 + r;
    float bias = kvb[o];
    #pragma unroll
    for (int reg = 0; reg < 4; ++reg) {
      int row = wid * 16 + g * 4 + reg;
      int tg  = tb + row;
      float v = acc[ct][reg] + bias;
      if (o < 32) {
        kb[(size_t)tg * 32 + o] = f2bf_rne(v);
      } else {
        int dd = o - 32;
        int kl = (tg - hb) & (lk - 1);
        int wstart = tg - kl;
        vbT[(size_t)wstart * 32 + dd * lk + kl] = f2bf_rne(v);
      }
    }
  }
}

// ---------------------------------------------------------------------------
// MFMA attention v2: block = 256 queries (4 waves x 4 tiles), K/V staged in LDS
// once per block; per-st P scratch (double-buffered) instead of full P tile.
// ---------------------------------------------------------------------------
template <int NW, int LK>
__device__ __forceinline__ void attn_v2_body(
    int bid, int head, int head_off, const u16* __restrict__ q,
    const u16* __restrict__ kb, const u16* __restrict__ vbT,
    float* __restrict__ cbuf) {
  constexpr int HWIN = H_ / NW;
  constexpr int LQ   = HWIN * HWIN;
  constexpr int BPW  = LQ / 256;          // blocks per window
  constexpr int NCT  = LK / 16;
  constexpr int NST  = LK / 32;
  constexpr int KS   = 40;                // K row stride (u16), 80B
  constexpr int VS   = LK + 8;            // V row stride (u16)
  extern __shared__ __align__(16) u16 alds[];
  u16* klds = alds;                       // [LK][KS]
  u16* vlds = alds + LK * KS;             // [32][VS]
  u16* plds = vlds + 32 * VS;             // 4 waves x 2 bufs x 16 x KS
  int tid = threadIdx.x, wid = tid >> 6, lane = tid & 63;
  int g = lane >> 4, c = lane & 15;
  int win  = bid / BPW;
  int n = win / (NW * NW);
  int wrem = win % (NW * NW);
  int wy = wrem / NW, wx = wrem % NW;
  int kstart = head_off + win * LK;

  // cooperative K/V staging (coalesced 16B chunks)
  const u16* kgl = kb  + (size_t)kstart * 32;
  const u16* vgl = vbT + (size_t)kstart * 32;
  #pragma unroll
  for (int ch = tid; ch < LK * 4; ch += 256) {
    int key = ch >> 2, gg = ch & 3;
    *(uint4*)&klds[key * KS + gg * 8] = *(const uint4*)&kgl[ch * 8];
  }
  #pragma unroll
  for (int ch = tid; ch < LK * 4; ch += 256) {   // 32*LK/8 == LK*4
    int d = ch / (LK / 8), pos = ch % (LK / 8);
    *(uint4*)&vlds[d * VS + pos * 8] = *(const uint4*)&vgl[ch * 8];
  }
  __syncthreads();

  u16* pw0 = plds + wid * 2 * 16 * KS;
  f32x4 zero4 = {0.f, 0.f, 0.f, 0.f};

  #pragma unroll
  for (int tq = 0; tq < 4; ++tq) {
    int tIdx = (bid % BPW) * 16 + wid * 4 + tq;
    int j = tIdx * 16 + c;
    int ih = j / HWIN, iw = j % HWIN;
    int t = (wy * HWIN + ih) * W_ + wx * HWIN + iw;
    bf16x8 qa = *(const bf16x8*)&q[((size_t)n * HW_ + t) * 128 + head * 32 + g * 8];

    // S = Q K^T from LDS K
    f32x4 sacc[NCT];
    #pragma unroll
    for (int ct = 0; ct < NCT; ++ct) {
      bf16x8 kf = *(const bf16x8*)&klds[(ct * 16 + c) * KS + g * 8];
      sacc[ct] = MFMA(qa, kf, zero4);
    }
    #pragma unroll
    for (int ct = 0; ct < NCT; ++ct)
      #pragma unroll
      for (int reg = 0; reg < 4; ++reg) sacc[ct][reg] *= SCALE_;
    // softmax per row (row = g*4+reg; cols spread over ct regs x 16 lanes)
    #pragma unroll
    for (int reg = 0; reg < 4; ++reg) {
      float mx = -1e30f;
      #pragma unroll
      for (int ct = 0; ct < NCT; ++ct) mx = fmaxf(mx, sacc[ct][reg]);
      mx = fmaxf(mx, __shfl_xor(mx, 1, 64));
      mx = fmaxf(mx, __shfl_xor(mx, 2, 64));
      mx = fmaxf(mx, __shfl_xor(mx, 4, 64));
      mx = fmaxf(mx, __shfl_xor(mx, 8, 64));
      float sm = 0.f;
      #pragma unroll
      for (int ct = 0; ct < NCT; ++ct) {
        float e = __expf(sacc[ct][reg] - mx);
        sacc[ct][reg] = e;
        sm += e;
      }
      sm += __shfl_xor(sm, 1, 64);
      sm += __shfl_xor(sm, 2, 64);
      sm += __shfl_xor(sm, 4, 64);
      sm += __shfl_xor(sm, 8, 64);
      float inv = 1.0f / sm;
      #pragma unroll
      for (int ct = 0; ct < NCT; ++ct) sacc[ct][reg] *= inv;
    }
    // PV with per-st P scratch (16x32, double-buffered, wave-private)
    f32x4 oacc[2] = {};
    #pragma unroll
    for (int st = 0; st < NST; ++st) {
      u16* pw_ = pw0 + (st & 1) * 16 * KS;
      #pragma unroll
      for (int ct2 = 0; ct2 < 2; ++ct2) {
        int ct = st * 2 + ct2;
        #pragma unroll
        for (int reg = 0; reg < 4; ++reg)
          pw_[(g * 4 + reg) * KS + ct2 * 16 + c] = f2bf_rne(sacc[ct][reg]);
      }
      bf16x8 pa = *(const bf16x8*)&pw_[c * KS + g * 8];
      #pragma unroll
      for (int dt = 0; dt < 2; ++dt) {
        bf16x8 vf = *(const bf16x8*)&vlds[(dt * 16 + c) * VS + st * 32 + g * 8];
        oacc[dt] = MFMA(pa, vf, oacc[dt]);
      }
    }
    // write O (C layout: col=c -> d, row=g*4+reg -> q local)
    #pragma unroll
    for (int reg = 0; reg < 4; ++reg) {
      int jo = tIdx * 16 + g * 4 + reg;
      int iho = jo / HWIN, iwo = jo % HWIN;
      int to = (wy * HWIN + iho) * W_ + wx * HWIN + iwo;
      float* op = cbuf + ((size_t)n * HW_ + to) * 128 + head * 32;
      op[c]      = oacc[0][reg];
      op[16 + c] = oacc[1][reg];
    }
  }
}

__global__ __launch_bounds__(256) void attn01_kernel(
    const u16* __restrict__ q, const u16* __restrict__ kb,
    const u16* __restrict__ vbT, float* __restrict__ cbuf) {
  int bid = blockIdx.x;
  if (bid < 256) attn_v2_body<1, 256>(bid,       0, 0,    q, kb, vbT, cbuf);
  else           attn_v2_body<2, 256>(bid - 256, 1, 1024, q, kb, vbT, cbuf);
}

__global__ __launch_bounds__(256) void attn23_kernel(
    const u16* __restrict__ q, const u16* __restrict__ kb,
    const u16* __restrict__ vbT, float* __restrict__ cbuf) {
  int bid = blockIdx.x;
  if (bid < 256) attn_v2_body<4, 64>(bid,       2, 5120, q, kb, vbT, cbuf);
  else           attn_v2_body<8, 64>(bid - 256, 3, 9216, q, kb, vbT, cbuf);
}

// ---------------------------------------------------------------------------
extern "C" void kernel_launch(void* const* d_in, const int* in_sizes, int n_in,
                              void* d_out, int out_size, void* d_ws, size_t ws_size,
                              hipStream_t stream) {
  const float* inp = (const float*)d_in[0];
  const float* nw  = (const float*)d_in[1];
  const float* nb  = (const float*)d_in[2];
  const float* qw  = (const float*)d_in[3];
  const float* qb  = (const float*)d_in[4];
  const float* pw  = (const float*)d_in[29];
  const float* pb  = (const float*)d_in[30];

  float* ws   = (float*)d_ws;
  u16*   qb16 = (u16*)(ws + QB_OFF);
  float* y    = ws + Y_OFF;
  u16*   kb   = (u16*)(ws + KB_OFF);
  u16*   vbT  = (u16*)(ws + VT_OFF);
  float* part = ws + PART_OFF;
  u16*   wsp  = (u16*)(ws + WSP_OFF);
  u16*   whi  = wsp;
  u16*   wlo  = wsp + TOTW;
  u16*   inph = (u16*)(ws + INH_OFF);
  u16*   inpl = (u16*)(ws + INL_OFF);
  float* cbuf = (float*)d_out;

  // 0) split weights + input to bf16 hi/lo
  split_w_kernel<<<TOTW / 256, 256, 0, stream>>>(
      qw, pw, (const float*)d_in[5], (const float*)d_in[11],
      (const float*)d_in[17], (const float*)d_in[23],
      (const float*)d_in[9], (const float*)d_in[15],
      (const float*)d_in[21], (const float*)d_in[27], whi, wlo);
  presplit_kernel<<<8192, 256, 0, stream>>>(inp, inph, inpl);

  // 1) fused LN + Q projection (MFMA) -> bf16 q
  lnq_mfma_kernel<<<1024, 256, 0, stream>>>(inp, nw, nb, whi + OQW, wlo + OQW,
                                            qb, qb16);

  // 2) all 4 patch-embed convs in one launch (MFMA)
  conv_mfma_kernel<<<1024, 256, 0, stream>>>(inph, inpl, whi, wlo,
                                             (const float*)d_in[24], part, y);

  // 3) wide reduce of K-split partials + bias -> y (heads 1-3)
  reduce_kernel<<<2304, 256, 0, stream>>>(part, (const float*)d_in[6],
                                          (const float*)d_in[12],
                                          (const float*)d_in[18], y);

  // 4) fused LN + GELU + KV projection (MFMA)
  LnkvArgs la;
  la.lnw[0] = (const float*)d_in[7];  la.lnb[0] = (const float*)d_in[8];
  la.kvb[0] = (const float*)d_in[10];
  la.lnw[1] = (const float*)d_in[13]; la.lnb[1] = (const float*)d_in[14];
  la.kvb[1] = (const float*)d_in[16];
  la.lnw[2] = (const float*)d_in[19]; la.lnb[2] = (const float*)d_in[20];
  la.kvb[2] = (const float*)d_in[22];
  la.lnw[3] = (const float*)d_in[25]; la.lnb[3] = (const float*)d_in[26];
  la.kvb[3] = (const float*)d_in[28];
  lnkv_mfma_kernel<<<400, 256, 0, stream>>>(y, whi + OKV, wlo + OKV, la, kb, vbT);

  // 5) MFMA attention v2
  // heads 0,1: LDS = 256*40 + 32*264 + 4*2*16*40 (u16) = 47616 B
  attn01_kernel<<<512, 256, 47616, stream>>>(qb16, kb, vbT, cbuf);
  // heads 2,3: LDS = 64*40 + 32*72 + 4*2*16*40 (u16) = 19968 B
  attn23_kernel<<<512, 256, 19968, stream>>>(qb16, kb, vbT, cbuf);

  // 6) final projection, in place on d_out (MFMA)
  gemm128_mfma_kernel<<<1024, 256, 0, stream>>>(cbuf, whi + OPW, wlo + OPW, pb,
                                                (float*)d_out);
}

// Round 10
// 199.245 us; speedup vs baseline: 1.2989x; 1.0098x over previous
//
#include <hip/hip_runtime.h>
#include <math.h>

#define N_   4
#define C_   128
#define H_   128
#define W_   128
#define HW_  16384
#define SCALE_ 0.17677669529663687f   // 32^-0.5

typedef unsigned short u16;
typedef unsigned int   u32;
typedef __bf16 bf16x8 __attribute__((ext_vector_type(8)));
typedef float  f32x4  __attribute__((ext_vector_type(4)));

#define MFMA(a, b, c) __builtin_amdgcn_mfma_f32_16x16x32_bf16((a), (b), (c), 0, 0, 0)

// ---- ws float offsets -------------------------------------------------------
#define QB_OFF   0            // 4,194,304 floats (8,388,608 u16 bf16 q)
#define Y_OFF    4194304      // 1,638,400 (all heads, post-reduce + bias)
#define KB_OFF   5832704      //   409,600 floats (819,200 u16 bf16 K)
#define VT_OFF   6242304      //   409,600 floats (819,200 u16 bf16 V^T)
#define PART_OFF 6651904      // 3,145,728
#define WSP_OFF  9797632      //   868,352 floats (2 x 868,352 u16 hi+lo)
#define INH_OFF  10665984     // 4,194,304 floats (8,388,608 u16)
#define INL_OFF  14860288     // 4,194,304 floats
// total 19,054,592 floats = 76.2 MB

// split-weight region offsets (u16 units, within hi or lo half)
#define OQW 0
#define OPW 16384
#define OS1 32768
#define OS2 557056
#define OS3 688128
#define OS4 819200
#define OKV 851968
#define TOTW 868352

#define GS  520    // A-LDS kgroup stride (64-row tiles), u16
#define GSA 1032   // A-LDS kgroup stride (128-row conv tiles), u16

// ---------------------------------------------------------------------------
__device__ __forceinline__ u16 f2bf_rne(float x) {
  unsigned u = __float_as_uint(x);
  return (u16)((u + 0x7FFFu + ((u >> 16) & 1u)) >> 16);
}
__device__ __forceinline__ void split2(float v, u16& h, u16& l) {
  unsigned u = __float_as_uint(v);
  unsigned hb = (u + 0x7FFFu + ((u >> 16) & 1u)) & 0xFFFF0000u;
  h = (u16)(hb >> 16);
  float lf = v - __uint_as_float(hb);
  l = f2bf_rne(lf);
}
__device__ __forceinline__ void split4(float4 v, ushort4& h, ushort4& l) {
  split2(v.x, h.x, l.x); split2(v.y, h.y, l.y);
  split2(v.z, h.z, l.z); split2(v.w, h.w, l.w);
}

// ---------------------------------------------------------------------------
// split weights fp32 -> bf16 hi/lo (all 10 weight matrices, concatenated)
// ---------------------------------------------------------------------------
__global__ __launch_bounds__(256) void split_w_kernel(
    const float* __restrict__ qw, const float* __restrict__ pw,
    const float* __restrict__ s1, const float* __restrict__ s2,
    const float* __restrict__ s3, const float* __restrict__ s4,
    const float* __restrict__ kv1, const float* __restrict__ kv2,
    const float* __restrict__ kv3, const float* __restrict__ kv4,
    u16* __restrict__ hi, u16* __restrict__ lo) {
  int idx = blockIdx.x * 256 + threadIdx.x;   // grid sized exactly TOTW/256
  const float* src; int off;
  if      (idx < OPW)  { src = qw; off = idx; }
  else if (idx < OS1)  { src = pw; off = idx - OPW; }
  else if (idx < OS2)  { src = s1; off = idx - OS1; }
  else if (idx < OS3)  { src = s2; off = idx - OS2; }
  else if (idx < OS4)  { src = s3; off = idx - OS3; }
  else if (idx < OKV)  { src = s4; off = idx - OS4; }
  else {
    int j = idx - OKV;
    int h = j >> 12; off = j & 4095;
    src = (h == 0) ? kv1 : (h == 1) ? kv2 : (h == 2) ? kv3 : kv4;
  }
  u16 h, l; split2(src[off], h, l);
  hi[idx] = h; lo[idx] = l;
}

// ---------------------------------------------------------------------------
// pre-split input fp32 -> bf16 hi/lo (memory-bound pass)
// ---------------------------------------------------------------------------
__global__ __launch_bounds__(256) void presplit_kernel(
    const float* __restrict__ inp, u16* __restrict__ h, u16* __restrict__ l) {
  int idx = blockIdx.x * 256 + threadIdx.x;   // float4 units; grid = 8192
  float4 v = *(const float4*)&inp[(size_t)idx * 4];
  ushort4 h4, l4; split4(v, h4, l4);
  *(ushort4*)&h[(size_t)idx * 4] = h4;
  *(ushort4*)&l[(size_t)idx * 4] = l4;
}

// ---------------------------------------------------------------------------
// fused LayerNorm(128) + Q-projection via bf16x3 MFMA -> bf16 q out
// ---------------------------------------------------------------------------
__global__ __launch_bounds__(256) void lnq_mfma_kernel(
    const float* __restrict__ inp, const float* __restrict__ nw,
    const float* __restrict__ nb, const u16* __restrict__ wh,
    const u16* __restrict__ wl, const float* __restrict__ qb,
    u16* __restrict__ q) {
  __shared__ float xs[128 * 65];
  __shared__ float ps[4][64], ps2[4][64];
  __shared__ float mu[64], rs[64];
  __shared__ __align__(16) u16 xsh[16 * GS];
  __shared__ __align__(16) u16 xsl[16 * GS];
  int bid = blockIdx.x, n = bid >> 8, t0 = (bid & 255) * 64;
  const float* xb = inp + (size_t)n * C_ * HW_;
  for (int idx = threadIdx.x; idx < 8192; idx += 256) {
    int c = idx >> 6, tt = idx & 63;
    xs[c * 65 + tt] = xb[c * HW_ + t0 + tt];
  }
  __syncthreads();
  {
    int tt = threadIdx.x & 63, part = threadIdx.x >> 6;
    float s = 0.f, s2 = 0.f;
    for (int c = part * 32; c < part * 32 + 32; ++c) {
      float v = xs[c * 65 + tt];
      s += v; s2 += v * v;
    }
    ps[part][tt] = s; ps2[part][tt] = s2;
  }
  __syncthreads();
  if (threadIdx.x < 64) {
    int tt = threadIdx.x;
    float s  = ps[0][tt] + ps[1][tt] + ps[2][tt] + ps[3][tt];
    float s2 = ps2[0][tt] + ps2[1][tt] + ps2[2][tt] + ps2[3][tt];
    float m = s * (1.0f / 128.0f);
    float v = s2 * (1.0f / 128.0f) - m * m;
    mu[tt] = m; rs[tt] = rsqrtf(v + 1e-5f);
  }
  __syncthreads();
  for (int idx = threadIdx.x; idx < 8192; idx += 256) {
    int c = idx & 127, tt = idx >> 7;
    float v = (xs[c * 65 + tt] - mu[tt]) * rs[tt] * nw[c] + nb[c];
    u16 h, l; split2(v, h, l);
    int o = (c >> 3) * GS + tt * 8 + (c & 7);
    xsh[o] = h; xsl[o] = l;
  }
  __syncthreads();
  int wid = threadIdx.x >> 6, lane = threadIdx.x & 63;
  int r = lane & 15, g = lane >> 4;
  f32x4 acc[8] = {};
  #pragma unroll
  for (int kk = 0; kk < 4; ++kk) {
    bf16x8 ah = *(const bf16x8*)&xsh[(kk * 4 + g) * GS + (wid * 16 + r) * 8];
    bf16x8 al = *(const bf16x8*)&xsl[(kk * 4 + g) * GS + (wid * 16 + r) * 8];
    #pragma unroll
    for (int ct = 0; ct < 8; ++ct) {
      int o = ct * 16 + r;
      bf16x8 bh = *(const bf16x8*)&wh[o * 128 + kk * 32 + g * 8];
      bf16x8 bl = *(const bf16x8*)&wl[o * 128 + kk * 32 + g * 8];
      acc[ct] = MFMA(ah, bh, acc[ct]);
      acc[ct] = MFMA(ah, bl, acc[ct]);
      acc[ct] = MFMA(al, bh, acc[ct]);
    }
  }
  #pragma unroll
  for (int ct = 0; ct < 8; ++ct) {
    int col = ct * 16 + r;
    #pragma unroll
    for (int reg = 0; reg < 4; ++reg) {
      int row = wid * 16 + g * 4 + reg;
      q[((size_t)n * HW_ + t0 + row) * 128 + col] = f2bf_rne(acc[ct][reg] + qb[col]);
    }
  }
}

// ---------------------------------------------------------------------------
// generic 128-K GEMM via bf16x3 MFMA (final projection, in-place safe)
// ---------------------------------------------------------------------------
__global__ __launch_bounds__(256) void gemm128_mfma_kernel(
    const float* __restrict__ x, const u16* __restrict__ wh,
    const u16* __restrict__ wl, const float* __restrict__ b,
    float* __restrict__ out) {
  __shared__ __align__(16) u16 xsh[16 * GS];
  __shared__ __align__(16) u16 xsl[16 * GS];
  int r0 = blockIdx.x * 64;
  #pragma unroll
  for (int it = 0; it < 8; ++it) {
    int idx4 = it * 256 + threadIdx.x;       // 2048 float4s
    int row = idx4 >> 5, cg = idx4 & 31;
    float4 v = *(const float4*)&x[(size_t)(r0 + row) * 128 + cg * 4];
    ushort4 h4, l4; split4(v, h4, l4);
    int o = (cg >> 1) * GS + row * 8 + (cg & 1) * 4;
    *(ushort4*)&xsh[o] = h4; *(ushort4*)&xsl[o] = l4;
  }
  __syncthreads();
  int wid = threadIdx.x >> 6, lane = threadIdx.x & 63;
  int r = lane & 15, g = lane >> 4;
  f32x4 acc[8] = {};
  #pragma unroll
  for (int kk = 0; kk < 4; ++kk) {
    bf16x8 ah = *(const bf16x8*)&xsh[(kk * 4 + g) * GS + (wid * 16 + r) * 8];
    bf16x8 al = *(const bf16x8*)&xsl[(kk * 4 + g) * GS + (wid * 16 + r) * 8];
    #pragma unroll
    for (int ct = 0; ct < 8; ++ct) {
      int o = ct * 16 + r;
      bf16x8 bh = *(const bf16x8*)&wh[o * 128 + kk * 32 + g * 8];
      bf16x8 bl = *(const bf16x8*)&wl[o * 128 + kk * 32 + g * 8];
      acc[ct] = MFMA(ah, bh, acc[ct]);
      acc[ct] = MFMA(ah, bl, acc[ct]);
      acc[ct] = MFMA(al, bh, acc[ct]);
    }
  }
  #pragma unroll
  for (int ct = 0; ct < 8; ++ct) {
    int col = ct * 16 + r;
    #pragma unroll
    for (int reg = 0; reg < 4; ++reg) {
      int row = r0 + wid * 16 + g * 4 + reg;
      out[(size_t)row * 128 + col] = acc[ct][reg] + b[col];
    }
  }
}

// ---------------------------------------------------------------------------
// conv-as-GEMM v2: BM=128 (2 row-tiles/wave), bf16x3 MFMA, LDS-staged weights,
// pipelined. Halves per-block weight re-fetch vs BM=64.
// ---------------------------------------------------------------------------
template <int P, int NW, int SEG>
__device__ __forceinline__ void conv_body(
    int mblk, int seg, const u16* __restrict__ inph, const u16* __restrict__ inpl,
    const u16* __restrict__ wh, const u16* __restrict__ wl,
    float* __restrict__ dst, const float* __restrict__ bias,
    u16* ash, u16* asl, u16* wsh, u16* wsl) {
  constexpr int K    = 128 * P * P;
  constexpr int KSEG = K / SEG;
  constexpr int NT   = KSEG / 32;
  constexpr int HWIN = H_ / NW;
  constexpr int G    = HWIN / P;
  constexpr int L    = G * G;
  constexpr int M    = 4 * NW * NW * L;
  constexpr int LGL  = (L == 256) ? 8 : 6;
  constexpr int LGG  = (G == 16) ? 4 : 3;
  constexpr int LGNW = (NW == 8) ? 3 : (NW == 4) ? 2 : (NW == 2) ? 1 : 0;
  constexpr int LGP  = (P == 8) ? 3 : (P == 4) ? 2 : 1;
  constexpr int LGP2 = 2 * LGP;
  int tid = threadIdx.x, wid = tid >> 6, lane = tid & 63;
  int r = lane & 15, g = lane >> 4;
  int t0 = mblk * 128;
  int kq = tid & 7;
  int kbase = seg * KSEG;

  // per-thread gather row decode (4 rows per thread)
  size_t rbase[4];
  #pragma unroll
  for (int hh = 0; hh < 4; ++hh) {
    int row = (tid >> 3) + hh * 32;
    int tglob = t0 + row;
    int bwin = tglob >> LGL;
    int loc  = tglob & (L - 1);
    int n    = bwin >> (2 * LGNW);
    int wrem = bwin & (NW * NW - 1);
    int wy = wrem >> LGNW, wx = wrem & (NW - 1);
    int oh = loc >> LGG,   ow = loc & (G - 1);
    rbase[hh] = (size_t)n * C_ * HW_ + (size_t)(wy * HWIN + oh * P) * W_ +
                wx * HWIN + ow * P;
  }
  int ldso = (kq >> 1) * GSA + (tid >> 3) * 8 + (kq & 1) * 4;
  int wo = tid >> 2, wpart = tid & 3;
  const u16* wrowh = wh + (size_t)wo * K + kbase + wpart * 8;
  const u16* wrowl = wl + (size_t)wo * K + kbase + wpart * 8;
  int wlo_ = wo * 40 + wpart * 8;

  f32x4 acc[2][4] = {};
  ushort4 avh[4], avl[4];
  uint4 wvh, wvl;

  auto LOADSTEP = [&](int kt) {
    int k = kbase + kt * 32 + kq * 4;
    int ci = k >> LGP2;
    int wp = k & (P * P - 1);
    if constexpr (P >= 4) {
      int kh = wp >> LGP, kw = wp & (P - 1);
      size_t koff = (size_t)ci * HW_ + kh * W_ + kw;
      #pragma unroll
      for (int hh = 0; hh < 4; ++hh) {
        avh[hh] = *(const ushort4*)&inph[rbase[hh] + koff];
        avl[hh] = *(const ushort4*)&inpl[rbase[hh] + koff];
      }
    } else {
      size_t koff = (size_t)ci * HW_;
      #pragma unroll
      for (int hh = 0; hh < 4; ++hh) {
        union { uint2 u; ushort4 s; } cv;
        cv.u.x = *(const u32*)&inph[rbase[hh] + koff];
        cv.u.y = *(const u32*)&inph[rbase[hh] + koff + W_];
        avh[hh] = cv.s;
        cv.u.x = *(const u32*)&inpl[rbase[hh] + koff];
        cv.u.y = *(const u32*)&inpl[rbase[hh] + koff + W_];
        avl[hh] = cv.s;
      }
    }
    wvh = *(const uint4*)(wrowh + kt * 32);
    wvl = *(const uint4*)(wrowl + kt * 32);
  };

  LOADSTEP(0);
  for (int kt = 0; kt < NT; ++kt) {
    __syncthreads();
    #pragma unroll
    for (int hh = 0; hh < 4; ++hh) {
      *(ushort4*)&ash[ldso + hh * 256] = avh[hh];
      *(ushort4*)&asl[ldso + hh * 256] = avl[hh];
    }
    *(uint4*)&wsh[wlo_] = wvh;
    *(uint4*)&wsl[wlo_] = wvl;
    __syncthreads();
    if (kt + 1 < NT) LOADSTEP(kt + 1);
    #pragma unroll
    for (int mrep = 0; mrep < 2; ++mrep) {
      int arow = wid * 32 + mrep * 16 + r;
      bf16x8 ahf = *(const bf16x8*)&ash[g * GSA + arow * 8];
      bf16x8 alf = *(const bf16x8*)&asl[g * GSA + arow * 8];
      #pragma unroll
      for (int ct = 0; ct < 4; ++ct) {
        bf16x8 bh = *(const bf16x8*)&wsh[(ct * 16 + r) * 40 + g * 8];
        bf16x8 bl = *(const bf16x8*)&wsl[(ct * 16 + r) * 40 + g * 8];
        acc[mrep][ct] = MFMA(ahf, bh, acc[mrep][ct]);
        acc[mrep][ct] = MFMA(ahf, bl, acc[mrep][ct]);
        acc[mrep][ct] = MFMA(alf, bh, acc[mrep][ct]);
      }
    }
  }
  #pragma unroll
  for (int mrep = 0; mrep < 2; ++mrep) {
    #pragma unroll
    for (int ct = 0; ct < 4; ++ct) {
      int o = ct * 16 + r;
      #pragma unroll
      for (int reg = 0; reg < 4; ++reg) {
        int row = t0 + wid * 32 + mrep * 16 + g * 4 + reg;
        if constexpr (SEG == 1) dst[(size_t)row * 64 + o] = acc[mrep][ct][reg] + bias[o];
        else                    dst[((size_t)seg * M + row) * 64 + o] = acc[mrep][ct][reg];
      }
    }
  }
}

__global__ __launch_bounds__(256) void conv_mfma_kernel(
    const u16* __restrict__ inph, const u16* __restrict__ inpl,
    const u16* __restrict__ wsh_g, const u16* __restrict__ wsl_g,
    const float* __restrict__ b4, float* __restrict__ part,
    float* __restrict__ y) {
  __shared__ __align__(16) u16 ash[4 * GSA];
  __shared__ __align__(16) u16 asl[4 * GSA];
  __shared__ __align__(16) u16 wsh[64 * 40];
  __shared__ __align__(16) u16 wsl[64 * 40];
  int bid = blockIdx.x;
  // seg-major decode: same-seg blocks share bid%8 -> same XCD L2 (weight reuse)
  if (bid < 128) {            // head1: 8 mblk x 16 seg
    conv_body<8, 1, 16>(bid >> 4, bid & 15, inph, inpl, wsh_g + OS1, wsl_g + OS1,
                        part, nullptr, ash, asl, wsh, wsl);
  } else if (bid < 256) {     // head2: 32 mblk x 4 seg
    int lb = bid - 128;
    conv_body<4, 2, 4>(lb >> 2, lb & 3, inph, inpl, wsh_g + OS2, wsl_g + OS2,
                       part + 1048576, nullptr, ash, asl, wsh, wsl);
  } else if (bid < 384) {     // head3: 32 mblk x 4 seg
    int lb = bid - 256;
    conv_body<4, 4, 4>(lb >> 2, lb & 3, inph, inpl, wsh_g + OS3, wsl_g + OS3,
                       part + 2097152, nullptr, ash, asl, wsh, wsl);
  } else {                    // head4: 128 mblk, direct to y
    conv_body<2, 8, 1>(bid - 384, 0, inph, inpl, wsh_g + OS4, wsl_g + OS4,
                       y + (size_t)9216 * 64, b4, ash, asl, wsh, wsl);
  }
}

// reduce K-split partials + conv bias for heads 1-3 -> y
__global__ __launch_bounds__(256) void reduce_kernel(
    const float* __restrict__ part, const float* __restrict__ b1,
    const float* __restrict__ b2, const float* __restrict__ b3,
    float* __restrict__ y) {
  int idx = blockIdx.x * 256 + threadIdx.x;   // grid exactly 589824/256 = 2304
  int tg = idx >> 6, o = idx & 63;
  float s;
  if (tg < 1024) {
    s = b1[o];
    #pragma unroll
    for (int sg = 0; sg < 16; ++sg) s += part[((size_t)sg * 1024 + tg) * 64 + o];
  } else if (tg < 5120) {
    int t = tg - 1024;
    const float* p2 = part + 1048576;
    s = b2[o];
    #pragma unroll
    for (int sg = 0; sg < 4; ++sg) s += p2[((size_t)sg * 4096 + t) * 64 + o];
  } else {
    int t = tg - 5120;
    const float* p3 = part + 2097152;
    s = b3[o];
    #pragma unroll
    for (int sg = 0; sg < 4; ++sg) s += p3[((size_t)sg * 4096 + t) * 64 + o];
  }
  y[(size_t)tg * 64 + o] = s;
}

// ---------------------------------------------------------------------------
// fused LN(64) + exact GELU + KV projection (MFMA). 64 tokens/block, 400 blocks.
// K out bf16 [token][32]; V out bf16 window-transposed [d][k].
// ---------------------------------------------------------------------------
struct LnkvArgs { const float* lnw[4]; const float* lnb[4]; const float* kvb[4]; };

__global__ __launch_bounds__(256) void lnkv_mfma_kernel(
    const float* __restrict__ y, const u16* __restrict__ kvwh,
    const u16* __restrict__ kvwl, LnkvArgs a,
    u16* __restrict__ kb, u16* __restrict__ vbT) {
  __shared__ float ych[64 * 65];
  __shared__ __align__(16) u16 ash[8 * GS];
  __shared__ __align__(16) u16 asl[8 * GS];
  int bid = blockIdx.x, tid = threadIdx.x;
  int tb = bid * 64;
  int h  = (tb < 1024) ? 0 : (tb < 5120) ? 1 : (tb < 9216) ? 2 : 3;
  int hb = (h == 0) ? 0 : (h == 1) ? 1024 : (h == 2) ? 5120 : 9216;
  // stage 64x64 token tile (coalesced float4)
  #pragma unroll
  for (int it = 0; it < 4; ++it) {
    int i4 = it * 256 + tid;            // 1024 float4s
    int row = i4 >> 4, cg = i4 & 15;
    float4 v = *(const float4*)&y[(size_t)(tb + row) * 64 + cg * 4];
    *(float4*)&ych[row * 65 + cg * 4] = v;
  }
  __syncthreads();
  // LN + GELU, 4 threads per token, split to A-frag LDS
  {
    int tt = tid >> 2, p = tid & 3;
    const float* xr = &ych[tt * 65 + p * 16];
    float s = 0.f, s2 = 0.f;
    #pragma unroll
    for (int i = 0; i < 16; ++i) { float v = xr[i]; s += v; s2 += v * v; }
    s  += __shfl_xor(s, 1, 64);  s  += __shfl_xor(s, 2, 64);
    s2 += __shfl_xor(s2, 1, 64); s2 += __shfl_xor(s2, 2, 64);
    float mean = s * (1.0f / 64.0f);
    float var  = s2 * (1.0f / 64.0f) - mean * mean;
    float rstd = rsqrtf(var + 1e-5f);
    const float* lnw = a.lnw[h];
    const float* lnb = a.lnb[h];
    #pragma unroll
    for (int i = 0; i < 16; ++i) {
      int ch = p * 16 + i;
      float xn = (xr[i] - mean) * rstd * lnw[ch] + lnb[ch];
      float gg = 0.5f * xn * (1.0f + erff(xn * 0.70710678118654752f));
      u16 hh, ll; split2(gg, hh, ll);
      int o = (ch >> 3) * GS + tt * 8 + (ch & 7);
      ash[o] = hh; asl[o] = ll;
    }
  }
  __syncthreads();
  int wid = tid >> 6, lane = tid & 63, r = lane & 15, g = lane >> 4;
  const u16* wbh = kvwh + h * 4096;
  const u16* wbl = kvwl + h * 4096;
  f32x4 acc[4] = {};
  #pragma unroll
  for (int kk = 0; kk < 2; ++kk) {
    bf16x8 ah = *(const bf16x8*)&ash[(kk * 4 + g) * GS + (wid * 16 + r) * 8];
    bf16x8 al = *(const bf16x8*)&asl[(kk * 4 + g) * GS + (wid * 16 + r) * 8];
    #pragma unroll
    for (int ct = 0; ct < 4; ++ct) {
      bf16x8 bh = *(const bf16x8*)&wbh[(ct * 16 + r) * 64 + kk * 32 + g * 8];
      bf16x8 bl = *(const bf16x8*)&wbl[(ct * 16 + r) * 64 + kk * 32 + g * 8];
      acc[ct] = MFMA(ah, bh, acc[ct]);
      acc[ct] = MFMA(ah, bl, acc[ct]);
      acc[ct] = MFMA(al, bh, acc[ct]);
    }
  }
  const float* kvb = a.kvb[h];
  int lk = (h < 2) ? 256 : 64;
  #pragma unroll
  for (int ct = 0; ct < 4; ++ct) {
    int o = ct * 16 + r;
    float bias = kvb[o];
    #pragma unroll
    for (int reg = 0; reg < 4; ++reg) {
      int row = wid * 16 + g * 4 + reg;
      int tg  = tb + row;
      float v = acc[ct][reg] + bias;
      if (o < 32) {
        kb[(size_t)tg * 32 + o] = f2bf_rne(v);
      } else {
        int dd = o - 32;
        int kl = (tg - hb) & (lk - 1);
        int wstart = tg - kl;
        vbT[(size_t)wstart * 32 + dd * lk + kl] = f2bf_rne(v);
      }
    }
  }
}

// ---------------------------------------------------------------------------
// MFMA attention v2: block = 256 queries (4 waves x 4 tiles), K/V staged in LDS
// once per block; per-st P scratch (double-buffered) instead of full P tile.
// ---------------------------------------------------------------------------
template <int NW, int LK>
__device__ __forceinline__ void attn_v2_body(
    int bid, int head, int head_off, const u16* __restrict__ q,
    const u16* __restrict__ kb, const u16* __restrict__ vbT,
    float* __restrict__ cbuf) {
  constexpr int HWIN = H_ / NW;
  constexpr int LQ   = HWIN * HWIN;
  constexpr int BPW  = LQ / 256;          // blocks per window
  constexpr int NCT  = LK / 16;
  constexpr int NST  = LK / 32;
  constexpr int KS   = 40;                // K row stride (u16), 80B
  constexpr int VS   = LK + 8;            // V row stride (u16)
  extern __shared__ __align__(16) u16 alds[];
  u16* klds = alds;                       // [LK][KS]
  u16* vlds = alds + LK * KS;             // [32][VS]
  u16* plds = vlds + 32 * VS;             // 4 waves x 2 bufs x 16 x KS
  int tid = threadIdx.x, wid = tid >> 6, lane = tid & 63;
  int g = lane >> 4, c = lane & 15;
  int win  = bid / BPW;
  int n = win / (NW * NW);
  int wrem = win % (NW * NW);
  int wy = wrem / NW, wx = wrem % NW;
  int kstart = head_off + win * LK;

  // cooperative K/V staging (coalesced 16B chunks)
  const u16* kgl = kb  + (size_t)kstart * 32;
  const u16* vgl = vbT + (size_t)kstart * 32;
  #pragma unroll
  for (int ch = tid; ch < LK * 4; ch += 256) {
    int key = ch >> 2, gg = ch & 3;
    *(uint4*)&klds[key * KS + gg * 8] = *(const uint4*)&kgl[ch * 8];
  }
  #pragma unroll
  for (int ch = tid; ch < LK * 4; ch += 256) {   // 32*LK/8 == LK*4
    int d = ch / (LK / 8), pos = ch % (LK / 8);
    *(uint4*)&vlds[d * VS + pos * 8] = *(const uint4*)&vgl[ch * 8];
  }
  __syncthreads();

  u16* pw0 = plds + wid * 2 * 16 * KS;
  f32x4 zero4 = {0.f, 0.f, 0.f, 0.f};

  #pragma unroll
  for (int tq = 0; tq < 4; ++tq) {
    int tIdx = (bid % BPW) * 16 + wid * 4 + tq;
    int j = tIdx * 16 + c;
    int ih = j / HWIN, iw = j % HWIN;
    int t = (wy * HWIN + ih) * W_ + wx * HWIN + iw;
    bf16x8 qa = *(const bf16x8*)&q[((size_t)n * HW_ + t) * 128 + head * 32 + g * 8];

    // S = Q K^T from LDS K
    f32x4 sacc[NCT];
    #pragma unroll
    for (int ct = 0; ct < NCT; ++ct) {
      bf16x8 kf = *(const bf16x8*)&klds[(ct * 16 + c) * KS + g * 8];
      sacc[ct] = MFMA(qa, kf, zero4);
    }
    #pragma unroll
    for (int ct = 0; ct < NCT; ++ct)
      #pragma unroll
      for (int reg = 0; reg < 4; ++reg) sacc[ct][reg] *= SCALE_;
    // softmax per row (row = g*4+reg; cols spread over ct regs x 16 lanes)
    #pragma unroll
    for (int reg = 0; reg < 4; ++reg) {
      float mx = -1e30f;
      #pragma unroll
      for (int ct = 0; ct < NCT; ++ct) mx = fmaxf(mx, sacc[ct][reg]);
      mx = fmaxf(mx, __shfl_xor(mx, 1, 64));
      mx = fmaxf(mx, __shfl_xor(mx, 2, 64));
      mx = fmaxf(mx, __shfl_xor(mx, 4, 64));
      mx = fmaxf(mx, __shfl_xor(mx, 8, 64));
      float sm = 0.f;
      #pragma unroll
      for (int ct = 0; ct < NCT; ++ct) {
        float e = __expf(sacc[ct][reg] - mx);
        sacc[ct][reg] = e;
        sm += e;
      }
      sm += __shfl_xor(sm, 1, 64);
      sm += __shfl_xor(sm, 2, 64);
      sm += __shfl_xor(sm, 4, 64);
      sm += __shfl_xor(sm, 8, 64);
      float inv = 1.0f / sm;
      #pragma unroll
      for (int ct = 0; ct < NCT; ++ct) sacc[ct][reg] *= inv;
    }
    // PV with per-st P scratch (16x32, double-buffered, wave-private)
    f32x4 oacc[2] = {};
    #pragma unroll
    for (int st = 0; st < NST; ++st) {
      u16* pw_ = pw0 + (st & 1) * 16 * KS;
      #pragma unroll
      for (int ct2 = 0; ct2 < 2; ++ct2) {
        int ct = st * 2 + ct2;
        #pragma unroll
        for (int reg = 0; reg < 4; ++reg)
          pw_[(g * 4 + reg) * KS + ct2 * 16 + c] = f2bf_rne(sacc[ct][reg]);
      }
      bf16x8 pa = *(const bf16x8*)&pw_[c * KS + g * 8];
      #pragma unroll
      for (int dt = 0; dt < 2; ++dt) {
        bf16x8 vf = *(const bf16x8*)&vlds[(dt * 16 + c) * VS + st * 32 + g * 8];
        oacc[dt] = MFMA(pa, vf, oacc[dt]);
      }
    }
    // write O (C layout: col=c -> d, row=g*4+reg -> q local)
    #pragma unroll
    for (int reg = 0; reg < 4; ++reg) {
      int jo = tIdx * 16 + g * 4 + reg;
      int iho = jo / HWIN, iwo = jo % HWIN;
      int to = (wy * HWIN + iho) * W_ + wx * HWIN + iwo;
      float* op = cbuf + ((size_t)n * HW_ + to) * 128 + head * 32;
      op[c]      = oacc[0][reg];
      op[16 + c] = oacc[1][reg];
    }
  }
}

__global__ __launch_bounds__(256) void attn01_kernel(
    const u16* __restrict__ q, const u16* __restrict__ kb,
    const u16* __restrict__ vbT, float* __restrict__ cbuf) {
  int bid = blockIdx.x;
  if (bid < 256) attn_v2_body<1, 256>(bid,       0, 0,    q, kb, vbT, cbuf);
  else           attn_v2_body<2, 256>(bid - 256, 1, 1024, q, kb, vbT, cbuf);
}

__global__ __launch_bounds__(256) void attn23_kernel(
    const u16* __restrict__ q, const u16* __restrict__ kb,
    const u16* __restrict__ vbT, float* __restrict__ cbuf) {
  int bid = blockIdx.x;
  if (bid < 256) attn_v2_body<4, 64>(bid,       2, 5120, q, kb, vbT, cbuf);
  else           attn_v2_body<8, 64>(bid - 256, 3, 9216, q, kb, vbT, cbuf);
}

// ---------------------------------------------------------------------------
extern "C" void kernel_launch(void* const* d_in, const int* in_sizes, int n_in,
                              void* d_out, int out_size, void* d_ws, size_t ws_size,
                              hipStream_t stream) {
  const float* inp = (const float*)d_in[0];
  const float* nw  = (const float*)d_in[1];
  const float* nb  = (const float*)d_in[2];
  const float* qw  = (const float*)d_in[3];
  const float* qb  = (const float*)d_in[4];
  const float* pw  = (const float*)d_in[29];
  const float* pb  = (const float*)d_in[30];

  float* ws   = (float*)d_ws;
  u16*   qb16 = (u16*)(ws + QB_OFF);
  float* y    = ws + Y_OFF;
  u16*   kb   = (u16*)(ws + KB_OFF);
  u16*   vbT  = (u16*)(ws + VT_OFF);
  float* part = ws + PART_OFF;
  u16*   wsp  = (u16*)(ws + WSP_OFF);
  u16*   whi  = wsp;
  u16*   wlo  = wsp + TOTW;
  u16*   inph = (u16*)(ws + INH_OFF);
  u16*   inpl = (u16*)(ws + INL_OFF);
  float* cbuf = (float*)d_out;

  // 0) split weights + input to bf16 hi/lo
  split_w_kernel<<<TOTW / 256, 256, 0, stream>>>(
      qw, pw, (const float*)d_in[5], (const float*)d_in[11],
      (const float*)d_in[17], (const float*)d_in[23],
      (const float*)d_in[9], (const float*)d_in[15],
      (const float*)d_in[21], (const float*)d_in[27], whi, wlo);
  presplit_kernel<<<8192, 256, 0, stream>>>(inp, inph, inpl);

  // 1) fused LN + Q projection (MFMA) -> bf16 q
  lnq_mfma_kernel<<<1024, 256, 0, stream>>>(inp, nw, nb, whi + OQW, wlo + OQW,
                                            qb, qb16);

  // 2) all 4 patch-embed convs in one launch (MFMA, BM=128)
  conv_mfma_kernel<<<512, 256, 0, stream>>>(inph, inpl, whi, wlo,
                                            (const float*)d_in[24], part, y);

  // 3) wide reduce of K-split partials + bias -> y (heads 1-3)
  reduce_kernel<<<2304, 256, 0, stream>>>(part, (const float*)d_in[6],
                                          (const float*)d_in[12],
                                          (const float*)d_in[18], y);

  // 4) fused LN + GELU + KV projection (MFMA)
  LnkvArgs la;
  la.lnw[0] = (const float*)d_in[7];  la.lnb[0] = (const float*)d_in[8];
  la.kvb[0] = (const float*)d_in[10];
  la.lnw[1] = (const float*)d_in[13]; la.lnb[1] = (const float*)d_in[14];
  la.kvb[1] = (const float*)d_in[16];
  la.lnw[2] = (const float*)d_in[19]; la.lnb[2] = (const float*)d_in[20];
  la.kvb[2] = (const float*)d_in[22];
  la.lnw[3] = (const float*)d_in[25]; la.lnb[3] = (const float*)d_in[26];
  la.kvb[3] = (const float*)d_in[28];
  lnkv_mfma_kernel<<<400, 256, 0, stream>>>(y, whi + OKV, wlo + OKV, la, kb, vbT);

  // 5) MFMA attention v2
  // heads 0,1: LDS = 256*40 + 32*264 + 4*2*16*40 (u16) = 47616 B
  attn01_kernel<<<512, 256, 47616, stream>>>(qb16, kb, vbT, cbuf);
  // heads 2,3: LDS = 64*40 + 32*72 + 4*2*16*40 (u16) = 19968 B
  attn23_kernel<<<512, 256, 19968, stream>>>(qb16, kb, vbT, cbuf);

  // 6) final projection, in place on d_out (MFMA)
  gemm128_mfma_kernel<<<1024, 256, 0, stream>>>(cbuf, whi + OPW, wlo + OPW, pb,
                                                (float*)d_out);
}

// Round 11
// 175.708 us; speedup vs baseline: 1.4729x; 1.1340x over previous
//
#include <hip/hip_runtime.h>
#include <math.h>

#define N_   4
#define C_   128
#define H_   128
#define W_   128
#define HW_  16384
#define SCALE_ 0.17677669529663687f   // 32^-0.5

typedef unsigned short u16;
typedef unsigned int   u32;
typedef __bf16 bf16x8 __attribute__((ext_vector_type(8)));
typedef float  f32x4  __attribute__((ext_vector_type(4)));

#define MFMA(a, b, c) __builtin_amdgcn_mfma_f32_16x16x32_bf16((a), (b), (c), 0, 0, 0)

// ---- ws float offsets -------------------------------------------------------
#define QB_OFF   0            // 4,194,304 floats (8,388,608 u16 bf16 q)
#define Y_OFF    4194304      // 1,638,400 (all heads, post-reduce + bias)
#define KB_OFF   5832704      //   409,600 floats (819,200 u16 bf16 K)
#define VT_OFF   6242304      //   409,600 floats (819,200 u16 bf16 V^T)
#define PART_OFF 6651904      // 8,388,608 (4 heads x 2,097,152)
#define WSP_OFF  15040512     //   868,352 floats (2 x 868,352 u16 hi+lo)
#define INH_OFF  15908864     // 4,194,304 floats (8,388,608 u16 bf16 input)
// total 20,103,168 floats = 80.4 MB

// split-weight region offsets (u16 units, within hi or lo half)
#define OQW 0
#define OPW 16384
#define OS1 32768
#define OS2 557056
#define OS3 688128
#define OS4 819200
#define OKV 851968
#define TOTW 868352

#define GS  520    // A-LDS kgroup stride (64-row tiles), u16
#define GSA 1032   // A-LDS kgroup stride (128-row conv tiles), u16

// ---------------------------------------------------------------------------
__device__ __forceinline__ u16 f2bf_rne(float x) {
  unsigned u = __float_as_uint(x);
  return (u16)((u + 0x7FFFu + ((u >> 16) & 1u)) >> 16);
}
__device__ __forceinline__ float bf2f(u16 x) {
  return __uint_as_float((u32)x << 16);
}
__device__ __forceinline__ void split2(float v, u16& h, u16& l) {
  unsigned u = __float_as_uint(v);
  unsigned hb = (u + 0x7FFFu + ((u >> 16) & 1u)) & 0xFFFF0000u;
  h = (u16)(hb >> 16);
  float lf = v - __uint_as_float(hb);
  l = f2bf_rne(lf);
}
__device__ __forceinline__ void split4(float4 v, ushort4& h, ushort4& l) {
  split2(v.x, h.x, l.x); split2(v.y, h.y, l.y);
  split2(v.z, h.z, l.z); split2(v.w, h.w, l.w);
}

// ---------------------------------------------------------------------------
// prep: [bid<8192] input fp32 -> bf16 (RNE, hi only)
//       [else]     weights fp32 -> bf16 hi/lo (all 10 matrices)
// ---------------------------------------------------------------------------
__global__ __launch_bounds__(256) void prep_kernel(
    const float* __restrict__ inp, const float* __restrict__ qw,
    const float* __restrict__ pw, const float* __restrict__ s1,
    const float* __restrict__ s2, const float* __restrict__ s3,
    const float* __restrict__ s4, const float* __restrict__ kv1,
    const float* __restrict__ kv2, const float* __restrict__ kv3,
    const float* __restrict__ kv4, u16* __restrict__ hi,
    u16* __restrict__ lo, u16* __restrict__ inph) {
  int bid = blockIdx.x;
  if (bid < 8192) {
    int idx = bid * 256 + threadIdx.x;        // float4 units over 8,388,608 f
    float4 v = *(const float4*)&inp[(size_t)idx * 4];
    ushort4 h4;
    h4.x = f2bf_rne(v.x); h4.y = f2bf_rne(v.y);
    h4.z = f2bf_rne(v.z); h4.w = f2bf_rne(v.w);
    *(ushort4*)&inph[(size_t)idx * 4] = h4;
  } else {
    int idx = (bid - 8192) * 256 + threadIdx.x;   // < TOTW (3392 blocks)
    const float* src; int off;
    if      (idx < OPW)  { src = qw; off = idx; }
    else if (idx < OS1)  { src = pw; off = idx - OPW; }
    else if (idx < OS2)  { src = s1; off = idx - OS1; }
    else if (idx < OS3)  { src = s2; off = idx - OS2; }
    else if (idx < OS4)  { src = s3; off = idx - OS3; }
    else if (idx < OKV)  { src = s4; off = idx - OS4; }
    else {
      int j = idx - OKV;
      int h = j >> 12; off = j & 4095;
      src = (h == 0) ? kv1 : (h == 1) ? kv2 : (h == 2) ? kv3 : kv4;
    }
    u16 h, l; split2(src[off], h, l);
    hi[idx] = h; lo[idx] = l;
  }
}

// ---------------------------------------------------------------------------
// fused LayerNorm(128) + Q-projection via bf16x3 MFMA -> bf16 q out
// (input read as bf16; LN/split of normalized value still fp32-accurate)
// ---------------------------------------------------------------------------
__global__ __launch_bounds__(256) void lnq_mfma_kernel(
    const u16* __restrict__ inph, const float* __restrict__ nw,
    const float* __restrict__ nb, const u16* __restrict__ wh,
    const u16* __restrict__ wl, const float* __restrict__ qb,
    u16* __restrict__ q) {
  __shared__ float xs[128 * 65];
  __shared__ float ps[4][64], ps2[4][64];
  __shared__ float mu[64], rs[64];
  __shared__ __align__(16) u16 xsh[16 * GS];
  __shared__ __align__(16) u16 xsl[16 * GS];
  int bid = blockIdx.x, n = bid >> 8, t0 = (bid & 255) * 64;
  const u16* xb = inph + (size_t)n * C_ * HW_;
  #pragma unroll
  for (int it = 0; it < 8; ++it) {
    int i4 = it * 256 + threadIdx.x;           // 2048 ushort4 units
    int c = i4 >> 4, t4 = (i4 & 15) * 4;
    ushort4 v = *(const ushort4*)&xb[c * HW_ + t0 + t4];
    xs[c * 65 + t4 + 0] = bf2f(v.x);
    xs[c * 65 + t4 + 1] = bf2f(v.y);
    xs[c * 65 + t4 + 2] = bf2f(v.z);
    xs[c * 65 + t4 + 3] = bf2f(v.w);
  }
  __syncthreads();
  {
    int tt = threadIdx.x & 63, part = threadIdx.x >> 6;
    float s = 0.f, s2 = 0.f;
    for (int c = part * 32; c < part * 32 + 32; ++c) {
      float v = xs[c * 65 + tt];
      s += v; s2 += v * v;
    }
    ps[part][tt] = s; ps2[part][tt] = s2;
  }
  __syncthreads();
  if (threadIdx.x < 64) {
    int tt = threadIdx.x;
    float s  = ps[0][tt] + ps[1][tt] + ps[2][tt] + ps[3][tt];
    float s2 = ps2[0][tt] + ps2[1][tt] + ps2[2][tt] + ps2[3][tt];
    float m = s * (1.0f / 128.0f);
    float v = s2 * (1.0f / 128.0f) - m * m;
    mu[tt] = m; rs[tt] = rsqrtf(v + 1e-5f);
  }
  __syncthreads();
  for (int idx = threadIdx.x; idx < 8192; idx += 256) {
    int c = idx & 127, tt = idx >> 7;
    float v = (xs[c * 65 + tt] - mu[tt]) * rs[tt] * nw[c] + nb[c];
    u16 h, l; split2(v, h, l);
    int o = (c >> 3) * GS + tt * 8 + (c & 7);
    xsh[o] = h; xsl[o] = l;
  }
  __syncthreads();
  int wid = threadIdx.x >> 6, lane = threadIdx.x & 63;
  int r = lane & 15, g = lane >> 4;
  f32x4 acc[8] = {};
  #pragma unroll
  for (int kk = 0; kk < 4; ++kk) {
    bf16x8 ah = *(const bf16x8*)&xsh[(kk * 4 + g) * GS + (wid * 16 + r) * 8];
    bf16x8 al = *(const bf16x8*)&xsl[(kk * 4 + g) * GS + (wid * 16 + r) * 8];
    #pragma unroll
    for (int ct = 0; ct < 8; ++ct) {
      int o = ct * 16 + r;
      bf16x8 bh = *(const bf16x8*)&wh[o * 128 + kk * 32 + g * 8];
      bf16x8 bl = *(const bf16x8*)&wl[o * 128 + kk * 32 + g * 8];
      acc[ct] = MFMA(ah, bh, acc[ct]);
      acc[ct] = MFMA(ah, bl, acc[ct]);
      acc[ct] = MFMA(al, bh, acc[ct]);
    }
  }
  #pragma unroll
  for (int ct = 0; ct < 8; ++ct) {
    int col = ct * 16 + r;
    #pragma unroll
    for (int reg = 0; reg < 4; ++reg) {
      int row = wid * 16 + g * 4 + reg;
      q[((size_t)n * HW_ + t0 + row) * 128 + col] = f2bf_rne(acc[ct][reg] + qb[col]);
    }
  }
}

// ---------------------------------------------------------------------------
// generic 128-K GEMM via bf16x3 MFMA (final projection, in-place safe)
// ---------------------------------------------------------------------------
__global__ __launch_bounds__(256) void gemm128_mfma_kernel(
    const float* __restrict__ x, const u16* __restrict__ wh,
    const u16* __restrict__ wl, const float* __restrict__ b,
    float* __restrict__ out) {
  __shared__ __align__(16) u16 xsh[16 * GS];
  __shared__ __align__(16) u16 xsl[16 * GS];
  int r0 = blockIdx.x * 64;
  #pragma unroll
  for (int it = 0; it < 8; ++it) {
    int idx4 = it * 256 + threadIdx.x;       // 2048 float4s
    int row = idx4 >> 5, cg = idx4 & 31;
    float4 v = *(const float4*)&x[(size_t)(r0 + row) * 128 + cg * 4];
    ushort4 h4, l4; split4(v, h4, l4);
    int o = (cg >> 1) * GS + row * 8 + (cg & 1) * 4;
    *(ushort4*)&xsh[o] = h4; *(ushort4*)&xsl[o] = l4;
  }
  __syncthreads();
  int wid = threadIdx.x >> 6, lane = threadIdx.x & 63;
  int r = lane & 15, g = lane >> 4;
  f32x4 acc[8] = {};
  #pragma unroll
  for (int kk = 0; kk < 4; ++kk) {
    bf16x8 ah = *(const bf16x8*)&xsh[(kk * 4 + g) * GS + (wid * 16 + r) * 8];
    bf16x8 al = *(const bf16x8*)&xsl[(kk * 4 + g) * GS + (wid * 16 + r) * 8];
    #pragma unroll
    for (int ct = 0; ct < 8; ++ct) {
      int o = ct * 16 + r;
      bf16x8 bh = *(const bf16x8*)&wh[o * 128 + kk * 32 + g * 8];
      bf16x8 bl = *(const bf16x8*)&wl[o * 128 + kk * 32 + g * 8];
      acc[ct] = MFMA(ah, bh, acc[ct]);
      acc[ct] = MFMA(ah, bl, acc[ct]);
      acc[ct] = MFMA(al, bh, acc[ct]);
    }
  }
  #pragma unroll
  for (int ct = 0; ct < 8; ++ct) {
    int col = ct * 16 + r;
    #pragma unroll
    for (int reg = 0; reg < 4; ++reg) {
      int row = r0 + wid * 16 + g * 4 + reg;
      out[(size_t)row * 128 + col] = acc[ct][reg] + b[col];
    }
  }
}

// ---------------------------------------------------------------------------
// conv-as-GEMM v3: plain bf16, BM=128, uniform KSEG=256 (NT=8), all heads
// write fp32 K-split partials. LDS-staged A + W, pipelined.
// ---------------------------------------------------------------------------
template <int P, int NW, int SEG>
__device__ __forceinline__ void conv_body(
    int mblk, int seg, const u16* __restrict__ inph,
    const u16* __restrict__ wh, float* __restrict__ dst,
    u16* ash, u16* wsh) {
  constexpr int K    = 128 * P * P;
  constexpr int KSEG = K / SEG;              // 256 everywhere
  constexpr int NT   = KSEG / 32;            // 8
  constexpr int HWIN = H_ / NW;
  constexpr int G    = HWIN / P;
  constexpr int L    = G * G;
  constexpr int M    = 4 * NW * NW * L;
  constexpr int LGL  = (L == 256) ? 8 : 6;
  constexpr int LGG  = (G == 16) ? 4 : 3;
  constexpr int LGNW = (NW == 8) ? 3 : (NW == 4) ? 2 : (NW == 2) ? 1 : 0;
  constexpr int LGP  = (P == 8) ? 3 : (P == 4) ? 2 : 1;
  constexpr int LGP2 = 2 * LGP;
  int tid = threadIdx.x, wid = tid >> 6, lane = tid & 63;
  int r = lane & 15, g = lane >> 4;
  int t0 = mblk * 128;
  int kq = tid & 7;
  int kbase = seg * KSEG;

  // per-thread gather row decode (4 rows per thread)
  size_t rbase[4];
  #pragma unroll
  for (int hh = 0; hh < 4; ++hh) {
    int row = (tid >> 3) + hh * 32;
    int tglob = t0 + row;
    int bwin = tglob >> LGL;
    int loc  = tglob & (L - 1);
    int n    = bwin >> (2 * LGNW);
    int wrem = bwin & (NW * NW - 1);
    int wy = wrem >> LGNW, wx = wrem & (NW - 1);
    int oh = loc >> LGG,   ow = loc & (G - 1);
    rbase[hh] = (size_t)n * C_ * HW_ + (size_t)(wy * HWIN + oh * P) * W_ +
                wx * HWIN + ow * P;
  }
  int ldso = (kq >> 1) * GSA + (tid >> 3) * 8 + (kq & 1) * 4;
  int wo = tid >> 2, wpart = tid & 3;
  const u16* wrowh = wh + (size_t)wo * K + kbase + wpart * 8;
  int wlo_ = wo * 40 + wpart * 8;

  f32x4 acc[2][4] = {};
  ushort4 avh[4];
  uint4 wvh;

  auto LOADSTEP = [&](int kt) {
    int k = kbase + kt * 32 + kq * 4;
    int ci = k >> LGP2;
    int wp = k & (P * P - 1);
    if constexpr (P >= 4) {
      int kh = wp >> LGP, kw = wp & (P - 1);
      size_t koff = (size_t)ci * HW_ + kh * W_ + kw;
      #pragma unroll
      for (int hh = 0; hh < 4; ++hh)
        avh[hh] = *(const ushort4*)&inph[rbase[hh] + koff];
    } else {
      size_t koff = (size_t)ci * HW_;
      #pragma unroll
      for (int hh = 0; hh < 4; ++hh) {
        union { uint2 u; ushort4 s; } cv;
        cv.u.x = *(const u32*)&inph[rbase[hh] + koff];
        cv.u.y = *(const u32*)&inph[rbase[hh] + koff + W_];
        avh[hh] = cv.s;
      }
    }
    wvh = *(const uint4*)(wrowh + kt * 32);
  };

  LOADSTEP(0);
  for (int kt = 0; kt < NT; ++kt) {
    __syncthreads();
    #pragma unroll
    for (int hh = 0; hh < 4; ++hh)
      *(ushort4*)&ash[ldso + hh * 256] = avh[hh];
    *(uint4*)&wsh[wlo_] = wvh;
    __syncthreads();
    if (kt + 1 < NT) LOADSTEP(kt + 1);
    #pragma unroll
    for (int mrep = 0; mrep < 2; ++mrep) {
      int arow = wid * 32 + mrep * 16 + r;
      bf16x8 ahf = *(const bf16x8*)&ash[g * GSA + arow * 8];
      #pragma unroll
      for (int ct = 0; ct < 4; ++ct) {
        bf16x8 bh = *(const bf16x8*)&wsh[(ct * 16 + r) * 40 + g * 8];
        acc[mrep][ct] = MFMA(ahf, bh, acc[mrep][ct]);
      }
    }
  }
  #pragma unroll
  for (int mrep = 0; mrep < 2; ++mrep) {
    #pragma unroll
    for (int ct = 0; ct < 4; ++ct) {
      int o = ct * 16 + r;
      #pragma unroll
      for (int reg = 0; reg < 4; ++reg) {
        int row = t0 + wid * 32 + mrep * 16 + g * 4 + reg;
        dst[((size_t)seg * M + row) * 64 + o] = acc[mrep][ct][reg];
      }
    }
  }
}

__global__ __launch_bounds__(256) void conv_mfma_kernel(
    const u16* __restrict__ inph, const u16* __restrict__ wsh_g,
    float* __restrict__ part) {
  __shared__ __align__(16) u16 ash[4 * GSA];
  __shared__ __align__(16) u16 wsh[64 * 40];
  int bid = blockIdx.x;
  if (bid < 256) {            // head1: 8 mblk x 32 seg
    conv_body<8, 1, 32>(bid >> 5, bid & 31, inph, wsh_g + OS1, part, ash, wsh);
  } else if (bid < 512) {     // head2: 32 mblk x 8 seg
    int lb = bid - 256;
    conv_body<4, 2, 8>(lb >> 3, lb & 7, inph, wsh_g + OS2, part + 2097152,
                       ash, wsh);
  } else if (bid < 768) {     // head3: 32 mblk x 8 seg
    int lb = bid - 512;
    conv_body<4, 4, 8>(lb >> 3, lb & 7, inph, wsh_g + OS3, part + 4194304,
                       ash, wsh);
  } else {                    // head4: 128 mblk x 2 seg
    int lb = bid - 768;
    conv_body<2, 8, 2>(lb >> 1, lb & 1, inph, wsh_g + OS4, part + 6291456,
                       ash, wsh);
  }
}

// reduce K-split partials + conv bias, all heads -> y (25600 tokens)
__global__ __launch_bounds__(256) void reduce_kernel(
    const float* __restrict__ part, const float* __restrict__ b1,
    const float* __restrict__ b2, const float* __restrict__ b3,
    const float* __restrict__ b4, float* __restrict__ y) {
  int idx = blockIdx.x * 256 + threadIdx.x;   // grid exactly 1,638,400/256=6400
  int tg = idx >> 6, o = idx & 63;
  float s;
  if (tg < 1024) {
    s = b1[o];
    #pragma unroll
    for (int sg = 0; sg < 32; ++sg) s += part[((size_t)sg * 1024 + tg) * 64 + o];
  } else if (tg < 5120) {
    int t = tg - 1024;
    const float* p2 = part + 2097152;
    s = b2[o];
    #pragma unroll
    for (int sg = 0; sg < 8; ++sg) s += p2[((size_t)sg * 4096 + t) * 64 + o];
  } else if (tg < 9216) {
    int t = tg - 5120;
    const float* p3 = part + 4194304;
    s = b3[o];
    #pragma unroll
    for (int sg = 0; sg < 8; ++sg) s += p3[((size_t)sg * 4096 + t) * 64 + o];
  } else {
    int t = tg - 9216;
    const float* p4 = part + 6291456;
    s = b4[o] + p4[(size_t)t * 64 + o] + p4[((size_t)16384 + t) * 64 + o];
  }
  y[(size_t)tg * 64 + o] = s;
}

// ---------------------------------------------------------------------------
// fused LN(64) + exact GELU + KV projection (MFMA). 64 tokens/block, 400 blocks.
// K out bf16 [token][32]; V out bf16 window-transposed [d][k].
// ---------------------------------------------------------------------------
struct LnkvArgs { const float* lnw[4]; const float* lnb[4]; const float* kvb[4]; };

__global__ __launch_bounds__(256) void lnkv_mfma_kernel(
    const float* __restrict__ y, const u16* __restrict__ kvwh,
    const u16* __restrict__ kvwl, LnkvArgs a,
    u16* __restrict__ kb, u16* __restrict__ vbT) {
  __shared__ float ych[64 * 65];
  __shared__ __align__(16) u16 ash[8 * GS];
  __shared__ __align__(16) u16 asl[8 * GS];
  int bid = blockIdx.x, tid = threadIdx.x;
  int tb = bid * 64;
  int h  = (tb < 1024) ? 0 : (tb < 5120) ? 1 : (tb < 9216) ? 2 : 3;
  int hb = (h == 0) ? 0 : (h == 1) ? 1024 : (h == 2) ? 5120 : 9216;
  // stage 64x64 token tile (coalesced float4)
  #pragma unroll
  for (int it = 0; it < 4; ++it) {
    int i4 = it * 256 + tid;            // 1024 float4s
    int row = i4 >> 4, cg = i4 & 15;
    float4 v = *(const float4*)&y[(size_t)(tb + row) * 64 + cg * 4];
    *(float4*)&ych[row * 65 + cg * 4] = v;
  }
  __syncthreads();
  // LN + GELU, 4 threads per token, split to A-frag LDS
  {
    int tt = tid >> 2, p = tid & 3;
    const float* xr = &ych[tt * 65 + p * 16];
    float s = 0.f, s2 = 0.f;
    #pragma unroll
    for (int i = 0; i < 16; ++i) { float v = xr[i]; s += v; s2 += v * v; }
    s  += __shfl_xor(s, 1, 64);  s  += __shfl_xor(s, 2, 64);
    s2 += __shfl_xor(s2, 1, 64); s2 += __shfl_xor(s2, 2, 64);
    float mean = s * (1.0f / 64.0f);
    float var  = s2 * (1.0f / 64.0f) - mean * mean;
    float rstd = rsqrtf(var + 1e-5f);
    const float* lnw = a.lnw[h];
    const float* lnb = a.lnb[h];
    #pragma unroll
    for (int i = 0; i < 16; ++i) {
      int ch = p * 16 + i;
      float xn = (xr[i] - mean) * rstd * lnw[ch] + lnb[ch];
      float gg = 0.5f * xn * (1.0f + erff(xn * 0.70710678118654752f));
      u16 hh, ll; split2(gg, hh, ll);
      int o = (ch >> 3) * GS + tt * 8 + (ch & 7);
      ash[o] = hh; asl[o] = ll;
    }
  }
  __syncthreads();
  int wid = tid >> 6, lane = tid & 63, r = lane & 15, g = lane >> 4;
  const u16* wbh = kvwh + h * 4096;
  const u16* wbl = kvwl + h * 4096;
  f32x4 acc[4] = {};
  #pragma unroll
  for (int kk = 0; kk < 2; ++kk) {
    bf16x8 ah = *(const bf16x8*)&ash[(kk * 4 + g) * GS + (wid * 16 + r) * 8];
    bf16x8 al = *(const bf16x8*)&asl[(kk * 4 + g) * GS + (wid * 16 + r) * 8];
    #pragma unroll
    for (int ct = 0; ct < 4; ++ct) {
      bf16x8 bh = *(const bf16x8*)&wbh[(ct * 16 + r) * 64 + kk * 32 + g * 8];
      bf16x8 bl = *(const bf16x8*)&wbl[(ct * 16 + r) * 64 + kk * 32 + g * 8];
      acc[ct] = MFMA(ah, bh, acc[ct]);
      acc[ct] = MFMA(ah, bl, acc[ct]);
      acc[ct] = MFMA(al, bh, acc[ct]);
    }
  }
  const float* kvb = a.kvb[h];
  int lk = (h < 2) ? 256 : 64;
  #pragma unroll
  for (int ct = 0; ct < 4; ++ct) {
    int o = ct * 16 + r;
    float bias = kvb[o];
    #pragma unroll
    for (int reg = 0; reg < 4; ++reg) {
      int row = wid * 16 + g * 4 + reg;
      int tg  = tb + row;
      float v = acc[ct][reg] + bias;
      if (o < 32) {
        kb[(size_t)tg * 32 + o] = f2bf_rne(v);
      } else {
        int dd = o - 32;
        int kl = (tg - hb) & (lk - 1);
        int wstart = tg - kl;
        vbT[(size_t)wstart * 32 + dd * lk + kl] = f2bf_rne(v);
      }
    }
  }
}

// ---------------------------------------------------------------------------
// MFMA attention v2: block = 256 queries (4 waves x 4 tiles), K/V staged in LDS
// once per block; per-st P scratch (double-buffered). All heads, one launch.
// ---------------------------------------------------------------------------
template <int NW, int LK>
__device__ __forceinline__ void attn_v2_body(
    int bid, int head, int head_off, const u16* __restrict__ q,
    const u16* __restrict__ kb, const u16* __restrict__ vbT,
    float* __restrict__ cbuf) {
  constexpr int HWIN = H_ / NW;
  constexpr int LQ   = HWIN * HWIN;
  constexpr int BPW  = LQ / 256;          // blocks per window
  constexpr int NCT  = LK / 16;
  constexpr int NST  = LK / 32;
  constexpr int KS   = 40;                // K row stride (u16), 80B
  constexpr int VS   = LK + 8;            // V row stride (u16)
  extern __shared__ __align__(16) u16 alds[];
  u16* klds = alds;                       // [LK][KS]
  u16* vlds = alds + LK * KS;             // [32][VS]
  u16* plds = vlds + 32 * VS;             // 4 waves x 2 bufs x 16 x KS
  int tid = threadIdx.x, wid = tid >> 6, lane = tid & 63;
  int g = lane >> 4, c = lane & 15;
  int win  = bid / BPW;
  int n = win / (NW * NW);
  int wrem = win % (NW * NW);
  int wy = wrem / NW, wx = wrem % NW;
  int kstart = head_off + win * LK;

  // cooperative K/V staging (coalesced 16B chunks)
  const u16* kgl = kb  + (size_t)kstart * 32;
  const u16* vgl = vbT + (size_t)kstart * 32;
  #pragma unroll
  for (int ch = tid; ch < LK * 4; ch += 256) {
    int key = ch >> 2, gg = ch & 3;
    *(uint4*)&klds[key * KS + gg * 8] = *(const uint4*)&kgl[ch * 8];
  }
  #pragma unroll
  for (int ch = tid; ch < LK * 4; ch += 256) {   // 32*LK/8 == LK*4
    int d = ch / (LK / 8), pos = ch % (LK / 8);
    *(uint4*)&vlds[d * VS + pos * 8] = *(const uint4*)&vgl[ch * 8];
  }
  __syncthreads();

  u16* pw0 = plds + wid * 2 * 16 * KS;
  f32x4 zero4 = {0.f, 0.f, 0.f, 0.f};

  #pragma unroll
  for (int tq = 0; tq < 4; ++tq) {
    int tIdx = (bid % BPW) * 16 + wid * 4 + tq;
    int j = tIdx * 16 + c;
    int ih = j / HWIN, iw = j % HWIN;
    int t = (wy * HWIN + ih) * W_ + wx * HWIN + iw;
    bf16x8 qa = *(const bf16x8*)&q[((size_t)n * HW_ + t) * 128 + head * 32 + g * 8];

    // S = Q K^T from LDS K
    f32x4 sacc[NCT];
    #pragma unroll
    for (int ct = 0; ct < NCT; ++ct) {
      bf16x8 kf = *(const bf16x8*)&klds[(ct * 16 + c) * KS + g * 8];
      sacc[ct] = MFMA(qa, kf, zero4);
    }
    #pragma unroll
    for (int ct = 0; ct < NCT; ++ct)
      #pragma unroll
      for (int reg = 0; reg < 4; ++reg) sacc[ct][reg] *= SCALE_;
    // softmax per row (row = g*4+reg; cols spread over ct regs x 16 lanes)
    #pragma unroll
    for (int reg = 0; reg < 4; ++reg) {
      float mx = -1e30f;
      #pragma unroll
      for (int ct = 0; ct < NCT; ++ct) mx = fmaxf(mx, sacc[ct][reg]);
      mx = fmaxf(mx, __shfl_xor(mx, 1, 64));
      mx = fmaxf(mx, __shfl_xor(mx, 2, 64));
      mx = fmaxf(mx, __shfl_xor(mx, 4, 64));
      mx = fmaxf(mx, __shfl_xor(mx, 8, 64));
      float sm = 0.f;
      #pragma unroll
      for (int ct = 0; ct < NCT; ++ct) {
        float e = __expf(sacc[ct][reg] - mx);
        sacc[ct][reg] = e;
        sm += e;
      }
      sm += __shfl_xor(sm, 1, 64);
      sm += __shfl_xor(sm, 2, 64);
      sm += __shfl_xor(sm, 4, 64);
      sm += __shfl_xor(sm, 8, 64);
      float inv = 1.0f / sm;
      #pragma unroll
      for (int ct = 0; ct < NCT; ++ct) sacc[ct][reg] *= inv;
    }
    // PV with per-st P scratch (16x32, double-buffered, wave-private)
    f32x4 oacc[2] = {};
    #pragma unroll
    for (int st = 0; st < NST; ++st) {
      u16* pw_ = pw0 + (st & 1) * 16 * KS;
      #pragma unroll
      for (int ct2 = 0; ct2 < 2; ++ct2) {
        int ct = st * 2 + ct2;
        #pragma unroll
        for (int reg = 0; reg < 4; ++reg)
          pw_[(g * 4 + reg) * KS + ct2 * 16 + c] = f2bf_rne(sacc[ct][reg]);
      }
      bf16x8 pa = *(const bf16x8*)&pw_[c * KS + g * 8];
      #pragma unroll
      for (int dt = 0; dt < 2; ++dt) {
        bf16x8 vf = *(const bf16x8*)&vlds[(dt * 16 + c) * VS + st * 32 + g * 8];
        oacc[dt] = MFMA(pa, vf, oacc[dt]);
      }
    }
    // write O (C layout: col=c -> d, row=g*4+reg -> q local)
    #pragma unroll
    for (int reg = 0; reg < 4; ++reg) {
      int jo = tIdx * 16 + g * 4 + reg;
      int iho = jo / HWIN, iwo = jo % HWIN;
      int to = (wy * HWIN + iho) * W_ + wx * HWIN + iwo;
      float* op = cbuf + ((size_t)n * HW_ + to) * 128 + head * 32;
      op[c]      = oacc[0][reg];
      op[16 + c] = oacc[1][reg];
    }
  }
}

__global__ __launch_bounds__(256) void attn_kernel(
    const u16* __restrict__ q, const u16* __restrict__ kb,
    const u16* __restrict__ vbT, float* __restrict__ cbuf) {
  int bid = blockIdx.x;
  if      (bid < 256)  attn_v2_body<1, 256>(bid,       0, 0,    q, kb, vbT, cbuf);
  else if (bid < 512)  attn_v2_body<2, 256>(bid - 256, 1, 1024, q, kb, vbT, cbuf);
  else if (bid < 768)  attn_v2_body<4, 64 >(bid - 512, 2, 5120, q, kb, vbT, cbuf);
  else                 attn_v2_body<8, 64 >(bid - 768, 3, 9216, q, kb, vbT, cbuf);
}

// ---------------------------------------------------------------------------
extern "C" void kernel_launch(void* const* d_in, const int* in_sizes, int n_in,
                              void* d_out, int out_size, void* d_ws, size_t ws_size,
                              hipStream_t stream) {
  const float* inp = (const float*)d_in[0];
  const float* nw  = (const float*)d_in[1];
  const float* nb  = (const float*)d_in[2];
  const float* qw  = (const float*)d_in[3];
  const float* qb  = (const float*)d_in[4];
  const float* pw  = (const float*)d_in[29];
  const float* pb  = (const float*)d_in[30];

  float* ws   = (float*)d_ws;
  u16*   qb16 = (u16*)(ws + QB_OFF);
  float* y    = ws + Y_OFF;
  u16*   kb   = (u16*)(ws + KB_OFF);
  u16*   vbT  = (u16*)(ws + VT_OFF);
  float* part = ws + PART_OFF;
  u16*   wsp  = (u16*)(ws + WSP_OFF);
  u16*   whi  = wsp;
  u16*   wlo  = wsp + TOTW;
  u16*   inph = (u16*)(ws + INH_OFF);
  float* cbuf = (float*)d_out;

  // 0) prep: input -> bf16, weights -> bf16 hi/lo (one launch)
  prep_kernel<<<8192 + TOTW / 256, 256, 0, stream>>>(
      inp, qw, pw, (const float*)d_in[5], (const float*)d_in[11],
      (const float*)d_in[17], (const float*)d_in[23],
      (const float*)d_in[9], (const float*)d_in[15],
      (const float*)d_in[21], (const float*)d_in[27], whi, wlo, inph);

  // 1) fused LN + Q projection (MFMA) -> bf16 q
  lnq_mfma_kernel<<<1024, 256, 0, stream>>>(inph, nw, nb, whi + OQW, wlo + OQW,
                                            qb, qb16);

  // 2) all 4 patch-embed convs, plain bf16, uniform K-split (1024 blocks)
  conv_mfma_kernel<<<1024, 256, 0, stream>>>(inph, whi, part);

  // 3) wide reduce of K-split partials + bias -> y (all heads)
  reduce_kernel<<<6400, 256, 0, stream>>>(part, (const float*)d_in[6],
                                          (const float*)d_in[12],
                                          (const float*)d_in[18],
                                          (const float*)d_in[24], y);

  // 4) fused LN + GELU + KV projection (MFMA)
  LnkvArgs la;
  la.lnw[0] = (const float*)d_in[7];  la.lnb[0] = (const float*)d_in[8];
  la.kvb[0] = (const float*)d_in[10];
  la.lnw[1] = (const float*)d_in[13]; la.lnb[1] = (const float*)d_in[14];
  la.kvb[1] = (const float*)d_in[16];
  la.lnw[2] = (const float*)d_in[19]; la.lnb[2] = (const float*)d_in[20];
  la.kvb[2] = (const float*)d_in[22];
  la.lnw[3] = (const float*)d_in[25]; la.lnb[3] = (const float*)d_in[26];
  la.kvb[3] = (const float*)d_in[28];
  lnkv_mfma_kernel<<<400, 256, 0, stream>>>(y, whi + OKV, wlo + OKV, la, kb, vbT);

  // 5) MFMA attention, all heads one launch (LDS sized for LK=256: 47616 B)
  attn_kernel<<<1024, 256, 47616, stream>>>(qb16, kb, vbT, cbuf);

  // 6) final projection, in place on d_out (MFMA)
  gemm128_mfma_kernel<<<1024, 256, 0, stream>>>(cbuf, whi + OPW, wlo + OPW, pb,
                                                (float*)d_out);
}

// Round 12
// 167.764 us; speedup vs baseline: 1.5426x; 1.0474x over previous
//
#include <hip/hip_runtime.h>
#include <math.h>

#define N_   4
#define C_   128
#define H_   128
#define W_   128
#define HW_  16384
#define SCALE_ 0.17677669529663687f   // 32^-0.5

typedef unsigned short u16;
typedef unsigned int   u32;
typedef __bf16 bf16x8 __attribute__((ext_vector_type(8)));
typedef float  f32x4  __attribute__((ext_vector_type(4)));

#define MFMA(a, b, c) __builtin_amdgcn_mfma_f32_16x16x32_bf16((a), (b), (c), 0, 0, 0)

// ---- ws float offsets -------------------------------------------------------
#define QB_OFF   0            // 4,194,304 floats (8,388,608 u16 bf16 q)
#define Y_OFF    4194304      // 1,638,400 (all heads, post-reduce + bias)
#define KB_OFF   5832704      //   409,600 floats (819,200 u16 bf16 K)
#define VT_OFF   6242304      //   409,600 floats (819,200 u16 bf16 V^T)
#define PART_OFF 6651904      // 8,388,608 (4 heads x 2,097,152)
#define WSP_OFF  15040512     //   868,352 floats (2 x 868,352 u16 hi+lo)
#define INH_OFF  15908864     // 4,194,304 floats (8,388,608 u16 bf16 input)
// total 20,103,168 floats = 80.4 MB

// split-weight region offsets (u16 units, within hi or lo half)
#define OQW 0
#define OPW 16384
#define OS1 32768
#define OS2 557056
#define OS3 688128
#define OS4 819200
#define OKV 851968
#define TOTW 868352

#define GS  520    // A-LDS kgroup stride (64-row tiles), u16
#define GSA 1032   // A-LDS kgroup stride (128-row conv tiles), u16

// ---------------------------------------------------------------------------
__device__ __forceinline__ u16 f2bf_rne(float x) {
  unsigned u = __float_as_uint(x);
  return (u16)((u + 0x7FFFu + ((u >> 16) & 1u)) >> 16);
}
__device__ __forceinline__ float bf2f(u16 x) {
  return __uint_as_float((u32)x << 16);
}
__device__ __forceinline__ void split2(float v, u16& h, u16& l) {
  unsigned u = __float_as_uint(v);
  unsigned hb = (u + 0x7FFFu + ((u >> 16) & 1u)) & 0xFFFF0000u;
  h = (u16)(hb >> 16);
  float lf = v - __uint_as_float(hb);
  l = f2bf_rne(lf);
}
__device__ __forceinline__ void split4(float4 v, ushort4& h, ushort4& l) {
  split2(v.x, h.x, l.x); split2(v.y, h.y, l.y);
  split2(v.z, h.z, l.z); split2(v.w, h.w, l.w);
}

// ---------------------------------------------------------------------------
// prep: [bid<8192] input fp32 -> bf16 (RNE, hi only)
//       [else]     weights fp32 -> bf16 hi/lo (all 10 matrices)
// ---------------------------------------------------------------------------
__global__ __launch_bounds__(256) void prep_kernel(
    const float* __restrict__ inp, const float* __restrict__ qw,
    const float* __restrict__ pw, const float* __restrict__ s1,
    const float* __restrict__ s2, const float* __restrict__ s3,
    const float* __restrict__ s4, const float* __restrict__ kv1,
    const float* __restrict__ kv2, const float* __restrict__ kv3,
    const float* __restrict__ kv4, u16* __restrict__ hi,
    u16* __restrict__ lo, u16* __restrict__ inph) {
  int bid = blockIdx.x;
  if (bid < 8192) {
    int idx = bid * 256 + threadIdx.x;        // float4 units over 8,388,608 f
    float4 v = *(const float4*)&inp[(size_t)idx * 4];
    ushort4 h4;
    h4.x = f2bf_rne(v.x); h4.y = f2bf_rne(v.y);
    h4.z = f2bf_rne(v.z); h4.w = f2bf_rne(v.w);
    *(ushort4*)&inph[(size_t)idx * 4] = h4;
  } else {
    int idx = (bid - 8192) * 256 + threadIdx.x;   // < TOTW (3392 blocks)
    const float* src; int off;
    if      (idx < OPW)  { src = qw; off = idx; }
    else if (idx < OS1)  { src = pw; off = idx - OPW; }
    else if (idx < OS2)  { src = s1; off = idx - OS1; }
    else if (idx < OS3)  { src = s2; off = idx - OS2; }
    else if (idx < OS4)  { src = s3; off = idx - OS3; }
    else if (idx < OKV)  { src = s4; off = idx - OS4; }
    else {
      int j = idx - OKV;
      int h = j >> 12; off = j & 4095;
      src = (h == 0) ? kv1 : (h == 1) ? kv2 : (h == 2) ? kv3 : kv4;
    }
    u16 h, l; split2(src[off], h, l);
    hi[idx] = h; lo[idx] = l;
  }
}

// ---------------------------------------------------------------------------
// fused LayerNorm(128) + Q-projection via bf16x3 MFMA -> bf16 q out
// ---------------------------------------------------------------------------
__global__ __launch_bounds__(256) void lnq_mfma_kernel(
    const u16* __restrict__ inph, const float* __restrict__ nw,
    const float* __restrict__ nb, const u16* __restrict__ wh,
    const u16* __restrict__ wl, const float* __restrict__ qb,
    u16* __restrict__ q) {
  __shared__ float xs[128 * 65];
  __shared__ float ps[4][64], ps2[4][64];
  __shared__ float mu[64], rs[64];
  __shared__ __align__(16) u16 xsh[16 * GS];
  __shared__ __align__(16) u16 xsl[16 * GS];
  int bid = blockIdx.x, n = bid >> 8, t0 = (bid & 255) * 64;
  const u16* xb = inph + (size_t)n * C_ * HW_;
  #pragma unroll
  for (int it = 0; it < 8; ++it) {
    int i4 = it * 256 + threadIdx.x;           // 2048 ushort4 units
    int c = i4 >> 4, t4 = (i4 & 15) * 4;
    ushort4 v = *(const ushort4*)&xb[c * HW_ + t0 + t4];
    xs[c * 65 + t4 + 0] = bf2f(v.x);
    xs[c * 65 + t4 + 1] = bf2f(v.y);
    xs[c * 65 + t4 + 2] = bf2f(v.z);
    xs[c * 65 + t4 + 3] = bf2f(v.w);
  }
  __syncthreads();
  {
    int tt = threadIdx.x & 63, part = threadIdx.x >> 6;
    float s = 0.f, s2 = 0.f;
    for (int c = part * 32; c < part * 32 + 32; ++c) {
      float v = xs[c * 65 + tt];
      s += v; s2 += v * v;
    }
    ps[part][tt] = s; ps2[part][tt] = s2;
  }
  __syncthreads();
  if (threadIdx.x < 64) {
    int tt = threadIdx.x;
    float s  = ps[0][tt] + ps[1][tt] + ps[2][tt] + ps[3][tt];
    float s2 = ps2[0][tt] + ps2[1][tt] + ps2[2][tt] + ps2[3][tt];
    float m = s * (1.0f / 128.0f);
    float v = s2 * (1.0f / 128.0f) - m * m;
    mu[tt] = m; rs[tt] = rsqrtf(v + 1e-5f);
  }
  __syncthreads();
  for (int idx = threadIdx.x; idx < 8192; idx += 256) {
    int c = idx & 127, tt = idx >> 7;
    float v = (xs[c * 65 + tt] - mu[tt]) * rs[tt] * nw[c] + nb[c];
    u16 h, l; split2(v, h, l);
    int o = (c >> 3) * GS + tt * 8 + (c & 7);
    xsh[o] = h; xsl[o] = l;
  }
  __syncthreads();
  int wid = threadIdx.x >> 6, lane = threadIdx.x & 63;
  int r = lane & 15, g = lane >> 4;
  f32x4 acc[8] = {};
  #pragma unroll
  for (int kk = 0; kk < 4; ++kk) {
    bf16x8 ah = *(const bf16x8*)&xsh[(kk * 4 + g) * GS + (wid * 16 + r) * 8];
    bf16x8 al = *(const bf16x8*)&xsl[(kk * 4 + g) * GS + (wid * 16 + r) * 8];
    #pragma unroll
    for (int ct = 0; ct < 8; ++ct) {
      int o = ct * 16 + r;
      bf16x8 bh = *(const bf16x8*)&wh[o * 128 + kk * 32 + g * 8];
      bf16x8 bl = *(const bf16x8*)&wl[o * 128 + kk * 32 + g * 8];
      acc[ct] = MFMA(ah, bh, acc[ct]);
      acc[ct] = MFMA(ah, bl, acc[ct]);
      acc[ct] = MFMA(al, bh, acc[ct]);
    }
  }
  #pragma unroll
  for (int ct = 0; ct < 8; ++ct) {
    int col = ct * 16 + r;
    #pragma unroll
    for (int reg = 0; reg < 4; ++reg) {
      int row = wid * 16 + g * 4 + reg;
      q[((size_t)n * HW_ + t0 + row) * 128 + col] = f2bf_rne(acc[ct][reg] + qb[col]);
    }
  }
}

// ---------------------------------------------------------------------------
// generic 128-K GEMM via bf16x3 MFMA (final projection, in-place safe)
// ---------------------------------------------------------------------------
__global__ __launch_bounds__(256) void gemm128_mfma_kernel(
    const float* __restrict__ x, const u16* __restrict__ wh,
    const u16* __restrict__ wl, const float* __restrict__ b,
    float* __restrict__ out) {
  __shared__ __align__(16) u16 xsh[16 * GS];
  __shared__ __align__(16) u16 xsl[16 * GS];
  int r0 = blockIdx.x * 64;
  #pragma unroll
  for (int it = 0; it < 8; ++it) {
    int idx4 = it * 256 + threadIdx.x;       // 2048 float4s
    int row = idx4 >> 5, cg = idx4 & 31;
    float4 v = *(const float4*)&x[(size_t)(r0 + row) * 128 + cg * 4];
    ushort4 h4, l4; split4(v, h4, l4);
    int o = (cg >> 1) * GS + row * 8 + (cg & 1) * 4;
    *(ushort4*)&xsh[o] = h4; *(ushort4*)&xsl[o] = l4;
  }
  __syncthreads();
  int wid = threadIdx.x >> 6, lane = threadIdx.x & 63;
  int r = lane & 15, g = lane >> 4;
  f32x4 acc[8] = {};
  #pragma unroll
  for (int kk = 0; kk < 4; ++kk) {
    bf16x8 ah = *(const bf16x8*)&xsh[(kk * 4 + g) * GS + (wid * 16 + r) * 8];
    bf16x8 al = *(const bf16x8*)&xsl[(kk * 4 + g) * GS + (wid * 16 + r) * 8];
    #pragma unroll
    for (int ct = 0; ct < 8; ++ct) {
      int o = ct * 16 + r;
      bf16x8 bh = *(const bf16x8*)&wh[o * 128 + kk * 32 + g * 8];
      bf16x8 bl = *(const bf16x8*)&wl[o * 128 + kk * 32 + g * 8];
      acc[ct] = MFMA(ah, bh, acc[ct]);
      acc[ct] = MFMA(ah, bl, acc[ct]);
      acc[ct] = MFMA(al, bh, acc[ct]);
    }
  }
  #pragma unroll
  for (int ct = 0; ct < 8; ++ct) {
    int col = ct * 16 + r;
    #pragma unroll
    for (int reg = 0; reg < 4; ++reg) {
      int row = r0 + wid * 16 + g * 4 + reg;
      out[(size_t)row * 128 + col] = acc[ct][reg] + b[col];
    }
  }
}

// ---------------------------------------------------------------------------
// conv-as-GEMM v3: plain bf16, BM=128, uniform KSEG=256 (NT=8), all heads
// write fp32 K-split partials. LDS-staged A + W, pipelined.
// ---------------------------------------------------------------------------
template <int P, int NW, int SEG>
__device__ __forceinline__ void conv_body(
    int mblk, int seg, const u16* __restrict__ inph,
    const u16* __restrict__ wh, float* __restrict__ dst,
    u16* ash, u16* wsh) {
  constexpr int K    = 128 * P * P;
  constexpr int KSEG = K / SEG;              // 256 everywhere
  constexpr int NT   = KSEG / 32;            // 8
  constexpr int HWIN = H_ / NW;
  constexpr int G    = HWIN / P;
  constexpr int L    = G * G;
  constexpr int M    = 4 * NW * NW * L;
  constexpr int LGL  = (L == 256) ? 8 : 6;
  constexpr int LGG  = (G == 16) ? 4 : 3;
  constexpr int LGNW = (NW == 8) ? 3 : (NW == 4) ? 2 : (NW == 2) ? 1 : 0;
  constexpr int LGP  = (P == 8) ? 3 : (P == 4) ? 2 : 1;
  constexpr int LGP2 = 2 * LGP;
  int tid = threadIdx.x, wid = tid >> 6, lane = tid & 63;
  int r = lane & 15, g = lane >> 4;
  int t0 = mblk * 128;
  int kq = tid & 7;
  int kbase = seg * KSEG;

  size_t rbase[4];
  #pragma unroll
  for (int hh = 0; hh < 4; ++hh) {
    int row = (tid >> 3) + hh * 32;
    int tglob = t0 + row;
    int bwin = tglob >> LGL;
    int loc  = tglob & (L - 1);
    int n    = bwin >> (2 * LGNW);
    int wrem = bwin & (NW * NW - 1);
    int wy = wrem >> LGNW, wx = wrem & (NW - 1);
    int oh = loc >> LGG,   ow = loc & (G - 1);
    rbase[hh] = (size_t)n * C_ * HW_ + (size_t)(wy * HWIN + oh * P) * W_ +
                wx * HWIN + ow * P;
  }
  int ldso = (kq >> 1) * GSA + (tid >> 3) * 8 + (kq & 1) * 4;
  int wo = tid >> 2, wpart = tid & 3;
  const u16* wrowh = wh + (size_t)wo * K + kbase + wpart * 8;
  int wlo_ = wo * 40 + wpart * 8;

  f32x4 acc[2][4] = {};
  ushort4 avh[4];
  uint4 wvh;

  auto LOADSTEP = [&](int kt) {
    int k = kbase + kt * 32 + kq * 4;
    int ci = k >> LGP2;
    int wp = k & (P * P - 1);
    if constexpr (P >= 4) {
      int kh = wp >> LGP, kw = wp & (P - 1);
      size_t koff = (size_t)ci * HW_ + kh * W_ + kw;
      #pragma unroll
      for (int hh = 0; hh < 4; ++hh)
        avh[hh] = *(const ushort4*)&inph[rbase[hh] + koff];
    } else {
      size_t koff = (size_t)ci * HW_;
      #pragma unroll
      for (int hh = 0; hh < 4; ++hh) {
        union { uint2 u; ushort4 s; } cv;
        cv.u.x = *(const u32*)&inph[rbase[hh] + koff];
        cv.u.y = *(const u32*)&inph[rbase[hh] + koff + W_];
        avh[hh] = cv.s;
      }
    }
    wvh = *(const uint4*)(wrowh + kt * 32);
  };

  LOADSTEP(0);
  for (int kt = 0; kt < NT; ++kt) {
    __syncthreads();
    #pragma unroll
    for (int hh = 0; hh < 4; ++hh)
      *(ushort4*)&ash[ldso + hh * 256] = avh[hh];
    *(uint4*)&wsh[wlo_] = wvh;
    __syncthreads();
    if (kt + 1 < NT) LOADSTEP(kt + 1);
    #pragma unroll
    for (int mrep = 0; mrep < 2; ++mrep) {
      int arow = wid * 32 + mrep * 16 + r;
      bf16x8 ahf = *(const bf16x8*)&ash[g * GSA + arow * 8];
      #pragma unroll
      for (int ct = 0; ct < 4; ++ct) {
        bf16x8 bh = *(const bf16x8*)&wsh[(ct * 16 + r) * 40 + g * 8];
        acc[mrep][ct] = MFMA(ahf, bh, acc[mrep][ct]);
      }
    }
  }
  #pragma unroll
  for (int mrep = 0; mrep < 2; ++mrep) {
    #pragma unroll
    for (int ct = 0; ct < 4; ++ct) {
      int o = ct * 16 + r;
      #pragma unroll
      for (int reg = 0; reg < 4; ++reg) {
        int row = t0 + wid * 32 + mrep * 16 + g * 4 + reg;
        dst[((size_t)seg * M + row) * 64 + o] = acc[mrep][ct][reg];
      }
    }
  }
}

__global__ __launch_bounds__(256) void conv_mfma_kernel(
    const u16* __restrict__ inph, const u16* __restrict__ wsh_g,
    float* __restrict__ part) {
  __shared__ __align__(16) u16 ash[4 * GSA];
  __shared__ __align__(16) u16 wsh[64 * 40];
  int bid = blockIdx.x;
  if (bid < 256) {            // head1: 8 mblk x 32 seg
    conv_body<8, 1, 32>(bid >> 5, bid & 31, inph, wsh_g + OS1, part, ash, wsh);
  } else if (bid < 512) {     // head2: 32 mblk x 8 seg
    int lb = bid - 256;
    conv_body<4, 2, 8>(lb >> 3, lb & 7, inph, wsh_g + OS2, part + 2097152,
                       ash, wsh);
  } else if (bid < 768) {     // head3: 32 mblk x 8 seg
    int lb = bid - 512;
    conv_body<4, 4, 8>(lb >> 3, lb & 7, inph, wsh_g + OS3, part + 4194304,
                       ash, wsh);
  } else {                    // head4: 128 mblk x 2 seg
    int lb = bid - 768;
    conv_body<2, 8, 2>(lb >> 1, lb & 1, inph, wsh_g + OS4, part + 6291456,
                       ash, wsh);
  }
}

// reduce K-split partials + conv bias, all heads -> y (25600 tokens)
__global__ __launch_bounds__(256) void reduce_kernel(
    const float* __restrict__ part, const float* __restrict__ b1,
    const float* __restrict__ b2, const float* __restrict__ b3,
    const float* __restrict__ b4, float* __restrict__ y) {
  int idx = blockIdx.x * 256 + threadIdx.x;   // grid exactly 1,638,400/256=6400
  int tg = idx >> 6, o = idx & 63;
  float s;
  if (tg < 1024) {
    s = b1[o];
    #pragma unroll
    for (int sg = 0; sg < 32; ++sg) s += part[((size_t)sg * 1024 + tg) * 64 + o];
  } else if (tg < 5120) {
    int t = tg - 1024;
    const float* p2 = part + 2097152;
    s = b2[o];
    #pragma unroll
    for (int sg = 0; sg < 8; ++sg) s += p2[((size_t)sg * 4096 + t) * 64 + o];
  } else if (tg < 9216) {
    int t = tg - 5120;
    const float* p3 = part + 4194304;
    s = b3[o];
    #pragma unroll
    for (int sg = 0; sg < 8; ++sg) s += p3[((size_t)sg * 4096 + t) * 64 + o];
  } else {
    int t = tg - 9216;
    const float* p4 = part + 6291456;
    s = b4[o] + p4[(size_t)t * 64 + o] + p4[((size_t)16384 + t) * 64 + o];
  }
  y[(size_t)tg * 64 + o] = s;
}

// ---------------------------------------------------------------------------
// fused LN(64) + exact GELU + KV projection (MFMA). 64 tokens/block, 400 blocks.
// K out bf16 [token][32]; V out bf16 window-transposed [d][k].
// ---------------------------------------------------------------------------
struct LnkvArgs { const float* lnw[4]; const float* lnb[4]; const float* kvb[4]; };

__global__ __launch_bounds__(256) void lnkv_mfma_kernel(
    const float* __restrict__ y, const u16* __restrict__ kvwh,
    const u16* __restrict__ kvwl, LnkvArgs a,
    u16* __restrict__ kb, u16* __restrict__ vbT) {
  __shared__ float ych[64 * 65];
  __shared__ __align__(16) u16 ash[8 * GS];
  __shared__ __align__(16) u16 asl[8 * GS];
  int bid = blockIdx.x, tid = threadIdx.x;
  int tb = bid * 64;
  int h  = (tb < 1024) ? 0 : (tb < 5120) ? 1 : (tb < 9216) ? 2 : 3;
  int hb = (h == 0) ? 0 : (h == 1) ? 1024 : (h == 2) ? 5120 : 9216;
  #pragma unroll
  for (int it = 0; it < 4; ++it) {
    int i4 = it * 256 + tid;            // 1024 float4s
    int row = i4 >> 4, cg = i4 & 15;
    float4 v = *(const float4*)&y[(size_t)(tb + row) * 64 + cg * 4];
    *(float4*)&ych[row * 65 + cg * 4] = v;
  }
  __syncthreads();
  {
    int tt = tid >> 2, p = tid & 3;
    const float* xr = &ych[tt * 65 + p * 16];
    float s = 0.f, s2 = 0.f;
    #pragma unroll
    for (int i = 0; i < 16; ++i) { float v = xr[i]; s += v; s2 += v * v; }
    s  += __shfl_xor(s, 1, 64);  s  += __shfl_xor(s, 2, 64);
    s2 += __shfl_xor(s2, 1, 64); s2 += __shfl_xor(s2, 2, 64);
    float mean = s * (1.0f / 64.0f);
    float var  = s2 * (1.0f / 64.0f) - mean * mean;
    float rstd = rsqrtf(var + 1e-5f);
    const float* lnw = a.lnw[h];
    const float* lnb = a.lnb[h];
    #pragma unroll
    for (int i = 0; i < 16; ++i) {
      int ch = p * 16 + i;
      float xn = (xr[i] - mean) * rstd * lnw[ch] + lnb[ch];
      float gg = 0.5f * xn * (1.0f + erff(xn * 0.70710678118654752f));
      u16 hh, ll; split2(gg, hh, ll);
      int o = (ch >> 3) * GS + tt * 8 + (ch & 7);
      ash[o] = hh; asl[o] = ll;
    }
  }
  __syncthreads();
  int wid = tid >> 6, lane = tid & 63, r = lane & 15, g = lane >> 4;
  const u16* wbh = kvwh + h * 4096;
  const u16* wbl = kvwl + h * 4096;
  f32x4 acc[4] = {};
  #pragma unroll
  for (int kk = 0; kk < 2; ++kk) {
    bf16x8 ah = *(const bf16x8*)&ash[(kk * 4 + g) * GS + (wid * 16 + r) * 8];
    bf16x8 al = *(const bf16x8*)&asl[(kk * 4 + g) * GS + (wid * 16 + r) * 8];
    #pragma unroll
    for (int ct = 0; ct < 4; ++ct) {
      bf16x8 bh = *(const bf16x8*)&wbh[(ct * 16 + r) * 64 + kk * 32 + g * 8];
      bf16x8 bl = *(const bf16x8*)&wbl[(ct * 16 + r) * 64 + kk * 32 + g * 8];
      acc[ct] = MFMA(ah, bh, acc[ct]);
      acc[ct] = MFMA(ah, bl, acc[ct]);
      acc[ct] = MFMA(al, bh, acc[ct]);
    }
  }
  const float* kvb = a.kvb[h];
  int lk = (h < 2) ? 256 : 64;
  #pragma unroll
  for (int ct = 0; ct < 4; ++ct) {
    int o = ct * 16 + r;
    float bias = kvb[o];
    #pragma unroll
    for (int reg = 0; reg < 4; ++reg) {
      int row = wid * 16 + g * 4 + reg;
      int tg  = tb + row;
      float v = acc[ct][reg] + bias;
      if (o < 32) {
        kb[(size_t)tg * 32 + o] = f2bf_rne(v);
      } else {
        int dd = o - 32;
        int kl = (tg - hb) & (lk - 1);
        int wstart = tg - kl;
        vbT[(size_t)wstart * 32 + dd * lk + kl] = f2bf_rne(v);
      }
    }
  }
}

// ---------------------------------------------------------------------------
// MFMA attention v3: block = 256 queries (4 waves x 4 tiles), K/V staged in LDS
// once per block; single per-wave P scratch; SCALE folded into exp arg;
// tq loop kept rolled to cap VGPR (occupancy-bound kernel).
// ---------------------------------------------------------------------------
template <int NW, int LK>
__device__ __forceinline__ void attn_v2_body(
    int bid, int head, int head_off, const u16* __restrict__ q,
    const u16* __restrict__ kb, const u16* __restrict__ vbT,
    float* __restrict__ cbuf) {
  constexpr int HWIN = H_ / NW;
  constexpr int LQ   = HWIN * HWIN;
  constexpr int BPW  = LQ / 256;          // blocks per window
  constexpr int NCT  = LK / 16;
  constexpr int NST  = LK / 32;
  constexpr int KS   = 40;                // K row stride (u16), 80B
  constexpr int VS   = LK + 8;            // V row stride (u16)
  extern __shared__ __align__(16) u16 alds[];
  u16* klds = alds;                       // [LK][KS]
  u16* vlds = alds + LK * KS;             // [32][VS]
  u16* plds = vlds + 32 * VS;             // 4 waves x 16 x KS (single buffer)
  int tid = threadIdx.x, wid = tid >> 6, lane = tid & 63;
  int g = lane >> 4, c = lane & 15;
  int win  = bid / BPW;
  int n = win / (NW * NW);
  int wrem = win % (NW * NW);
  int wy = wrem / NW, wx = wrem % NW;
  int kstart = head_off + win * LK;

  // cooperative K/V staging (coalesced 16B chunks)
  const u16* kgl = kb  + (size_t)kstart * 32;
  const u16* vgl = vbT + (size_t)kstart * 32;
  for (int ch = tid; ch < LK * 4; ch += 256) {
    int key = ch >> 2, gg = ch & 3;
    *(uint4*)&klds[key * KS + gg * 8] = *(const uint4*)&kgl[ch * 8];
  }
  for (int ch = tid; ch < LK * 4; ch += 256) {   // 32*LK/8 == LK*4
    int d = ch / (LK / 8), pos = ch % (LK / 8);
    *(uint4*)&vlds[d * VS + pos * 8] = *(const uint4*)&vgl[ch * 8];
  }
  __syncthreads();

  u16* pw0 = plds + wid * 16 * KS;
  f32x4 zero4 = {0.f, 0.f, 0.f, 0.f};

  #pragma unroll 1
  for (int tq = 0; tq < 4; ++tq) {
    int tIdx = (bid % BPW) * 16 + wid * 4 + tq;
    int j = tIdx * 16 + c;
    int ih = j / HWIN, iw = j % HWIN;
    int t = (wy * HWIN + ih) * W_ + wx * HWIN + iw;
    bf16x8 qa = *(const bf16x8*)&q[((size_t)n * HW_ + t) * 128 + head * 32 + g * 8];

    // S = Q K^T from LDS K (raw scores; SCALE folded into exp below)
    f32x4 sacc[NCT];
    #pragma unroll
    for (int ct = 0; ct < NCT; ++ct) {
      bf16x8 kf = *(const bf16x8*)&klds[(ct * 16 + c) * KS + g * 8];
      sacc[ct] = MFMA(qa, kf, zero4);
    }
    // softmax per row: max over raw s (SCALE>0), e = exp((s-mx)*SCALE)
    #pragma unroll
    for (int reg = 0; reg < 4; ++reg) {
      float mx = -1e30f;
      #pragma unroll
      for (int ct = 0; ct < NCT; ++ct) mx = fmaxf(mx, sacc[ct][reg]);
      mx = fmaxf(mx, __shfl_xor(mx, 1, 64));
      mx = fmaxf(mx, __shfl_xor(mx, 2, 64));
      mx = fmaxf(mx, __shfl_xor(mx, 4, 64));
      mx = fmaxf(mx, __shfl_xor(mx, 8, 64));
      float sm = 0.f;
      #pragma unroll
      for (int ct = 0; ct < NCT; ++ct) {
        float e = __expf((sacc[ct][reg] - mx) * SCALE_);
        sacc[ct][reg] = e;
        sm += e;
      }
      sm += __shfl_xor(sm, 1, 64);
      sm += __shfl_xor(sm, 2, 64);
      sm += __shfl_xor(sm, 4, 64);
      sm += __shfl_xor(sm, 8, 64);
      float inv = 1.0f / sm;
      #pragma unroll
      for (int ct = 0; ct < NCT; ++ct) sacc[ct][reg] *= inv;
    }
    // PV with per-st P scratch (16x32, wave-private, single buffer)
    f32x4 oacc[2] = {};
    #pragma unroll
    for (int st = 0; st < NST; ++st) {
      #pragma unroll
      for (int ct2 = 0; ct2 < 2; ++ct2) {
        int ct = st * 2 + ct2;
        #pragma unroll
        for (int reg = 0; reg < 4; ++reg)
          pw0[(g * 4 + reg) * KS + ct2 * 16 + c] = f2bf_rne(sacc[ct][reg]);
      }
      bf16x8 pa = *(const bf16x8*)&pw0[c * KS + g * 8];
      #pragma unroll
      for (int dt = 0; dt < 2; ++dt) {
        bf16x8 vf = *(const bf16x8*)&vlds[(dt * 16 + c) * VS + st * 32 + g * 8];
        oacc[dt] = MFMA(pa, vf, oacc[dt]);
      }
    }
    // write O (C layout: col=c -> d, row=g*4+reg -> q local)
    #pragma unroll
    for (int reg = 0; reg < 4; ++reg) {
      int jo = tIdx * 16 + g * 4 + reg;
      int iho = jo / HWIN, iwo = jo % HWIN;
      int to = (wy * HWIN + iho) * W_ + wx * HWIN + iwo;
      float* op = cbuf + ((size_t)n * HW_ + to) * 128 + head * 32;
      op[c]      = oacc[0][reg];
      op[16 + c] = oacc[1][reg];
    }
  }
}

__global__ __launch_bounds__(256) void attn01_kernel(
    const u16* __restrict__ q, const u16* __restrict__ kb,
    const u16* __restrict__ vbT, float* __restrict__ cbuf) {
  int bid = blockIdx.x;
  if (bid < 256) attn_v2_body<1, 256>(bid,       0, 0,    q, kb, vbT, cbuf);
  else           attn_v2_body<2, 256>(bid - 256, 1, 1024, q, kb, vbT, cbuf);
}

__global__ __launch_bounds__(256) void attn23_kernel(
    const u16* __restrict__ q, const u16* __restrict__ kb,
    const u16* __restrict__ vbT, float* __restrict__ cbuf) {
  int bid = blockIdx.x;
  if (bid < 256) attn_v2_body<4, 64>(bid,       2, 5120, q, kb, vbT, cbuf);
  else           attn_v2_body<8, 64>(bid - 256, 3, 9216, q, kb, vbT, cbuf);
}

// ---------------------------------------------------------------------------
extern "C" void kernel_launch(void* const* d_in, const int* in_sizes, int n_in,
                              void* d_out, int out_size, void* d_ws, size_t ws_size,
                              hipStream_t stream) {
  const float* inp = (const float*)d_in[0];
  const float* nw  = (const float*)d_in[1];
  const float* nb  = (const float*)d_in[2];
  const float* qw  = (const float*)d_in[3];
  const float* qb  = (const float*)d_in[4];
  const float* pw  = (const float*)d_in[29];
  const float* pb  = (const float*)d_in[30];

  float* ws   = (float*)d_ws;
  u16*   qb16 = (u16*)(ws + QB_OFF);
  float* y    = ws + Y_OFF;
  u16*   kb   = (u16*)(ws + KB_OFF);
  u16*   vbT  = (u16*)(ws + VT_OFF);
  float* part = ws + PART_OFF;
  u16*   wsp  = (u16*)(ws + WSP_OFF);
  u16*   whi  = wsp;
  u16*   wlo  = wsp + TOTW;
  u16*   inph = (u16*)(ws + INH_OFF);
  float* cbuf = (float*)d_out;

  // 0) prep: input -> bf16, weights -> bf16 hi/lo (one launch)
  prep_kernel<<<8192 + TOTW / 256, 256, 0, stream>>>(
      inp, qw, pw, (const float*)d_in[5], (const float*)d_in[11],
      (const float*)d_in[17], (const float*)d_in[23],
      (const float*)d_in[9], (const float*)d_in[15],
      (const float*)d_in[21], (const float*)d_in[27], whi, wlo, inph);

  // 1) fused LN + Q projection (MFMA) -> bf16 q
  lnq_mfma_kernel<<<1024, 256, 0, stream>>>(inph, nw, nb, whi + OQW, wlo + OQW,
                                            qb, qb16);

  // 2) all 4 patch-embed convs, plain bf16, uniform K-split (1024 blocks)
  conv_mfma_kernel<<<1024, 256, 0, stream>>>(inph, whi, part);

  // 3) wide reduce of K-split partials + bias -> y (all heads)
  reduce_kernel<<<6400, 256, 0, stream>>>(part, (const float*)d_in[6],
                                          (const float*)d_in[12],
                                          (const float*)d_in[18],
                                          (const float*)d_in[24], y);

  // 4) fused LN + GELU + KV projection (MFMA)
  LnkvArgs la;
  la.lnw[0] = (const float*)d_in[7];  la.lnb[0] = (const float*)d_in[8];
  la.kvb[0] = (const float*)d_in[10];
  la.lnw[1] = (const float*)d_in[13]; la.lnb[1] = (const float*)d_in[14];
  la.kvb[1] = (const float*)d_in[16];
  la.lnw[2] = (const float*)d_in[19]; la.lnb[2] = (const float*)d_in[20];
  la.kvb[2] = (const float*)d_in[22];
  la.lnw[3] = (const float*)d_in[25]; la.lnb[3] = (const float*)d_in[26];
  la.kvb[3] = (const float*)d_in[28];
  lnkv_mfma_kernel<<<400, 256, 0, stream>>>(y, whi + OKV, wlo + OKV, la, kb, vbT);

  // 5) MFMA attention, split launches (per-variant regalloc + LDS)
  // heads 0,1: LDS = (256*40 + 32*264 + 4*16*40) u16 = 42496 B
  attn01_kernel<<<512, 256, 42496, stream>>>(qb16, kb, vbT, cbuf);
  // heads 2,3: LDS = (64*40 + 32*72 + 4*16*40) u16 = 14848 B
  attn23_kernel<<<512, 256, 14848, stream>>>(qb16, kb, vbT, cbuf);

  // 6) final projection, in place on d_out (MFMA)
  gemm128_mfma_kernel<<<1024, 256, 0, stream>>>(cbuf, whi + OPW, wlo + OPW, pb,
                                                (float*)d_out);
}

// Round 13
// 163.932 us; speedup vs baseline: 1.5787x; 1.0234x over previous
//
#include <hip/hip_runtime.h>
#include <math.h>

#define N_   4
#define C_   128
#define H_   128
#define W_   128
#define HW_  16384
#define SCALE_ 0.17677669529663687f   // 32^-0.5

typedef unsigned short u16;
typedef unsigned int   u32;
typedef __bf16 bf16x8 __attribute__((ext_vector_type(8)));
typedef float  f32x4  __attribute__((ext_vector_type(4)));

#define MFMA(a, b, c) __builtin_amdgcn_mfma_f32_16x16x32_bf16((a), (b), (c), 0, 0, 0)

// ---- ws float offsets -------------------------------------------------------
#define QB_OFF   0            // 4,194,304 floats (8,388,608 u16 bf16 q)
#define Y_OFF    4194304      // 1,638,400 (all heads, post-reduce + bias)
#define KB_OFF   5832704      //   409,600 floats (819,200 u16 bf16 K)
#define VT_OFF   6242304      //   409,600 floats (819,200 u16 bf16 V^T)
#define PART_OFF 6651904      // 8,388,608 (4 heads x 2,097,152); cbuf16 aliases
#define WSP_OFF  15040512     //   868,352 floats (2 x 868,352 u16 hi+lo)
#define INH_OFF  15908864     // 4,194,304 floats (8,388,608 u16 bf16 input)
#define SCB_OFF  20103168     //       256 floats (S[128], cb[128])
// total 20,103,424 floats = 80.4 MB

// split-weight region offsets (u16 units, within hi or lo half)
#define OQW 0
#define OPW 16384
#define OS1 32768
#define OS2 557056
#define OS3 688128
#define OS4 819200
#define OKV 851968
#define TOTW 868352

#define GS  520    // A-LDS kgroup stride (64-row tiles), u16
#define GSA 1032   // A-LDS kgroup stride (128-row conv tiles), u16

// ---------------------------------------------------------------------------
__device__ __forceinline__ u16 f2bf_rne(float x) {
  unsigned u = __float_as_uint(x);
  return (u16)((u + 0x7FFFu + ((u >> 16) & 1u)) >> 16);
}
__device__ __forceinline__ float bf2f(u16 x) {
  return __uint_as_float((u32)x << 16);
}
__device__ __forceinline__ void split2(float v, u16& h, u16& l) {
  unsigned u = __float_as_uint(v);
  unsigned hb = (u + 0x7FFFu + ((u >> 16) & 1u)) & 0xFFFF0000u;
  h = (u16)(hb >> 16);
  float lf = v - __uint_as_float(hb);
  l = f2bf_rne(lf);
}
__device__ __forceinline__ void split4(float4 v, ushort4& h, ushort4& l) {
  split2(v.x, h.x, l.x); split2(v.y, h.y, l.y);
  split2(v.z, h.z, l.z); split2(v.w, h.w, l.w);
}

// ---------------------------------------------------------------------------
// prep: [bid<8192]       input fp32 -> bf16 (hi only)
//       [8192..+3392)    weights fp32 -> bf16 hi/lo; qw region holds w'=nw*qw
//       [last block]     S[o] = sum_c w'[o][c]; cb[o] = nb.qw[o] + qb[o]
// ---------------------------------------------------------------------------
__global__ __launch_bounds__(256) void prep_kernel(
    const float* __restrict__ inp, const float* __restrict__ qw,
    const float* __restrict__ pw, const float* __restrict__ s1,
    const float* __restrict__ s2, const float* __restrict__ s3,
    const float* __restrict__ s4, const float* __restrict__ kv1,
    const float* __restrict__ kv2, const float* __restrict__ kv3,
    const float* __restrict__ kv4, const float* __restrict__ nw,
    const float* __restrict__ nb, const float* __restrict__ qb,
    u16* __restrict__ hi, u16* __restrict__ lo, u16* __restrict__ inph,
    float* __restrict__ scb) {
  int bid = blockIdx.x;
  if (bid < 8192) {
    int idx = bid * 256 + threadIdx.x;        // float4 units over 8,388,608 f
    float4 v = *(const float4*)&inp[(size_t)idx * 4];
    ushort4 h4;
    h4.x = f2bf_rne(v.x); h4.y = f2bf_rne(v.y);
    h4.z = f2bf_rne(v.z); h4.w = f2bf_rne(v.w);
    *(ushort4*)&inph[(size_t)idx * 4] = h4;
  } else if (bid < 8192 + TOTW / 256) {
    int idx = (bid - 8192) * 256 + threadIdx.x;   // < TOTW
    const float* src; int off;
    float mul = 1.0f;
    if      (idx < OPW)  { src = qw; off = idx; mul = nw[idx & 127]; }
    else if (idx < OS1)  { src = pw; off = idx - OPW; }
    else if (idx < OS2)  { src = s1; off = idx - OS1; }
    else if (idx < OS3)  { src = s2; off = idx - OS2; }
    else if (idx < OS4)  { src = s3; off = idx - OS3; }
    else if (idx < OKV)  { src = s4; off = idx - OS4; }
    else {
      int j = idx - OKV;
      int h = j >> 12; off = j & 4095;
      src = (h == 0) ? kv1 : (h == 1) ? kv2 : (h == 2) ? kv3 : kv4;
    }
    u16 h, l; split2(src[off] * mul, h, l);
    hi[idx] = h; lo[idx] = l;
  } else {
    int o = threadIdx.x;
    if (o < 128) {
      float S = 0.f, cbv = qb[o];
      const float* wr = qw + o * 128;
      for (int c = 0; c < 128; ++c) {
        float w = wr[c];
        S   += w * nw[c];
        cbv += w * nb[c];
      }
      scb[o]       = S;
      scb[128 + o] = cbv;
    }
  }
}

// ---------------------------------------------------------------------------
// fused LN + Q-projection, LN folded into epilogue:
// q[t][o] = rs[t]*(x[t].w'[o] - mu[t]*S[o]) + cb[o].  A = raw bf16 x.
// ---------------------------------------------------------------------------
__global__ __launch_bounds__(256) void lnq_mfma_kernel(
    const u16* __restrict__ inph, const u16* __restrict__ wh,
    const u16* __restrict__ wl, const float* __restrict__ scb,
    u16* __restrict__ q) {
  __shared__ __align__(16) u16 xst[16 * GS];
  __shared__ float ps[4][64], ps2[4][64];
  __shared__ float mus[64], rss[64];
  int tid = threadIdx.x;
  int bid = blockIdx.x, n = bid >> 8, t0 = (bid & 255) * 64;
  const u16* xb = inph + (size_t)n * C_ * HW_;
  // phase 1: coalesced load -> A-frag scatter + register LN stats
  float s0 = 0.f, s1 = 0.f, s2v = 0.f, s3 = 0.f;
  float q0 = 0.f, q1 = 0.f, q2 = 0.f, q3 = 0.f;
  #pragma unroll
  for (int it = 0; it < 8; ++it) {
    int i4 = it * 256 + tid;                 // 2048 ushort4 units
    int c = i4 >> 4;                         // 0..127 (fixed t4 per thread)
    int t4 = (i4 & 15) * 4;
    ushort4 v = *(const ushort4*)&xb[c * HW_ + t0 + t4];
    int base = (c >> 3) * GS + (c & 7);
    xst[base + (t4 + 0) * 8] = v.x;
    xst[base + (t4 + 1) * 8] = v.y;
    xst[base + (t4 + 2) * 8] = v.z;
    xst[base + (t4 + 3) * 8] = v.w;
    float f0 = bf2f(v.x), f1 = bf2f(v.y), f2 = bf2f(v.z), f3 = bf2f(v.w);
    s0 += f0; q0 += f0 * f0;
    s1 += f1; q1 += f1 * f1;
    s2v += f2; q2 += f2 * f2;
    s3 += f3; q3 += f3 * f3;
  }
  // reduce across the 4 lanes sharing this token group (l, l^16, l^32)
  s0 += __shfl_xor(s0, 16, 64); s0 += __shfl_xor(s0, 32, 64);
  s1 += __shfl_xor(s1, 16, 64); s1 += __shfl_xor(s1, 32, 64);
  s2v += __shfl_xor(s2v, 16, 64); s2v += __shfl_xor(s2v, 32, 64);
  s3 += __shfl_xor(s3, 16, 64); s3 += __shfl_xor(s3, 32, 64);
  q0 += __shfl_xor(q0, 16, 64); q0 += __shfl_xor(q0, 32, 64);
  q1 += __shfl_xor(q1, 16, 64); q1 += __shfl_xor(q1, 32, 64);
  q2 += __shfl_xor(q2, 16, 64); q2 += __shfl_xor(q2, 32, 64);
  q3 += __shfl_xor(q3, 16, 64); q3 += __shfl_xor(q3, 32, 64);
  int lane = tid & 63, wave = tid >> 6;
  if (lane < 16) {
    int tk = lane * 4;
    ps[wave][tk + 0] = s0;  ps2[wave][tk + 0] = q0;
    ps[wave][tk + 1] = s1;  ps2[wave][tk + 1] = q1;
    ps[wave][tk + 2] = s2v; ps2[wave][tk + 2] = q2;
    ps[wave][tk + 3] = s3;  ps2[wave][tk + 3] = q3;
  }
  __syncthreads();
  if (tid < 64) {
    float s  = ps[0][tid] + ps[1][tid] + ps[2][tid] + ps[3][tid];
    float s2 = ps2[0][tid] + ps2[1][tid] + ps2[2][tid] + ps2[3][tid];
    float m = s * (1.0f / 128.0f);
    float v = s2 * (1.0f / 128.0f) - m * m;
    mus[tid] = m;
    rss[tid] = rsqrtf(v + 1e-5f);
  }
  __syncthreads();
  // phase 2: MFMA (raw x  .  w' hi/lo)
  int wid = tid >> 6;
  int r = lane & 15, g = lane >> 4;
  f32x4 acc[8] = {};
  #pragma unroll
  for (int kk = 0; kk < 4; ++kk) {
    bf16x8 ah = *(const bf16x8*)&xst[(kk * 4 + g) * GS + (wid * 16 + r) * 8];
    #pragma unroll
    for (int ct = 0; ct < 8; ++ct) {
      int o = ct * 16 + r;
      bf16x8 bh = *(const bf16x8*)&wh[o * 128 + kk * 32 + g * 8];
      bf16x8 bl = *(const bf16x8*)&wl[o * 128 + kk * 32 + g * 8];
      acc[ct] = MFMA(ah, bh, acc[ct]);
      acc[ct] = MFMA(ah, bl, acc[ct]);
    }
  }
  // epilogue: affine LN fold
  #pragma unroll
  for (int ct = 0; ct < 8; ++ct) {
    int col = ct * 16 + r;
    float S  = scb[col];
    float cb = scb[128 + col];
    #pragma unroll
    for (int reg = 0; reg < 4; ++reg) {
      int row = wid * 16 + g * 4 + reg;
      float val = rss[row] * (acc[ct][reg] - mus[row] * S) + cb;
      q[((size_t)n * HW_ + t0 + row) * 128 + col] = f2bf_rne(val);
    }
  }
}

// ---------------------------------------------------------------------------
// final projection: bf16 input (from attention), w hi/lo, fp32 out + bias
// ---------------------------------------------------------------------------
__global__ __launch_bounds__(256) void proj_mfma_kernel(
    const u16* __restrict__ x16, const u16* __restrict__ wh,
    const u16* __restrict__ wl, const float* __restrict__ b,
    float* __restrict__ out) {
  __shared__ __align__(16) u16 xst[16 * GS];
  int r0 = blockIdx.x * 64;
  #pragma unroll
  for (int it = 0; it < 4; ++it) {
    int i4 = it * 256 + threadIdx.x;        // 1024 uint4 units
    int row = i4 >> 4, cg = i4 & 15;
    *(uint4*)&xst[cg * GS + row * 8] =
        *(const uint4*)&x16[(size_t)(r0 + row) * 128 + cg * 8];
  }
  __syncthreads();
  int wid = threadIdx.x >> 6, lane = threadIdx.x & 63;
  int r = lane & 15, g = lane >> 4;
  f32x4 acc[8] = {};
  #pragma unroll
  for (int kk = 0; kk < 4; ++kk) {
    bf16x8 ah = *(const bf16x8*)&xst[(kk * 4 + g) * GS + (wid * 16 + r) * 8];
    #pragma unroll
    for (int ct = 0; ct < 8; ++ct) {
      int o = ct * 16 + r;
      bf16x8 bh = *(const bf16x8*)&wh[o * 128 + kk * 32 + g * 8];
      bf16x8 bl = *(const bf16x8*)&wl[o * 128 + kk * 32 + g * 8];
      acc[ct] = MFMA(ah, bh, acc[ct]);
      acc[ct] = MFMA(ah, bl, acc[ct]);
    }
  }
  #pragma unroll
  for (int ct = 0; ct < 8; ++ct) {
    int col = ct * 16 + r;
    #pragma unroll
    for (int reg = 0; reg < 4; ++reg) {
      int row = r0 + wid * 16 + g * 4 + reg;
      out[(size_t)row * 128 + col] = acc[ct][reg] + b[col];
    }
  }
}

// ---------------------------------------------------------------------------
// conv-as-GEMM v3: plain bf16, BM=128, uniform KSEG=256 (NT=8), all heads
// write fp32 K-split partials. LDS-staged A + W, pipelined.
// ---------------------------------------------------------------------------
template <int P, int NW, int SEG>
__device__ __forceinline__ void conv_body(
    int mblk, int seg, const u16* __restrict__ inph,
    const u16* __restrict__ wh, float* __restrict__ dst,
    u16* ash, u16* wsh) {
  constexpr int K    = 128 * P * P;
  constexpr int KSEG = K / SEG;              // 256 everywhere
  constexpr int NT   = KSEG / 32;            // 8
  constexpr int HWIN = H_ / NW;
  constexpr int G    = HWIN / P;
  constexpr int L    = G * G;
  constexpr int M    = 4 * NW * NW * L;
  constexpr int LGL  = (L == 256) ? 8 : 6;
  constexpr int LGG  = (G == 16) ? 4 : 3;
  constexpr int LGNW = (NW == 8) ? 3 : (NW == 4) ? 2 : (NW == 2) ? 1 : 0;
  constexpr int LGP  = (P == 8) ? 3 : (P == 4) ? 2 : 1;
  constexpr int LGP2 = 2 * LGP;
  int tid = threadIdx.x, wid = tid >> 6, lane = tid & 63;
  int r = lane & 15, g = lane >> 4;
  int t0 = mblk * 128;
  int kq = tid & 7;
  int kbase = seg * KSEG;

  size_t rbase[4];
  #pragma unroll
  for (int hh = 0; hh < 4; ++hh) {
    int row = (tid >> 3) + hh * 32;
    int tglob = t0 + row;
    int bwin = tglob >> LGL;
    int loc  = tglob & (L - 1);
    int n    = bwin >> (2 * LGNW);
    int wrem = bwin & (NW * NW - 1);
    int wy = wrem >> LGNW, wx = wrem & (NW - 1);
    int oh = loc >> LGG,   ow = loc & (G - 1);
    rbase[hh] = (size_t)n * C_ * HW_ + (size_t)(wy * HWIN + oh * P) * W_ +
                wx * HWIN + ow * P;
  }
  int ldso = (kq >> 1) * GSA + (tid >> 3) * 8 + (kq & 1) * 4;
  int wo = tid >> 2, wpart = tid & 3;
  const u16* wrowh = wh + (size_t)wo * K + kbase + wpart * 8;
  int wlo_ = wo * 40 + wpart * 8;

  f32x4 acc[2][4] = {};
  ushort4 avh[4];
  uint4 wvh;

  auto LOADSTEP = [&](int kt) {
    int k = kbase + kt * 32 + kq * 4;
    int ci = k >> LGP2;
    int wp = k & (P * P - 1);
    if constexpr (P >= 4) {
      int kh = wp >> LGP, kw = wp & (P - 1);
      size_t koff = (size_t)ci * HW_ + kh * W_ + kw;
      #pragma unroll
      for (int hh = 0; hh < 4; ++hh)
        avh[hh] = *(const ushort4*)&inph[rbase[hh] + koff];
    } else {
      size_t koff = (size_t)ci * HW_;
      #pragma unroll
      for (int hh = 0; hh < 4; ++hh) {
        union { uint2 u; ushort4 s; } cv;
        cv.u.x = *(const u32*)&inph[rbase[hh] + koff];
        cv.u.y = *(const u32*)&inph[rbase[hh] + koff + W_];
        avh[hh] = cv.s;
      }
    }
    wvh = *(const uint4*)(wrowh + kt * 32);
  };

  LOADSTEP(0);
  for (int kt = 0; kt < NT; ++kt) {
    __syncthreads();
    #pragma unroll
    for (int hh = 0; hh < 4; ++hh)
      *(ushort4*)&ash[ldso + hh * 256] = avh[hh];
    *(uint4*)&wsh[wlo_] = wvh;
    __syncthreads();
    if (kt + 1 < NT) LOADSTEP(kt + 1);
    #pragma unroll
    for (int mrep = 0; mrep < 2; ++mrep) {
      int arow = wid * 32 + mrep * 16 + r;
      bf16x8 ahf = *(const bf16x8*)&ash[g * GSA + arow * 8];
      #pragma unroll
      for (int ct = 0; ct < 4; ++ct) {
        bf16x8 bh = *(const bf16x8*)&wsh[(ct * 16 + r) * 40 + g * 8];
        acc[mrep][ct] = MFMA(ahf, bh, acc[mrep][ct]);
      }
    }
  }
  #pragma unroll
  for (int mrep = 0; mrep < 2; ++mrep) {
    #pragma unroll
    for (int ct = 0; ct < 4; ++ct) {
      int o = ct * 16 + r;
      #pragma unroll
      for (int reg = 0; reg < 4; ++reg) {
        int row = t0 + wid * 32 + mrep * 16 + g * 4 + reg;
        dst[((size_t)seg * M + row) * 64 + o] = acc[mrep][ct][reg];
      }
    }
  }
}

__global__ __launch_bounds__(256) void conv_mfma_kernel(
    const u16* __restrict__ inph, const u16* __restrict__ wsh_g,
    float* __restrict__ part) {
  __shared__ __align__(16) u16 ash[4 * GSA];
  __shared__ __align__(16) u16 wsh[64 * 40];
  int bid = blockIdx.x;
  if (bid < 256) {            // head1: 8 mblk x 32 seg
    conv_body<8, 1, 32>(bid >> 5, bid & 31, inph, wsh_g + OS1, part, ash, wsh);
  } else if (bid < 512) {     // head2: 32 mblk x 8 seg
    int lb = bid - 256;
    conv_body<4, 2, 8>(lb >> 3, lb & 7, inph, wsh_g + OS2, part + 2097152,
                       ash, wsh);
  } else if (bid < 768) {     // head3: 32 mblk x 8 seg
    int lb = bid - 512;
    conv_body<4, 4, 8>(lb >> 3, lb & 7, inph, wsh_g + OS3, part + 4194304,
                       ash, wsh);
  } else {                    // head4: 128 mblk x 2 seg
    int lb = bid - 768;
    conv_body<2, 8, 2>(lb >> 1, lb & 1, inph, wsh_g + OS4, part + 6291456,
                       ash, wsh);
  }
}

// reduce K-split partials + conv bias, all heads -> y (25600 tokens)
__global__ __launch_bounds__(256) void reduce_kernel(
    const float* __restrict__ part, const float* __restrict__ b1,
    const float* __restrict__ b2, const float* __restrict__ b3,
    const float* __restrict__ b4, float* __restrict__ y) {
  int idx = blockIdx.x * 256 + threadIdx.x;   // grid exactly 1,638,400/256=6400
  int tg = idx >> 6, o = idx & 63;
  float s;
  if (tg < 1024) {
    s = b1[o];
    #pragma unroll
    for (int sg = 0; sg < 32; ++sg) s += part[((size_t)sg * 1024 + tg) * 64 + o];
  } else if (tg < 5120) {
    int t = tg - 1024;
    const float* p2 = part + 2097152;
    s = b2[o];
    #pragma unroll
    for (int sg = 0; sg < 8; ++sg) s += p2[((size_t)sg * 4096 + t) * 64 + o];
  } else if (tg < 9216) {
    int t = tg - 5120;
    const float* p3 = part + 4194304;
    s = b3[o];
    #pragma unroll
    for (int sg = 0; sg < 8; ++sg) s += p3[((size_t)sg * 4096 + t) * 64 + o];
  } else {
    int t = tg - 9216;
    const float* p4 = part + 6291456;
    s = b4[o] + p4[(size_t)t * 64 + o] + p4[((size_t)16384 + t) * 64 + o];
  }
  y[(size_t)tg * 64 + o] = s;
}

// ---------------------------------------------------------------------------
// fused LN(64) + exact GELU + KV projection (MFMA). 64 tokens/block, 400 blocks.
// K out bf16 [token][32]; V out bf16 window-transposed [d][k].
// ---------------------------------------------------------------------------
struct LnkvArgs { const float* lnw[4]; const float* lnb[4]; const float* kvb[4]; };

__global__ __launch_bounds__(256) void lnkv_mfma_kernel(
    const float* __restrict__ y, const u16* __restrict__ kvwh,
    const u16* __restrict__ kvwl, LnkvArgs a,
    u16* __restrict__ kb, u16* __restrict__ vbT) {
  __shared__ float ych[64 * 65];
  __shared__ __align__(16) u16 ash[8 * GS];
  __shared__ __align__(16) u16 asl[8 * GS];
  int bid = blockIdx.x, tid = threadIdx.x;
  int tb = bid * 64;
  int h  = (tb < 1024) ? 0 : (tb < 5120) ? 1 : (tb < 9216) ? 2 : 3;
  int hb = (h == 0) ? 0 : (h == 1) ? 1024 : (h == 2) ? 5120 : 9216;
  #pragma unroll
  for (int it = 0; it < 4; ++it) {
    int i4 = it * 256 + tid;            // 1024 float4s
    int row = i4 >> 4, cg = i4 & 15;
    float4 v = *(const float4*)&y[(size_t)(tb + row) * 64 + cg * 4];
    *(float4*)&ych[row * 65 + cg * 4] = v;
  }
  __syncthreads();
  {
    int tt = tid >> 2, p = tid & 3;
    const float* xr = &ych[tt * 65 + p * 16];
    float s = 0.f, s2 = 0.f;
    #pragma unroll
    for (int i = 0; i < 16; ++i) { float v = xr[i]; s += v; s2 += v * v; }
    s  += __shfl_xor(s, 1, 64);  s  += __shfl_xor(s, 2, 64);
    s2 += __shfl_xor(s2, 1, 64); s2 += __shfl_xor(s2, 2, 64);
    float mean = s * (1.0f / 64.0f);
    float var  = s2 * (1.0f / 64.0f) - mean * mean;
    float rstd = rsqrtf(var + 1e-5f);
    const float* lnw = a.lnw[h];
    const float* lnb = a.lnb[h];
    #pragma unroll
    for (int i = 0; i < 16; ++i) {
      int ch = p * 16 + i;
      float xn = (xr[i] - mean) * rstd * lnw[ch] + lnb[ch];
      float gg = 0.5f * xn * (1.0f + erff(xn * 0.70710678118654752f));
      u16 hh, ll; split2(gg, hh, ll);
      int o = (ch >> 3) * GS + tt * 8 + (ch & 7);
      ash[o] = hh; asl[o] = ll;
    }
  }
  __syncthreads();
  int wid = tid >> 6, lane = tid & 63, r = lane & 15, g = lane >> 4;
  const u16* wbh = kvwh + h * 4096;
  const u16* wbl = kvwl + h * 4096;
  f32x4 acc[4] = {};
  #pragma unroll
  for (int kk = 0; kk < 2; ++kk) {
    bf16x8 ah = *(const bf16x8*)&ash[(kk * 4 + g) * GS + (wid * 16 + r) * 8];
    bf16x8 al = *(const bf16x8*)&asl[(kk * 4 + g) * GS + (wid * 16 + r) * 8];
    #pragma unroll
    for (int ct = 0; ct < 4; ++ct) {
      bf16x8 bh = *(const bf16x8*)&wbh[(ct * 16 + r) * 64 + kk * 32 + g * 8];
      bf16x8 bl = *(const bf16x8*)&wbl[(ct * 16 + r) * 64 + kk * 32 + g * 8];
      acc[ct] = MFMA(ah, bh, acc[ct]);
      acc[ct] = MFMA(ah, bl, acc[ct]);
      acc[ct] = MFMA(al, bh, acc[ct]);
    }
  }
  const float* kvb = a.kvb[h];
  int lk = (h < 2) ? 256 : 64;
  #pragma unroll
  for (int ct = 0; ct < 4; ++ct) {
    int o = ct * 16 + r;
    float bias = kvb[o];
    #pragma unroll
    for (int reg = 0; reg < 4; ++reg) {
      int row = wid * 16 + g * 4 + reg;
      int tg  = tb + row;
      float v = acc[ct][reg] + bias;
      if (o < 32) {
        kb[(size_t)tg * 32 + o] = f2bf_rne(v);
      } else {
        int dd = o - 32;
        int kl = (tg - hb) & (lk - 1);
        int wstart = tg - kl;
        vbT[(size_t)wstart * 32 + dd * lk + kl] = f2bf_rne(v);
      }
    }
  }
}

// ---------------------------------------------------------------------------
// MFMA attention v3: block = 256 queries, K/V in LDS, bf16 output to cbuf16
// ---------------------------------------------------------------------------
template <int NW, int LK>
__device__ __forceinline__ void attn_v2_body(
    int bid, int head, int head_off, const u16* __restrict__ q,
    const u16* __restrict__ kb, const u16* __restrict__ vbT,
    u16* __restrict__ cbuf16) {
  constexpr int HWIN = H_ / NW;
  constexpr int LQ   = HWIN * HWIN;
  constexpr int BPW  = LQ / 256;          // blocks per window
  constexpr int NCT  = LK / 16;
  constexpr int NST  = LK / 32;
  constexpr int KS   = 40;                // K row stride (u16), 80B
  constexpr int VS   = LK + 8;            // V row stride (u16)
  extern __shared__ __align__(16) u16 alds[];
  u16* klds = alds;                       // [LK][KS]
  u16* vlds = alds + LK * KS;             // [32][VS]
  u16* plds = vlds + 32 * VS;             // 4 waves x 16 x KS (single buffer)
  int tid = threadIdx.x, wid = tid >> 6, lane = tid & 63;
  int g = lane >> 4, c = lane & 15;
  int win  = bid / BPW;
  int n = win / (NW * NW);
  int wrem = win % (NW * NW);
  int wy = wrem / NW, wx = wrem % NW;
  int kstart = head_off + win * LK;

  const u16* kgl = kb  + (size_t)kstart * 32;
  const u16* vgl = vbT + (size_t)kstart * 32;
  for (int ch = tid; ch < LK * 4; ch += 256) {
    int key = ch >> 2, gg = ch & 3;
    *(uint4*)&klds[key * KS + gg * 8] = *(const uint4*)&kgl[ch * 8];
  }
  for (int ch = tid; ch < LK * 4; ch += 256) {   // 32*LK/8 == LK*4
    int d = ch / (LK / 8), pos = ch % (LK / 8);
    *(uint4*)&vlds[d * VS + pos * 8] = *(const uint4*)&vgl[ch * 8];
  }
  __syncthreads();

  u16* pw0 = plds + wid * 16 * KS;
  f32x4 zero4 = {0.f, 0.f, 0.f, 0.f};

  #pragma unroll 1
  for (int tq = 0; tq < 4; ++tq) {
    int tIdx = (bid % BPW) * 16 + wid * 4 + tq;
    int j = tIdx * 16 + c;
    int ih = j / HWIN, iw = j % HWIN;
    int t = (wy * HWIN + ih) * W_ + wx * HWIN + iw;
    bf16x8 qa = *(const bf16x8*)&q[((size_t)n * HW_ + t) * 128 + head * 32 + g * 8];

    f32x4 sacc[NCT];
    #pragma unroll
    for (int ct = 0; ct < NCT; ++ct) {
      bf16x8 kf = *(const bf16x8*)&klds[(ct * 16 + c) * KS + g * 8];
      sacc[ct] = MFMA(qa, kf, zero4);
    }
    #pragma unroll
    for (int reg = 0; reg < 4; ++reg) {
      float mx = -1e30f;
      #pragma unroll
      for (int ct = 0; ct < NCT; ++ct) mx = fmaxf(mx, sacc[ct][reg]);
      mx = fmaxf(mx, __shfl_xor(mx, 1, 64));
      mx = fmaxf(mx, __shfl_xor(mx, 2, 64));
      mx = fmaxf(mx, __shfl_xor(mx, 4, 64));
      mx = fmaxf(mx, __shfl_xor(mx, 8, 64));
      float sm = 0.f;
      #pragma unroll
      for (int ct = 0; ct < NCT; ++ct) {
        float e = __expf((sacc[ct][reg] - mx) * SCALE_);
        sacc[ct][reg] = e;
        sm += e;
      }
      sm += __shfl_xor(sm, 1, 64);
      sm += __shfl_xor(sm, 2, 64);
      sm += __shfl_xor(sm, 4, 64);
      sm += __shfl_xor(sm, 8, 64);
      float inv = 1.0f / sm;
      #pragma unroll
      for (int ct = 0; ct < NCT; ++ct) sacc[ct][reg] *= inv;
    }
    f32x4 oacc[2] = {};
    #pragma unroll
    for (int st = 0; st < NST; ++st) {
      #pragma unroll
      for (int ct2 = 0; ct2 < 2; ++ct2) {
        int ct = st * 2 + ct2;
        #pragma unroll
        for (int reg = 0; reg < 4; ++reg)
          pw0[(g * 4 + reg) * KS + ct2 * 16 + c] = f2bf_rne(sacc[ct][reg]);
      }
      bf16x8 pa = *(const bf16x8*)&pw0[c * KS + g * 8];
      #pragma unroll
      for (int dt = 0; dt < 2; ++dt) {
        bf16x8 vf = *(const bf16x8*)&vlds[(dt * 16 + c) * VS + st * 32 + g * 8];
        oacc[dt] = MFMA(pa, vf, oacc[dt]);
      }
    }
    #pragma unroll
    for (int reg = 0; reg < 4; ++reg) {
      int jo = tIdx * 16 + g * 4 + reg;
      int iho = jo / HWIN, iwo = jo % HWIN;
      int to = (wy * HWIN + iho) * W_ + wx * HWIN + iwo;
      u16* op = cbuf16 + ((size_t)n * HW_ + to) * 128 + head * 32;
      op[c]      = f2bf_rne(oacc[0][reg]);
      op[16 + c] = f2bf_rne(oacc[1][reg]);
    }
  }
}

__global__ __launch_bounds__(256) void attn01_kernel(
    const u16* __restrict__ q, const u16* __restrict__ kb,
    const u16* __restrict__ vbT, u16* __restrict__ cbuf16) {
  int bid = blockIdx.x;
  if (bid < 256) attn_v2_body<1, 256>(bid,       0, 0,    q, kb, vbT, cbuf16);
  else           attn_v2_body<2, 256>(bid - 256, 1, 1024, q, kb, vbT, cbuf16);
}

__global__ __launch_bounds__(256) void attn23_kernel(
    const u16* __restrict__ q, const u16* __restrict__ kb,
    const u16* __restrict__ vbT, u16* __restrict__ cbuf16) {
  int bid = blockIdx.x;
  if (bid < 256) attn_v2_body<4, 64>(bid,       2, 5120, q, kb, vbT, cbuf16);
  else           attn_v2_body<8, 64>(bid - 256, 3, 9216, q, kb, vbT, cbuf16);
}

// ---------------------------------------------------------------------------
extern "C" void kernel_launch(void* const* d_in, const int* in_sizes, int n_in,
                              void* d_out, int out_size, void* d_ws, size_t ws_size,
                              hipStream_t stream) {
  const float* inp = (const float*)d_in[0];
  const float* nw  = (const float*)d_in[1];
  const float* nb  = (const float*)d_in[2];
  const float* qw  = (const float*)d_in[3];
  const float* qb  = (const float*)d_in[4];
  const float* pw  = (const float*)d_in[29];
  const float* pb  = (const float*)d_in[30];

  float* ws   = (float*)d_ws;
  u16*   qb16 = (u16*)(ws + QB_OFF);
  float* y    = ws + Y_OFF;
  u16*   kb   = (u16*)(ws + KB_OFF);
  u16*   vbT  = (u16*)(ws + VT_OFF);
  float* part = ws + PART_OFF;
  u16*   cbuf16 = (u16*)part;                 // aliases part (dead after reduce)
  u16*   wsp  = (u16*)(ws + WSP_OFF);
  u16*   whi  = wsp;
  u16*   wlo  = wsp + TOTW;
  u16*   inph = (u16*)(ws + INH_OFF);
  float* scb  = ws + SCB_OFF;

  // 0) prep: input -> bf16, weights -> bf16 hi/lo (qw pre-scaled by nw), S/cb
  prep_kernel<<<8192 + TOTW / 256 + 1, 256, 0, stream>>>(
      inp, qw, pw, (const float*)d_in[5], (const float*)d_in[11],
      (const float*)d_in[17], (const float*)d_in[23],
      (const float*)d_in[9], (const float*)d_in[15],
      (const float*)d_in[21], (const float*)d_in[27],
      nw, nb, qb, whi, wlo, inph, scb);

  // 1) LN-folded Q projection (MFMA) -> bf16 q
  lnq_mfma_kernel<<<1024, 256, 0, stream>>>(inph, whi + OQW, wlo + OQW, scb,
                                            qb16);

  // 2) all 4 patch-embed convs, plain bf16, uniform K-split (1024 blocks)
  conv_mfma_kernel<<<1024, 256, 0, stream>>>(inph, whi, part);

  // 3) wide reduce of K-split partials + bias -> y (all heads)
  reduce_kernel<<<6400, 256, 0, stream>>>(part, (const float*)d_in[6],
                                          (const float*)d_in[12],
                                          (const float*)d_in[18],
                                          (const float*)d_in[24], y);

  // 4) fused LN + GELU + KV projection (MFMA)
  LnkvArgs la;
  la.lnw[0] = (const float*)d_in[7];  la.lnb[0] = (const float*)d_in[8];
  la.kvb[0] = (const float*)d_in[10];
  la.lnw[1] = (const float*)d_in[13]; la.lnb[1] = (const float*)d_in[14];
  la.kvb[1] = (const float*)d_in[16];
  la.lnw[2] = (const float*)d_in[19]; la.lnb[2] = (const float*)d_in[20];
  la.kvb[2] = (const float*)d_in[22];
  la.lnw[3] = (const float*)d_in[25]; la.lnb[3] = (const float*)d_in[26];
  la.kvb[3] = (const float*)d_in[28];
  lnkv_mfma_kernel<<<400, 256, 0, stream>>>(y, whi + OKV, wlo + OKV, la, kb, vbT);

  // 5) MFMA attention -> bf16 cbuf16 (part region)
  attn01_kernel<<<512, 256, 42496, stream>>>(qb16, kb, vbT, cbuf16);
  attn23_kernel<<<512, 256, 14848, stream>>>(qb16, kb, vbT, cbuf16);

  // 6) final projection: bf16 in, fp32 out to d_out
  proj_mfma_kernel<<<1024, 256, 0, stream>>>(cbuf16, whi + OPW, wlo + OPW, pb,
                                             (float*)d_out);
}

// Round 14
// 156.541 us; speedup vs baseline: 1.6532x; 1.0472x over previous
//
#include <hip/hip_runtime.h>
#include <math.h>

#define N_   4
#define C_   128
#define H_   128
#define W_   128
#define HW_  16384
#define SCALE_ 0.17677669529663687f   // 32^-0.5

typedef unsigned short u16;
typedef unsigned int   u32;
typedef __bf16 bf16x8 __attribute__((ext_vector_type(8)));
typedef float  f32x4  __attribute__((ext_vector_type(4)));

#define MFMA(a, b, c) __builtin_amdgcn_mfma_f32_16x16x32_bf16((a), (b), (c), 0, 0, 0)

// ---- ws float offsets -------------------------------------------------------
#define QB_OFF   0            // 4,194,304 floats (8,388,608 u16 bf16 q)
#define Y_OFF    4194304      // 1,638,400 (all heads, post-reduce + bias)
#define KB_OFF   5832704      //   409,600 floats (819,200 u16 bf16 K)
#define VT_OFF   6242304      //   409,600 floats (819,200 u16 bf16 V^T)
#define PART_OFF 6651904      // 8,388,608 (4 heads x 2,097,152); cbuf16 aliases
#define WSP_OFF  15040512     //   868,352 floats (2 x 868,352 u16 hi+lo)
#define INH_OFF  15908864     // 4,194,304 floats (8,388,608 u16 bf16 input)
#define SCB_OFF  20103168     //       256 floats (S[128], cb[128])
// total 20,103,424 floats = 80.4 MB

// split-weight region offsets (u16 units, within hi or lo half)
#define OQW 0
#define OPW 16384
#define OS1 32768
#define OS2 557056
#define OS3 688128
#define OS4 819200
#define OKV 851968
#define TOTW 868352

#define GS  520    // A-LDS kgroup stride (lnkv), u16

// ---------------------------------------------------------------------------
__device__ __forceinline__ u16 f2bf_rne(float x) {
  unsigned u = __float_as_uint(x);
  return (u16)((u + 0x7FFFu + ((u >> 16) & 1u)) >> 16);
}
__device__ __forceinline__ float bf2f(u16 x) {
  return __uint_as_float((u32)x << 16);
}
__device__ __forceinline__ void split2(float v, u16& h, u16& l) {
  unsigned u = __float_as_uint(v);
  unsigned hb = (u + 0x7FFFu + ((u >> 16) & 1u)) & 0xFFFF0000u;
  h = (u16)(hb >> 16);
  float lf = v - __uint_as_float(hb);
  l = f2bf_rne(lf);
}

// ---------------------------------------------------------------------------
// prep: [bid<8192]       input fp32 -> bf16 (hi only)
//       [8192..+3392)    weights fp32 -> bf16 hi/lo; qw region holds w'=nw*qw
//       [last block]     S[o] = sum_c w'[o][c]; cb[o] = nb.qw[o] + qb[o]
// ---------------------------------------------------------------------------
__global__ __launch_bounds__(256) void prep_kernel(
    const float* __restrict__ inp, const float* __restrict__ qw,
    const float* __restrict__ pw, const float* __restrict__ s1,
    const float* __restrict__ s2, const float* __restrict__ s3,
    const float* __restrict__ s4, const float* __restrict__ kv1,
    const float* __restrict__ kv2, const float* __restrict__ kv3,
    const float* __restrict__ kv4, const float* __restrict__ nw,
    const float* __restrict__ nb, const float* __restrict__ qb,
    u16* __restrict__ hi, u16* __restrict__ lo, u16* __restrict__ inph,
    float* __restrict__ scb) {
  int bid = blockIdx.x;
  if (bid < 8192) {
    int idx = bid * 256 + threadIdx.x;        // float4 units over 8,388,608 f
    float4 v = *(const float4*)&inp[(size_t)idx * 4];
    ushort4 h4;
    h4.x = f2bf_rne(v.x); h4.y = f2bf_rne(v.y);
    h4.z = f2bf_rne(v.z); h4.w = f2bf_rne(v.w);
    *(ushort4*)&inph[(size_t)idx * 4] = h4;
  } else if (bid < 8192 + TOTW / 256) {
    int idx = (bid - 8192) * 256 + threadIdx.x;   // < TOTW
    const float* src; int off;
    float mul = 1.0f;
    if      (idx < OPW)  { src = qw; off = idx; mul = nw[idx & 127]; }
    else if (idx < OS1)  { src = pw; off = idx - OPW; }
    else if (idx < OS2)  { src = s1; off = idx - OS1; }
    else if (idx < OS3)  { src = s2; off = idx - OS2; }
    else if (idx < OS4)  { src = s3; off = idx - OS3; }
    else if (idx < OKV)  { src = s4; off = idx - OS4; }
    else {
      int j = idx - OKV;
      int h = j >> 12; off = j & 4095;
      src = (h == 0) ? kv1 : (h == 1) ? kv2 : (h == 2) ? kv3 : kv4;
    }
    u16 h, l; split2(src[off] * mul, h, l);
    hi[idx] = h; lo[idx] = l;
  } else {
    int o = threadIdx.x;
    if (o < 128) {
      float S = 0.f, cbv = qb[o];
      const float* wr = qw + o * 128;
      for (int c = 0; c < 128; ++c) {
        float w = wr[c];
        S   += w * nw[c];
        cbv += w * nb[c];
      }
      scb[o]       = S;
      scb[128 + o] = cbv;
    }
  }
}

// ---------------------------------------------------------------------------
// LN-folded Q projection, A-frags loaded DIRECTLY from global (no LDS):
// q[t][o] = rs[t]*(x[t].w'[o] - mu[t]*S[o]) + cb[o]
// ---------------------------------------------------------------------------
__global__ __launch_bounds__(256) void lnq_mfma_kernel(
    const u16* __restrict__ inph, const u16* __restrict__ wh,
    const u16* __restrict__ wl, const float* __restrict__ scb,
    u16* __restrict__ q) {
  int tid = threadIdx.x;
  int bid = blockIdx.x, n = bid >> 8, t0 = (bid & 255) * 64;
  int wid = tid >> 6, lane = tid & 63, r = lane & 15, g = lane >> 4;
  const u16* xb = inph + (size_t)n * C_ * HW_ + t0 + wid * 16 + r;

  // load this lane's 4 A-frags (strided u16 gathers) + LN stats in registers
  bf16x8 af[4];
  float s = 0.f, s2 = 0.f;
  #pragma unroll
  for (int kk = 0; kk < 4; ++kk) {
    union { u16 e[8]; bf16x8 b; } cv;
    #pragma unroll
    for (int e = 0; e < 8; ++e) {
      int c = kk * 32 + g * 8 + e;
      u16 v = xb[(size_t)c * HW_];
      cv.e[e] = v;
      float f = bf2f(v);
      s += f; s2 += f * f;
    }
    af[kk] = cv.b;
  }
  s  += __shfl_xor(s, 16, 64);  s  += __shfl_xor(s, 32, 64);
  s2 += __shfl_xor(s2, 16, 64); s2 += __shfl_xor(s2, 32, 64);
  float mu = s * (1.0f / 128.0f);
  float var = s2 * (1.0f / 128.0f) - mu * mu;
  float rs = rsqrtf(var + 1e-5f);

  f32x4 acc[8] = {};
  #pragma unroll
  for (int kk = 0; kk < 4; ++kk) {
    #pragma unroll
    for (int ct = 0; ct < 8; ++ct) {
      int o = ct * 16 + r;
      bf16x8 bh = *(const bf16x8*)&wh[o * 128 + kk * 32 + g * 8];
      bf16x8 bl = *(const bf16x8*)&wl[o * 128 + kk * 32 + g * 8];
      acc[ct] = MFMA(af[kk], bh, acc[ct]);
      acc[ct] = MFMA(af[kk], bl, acc[ct]);
    }
  }
  #pragma unroll
  for (int reg = 0; reg < 4; ++reg) {
    float mur = __shfl(mu, g * 4 + reg, 64);
    float rsr = __shfl(rs, g * 4 + reg, 64);
    int row = wid * 16 + g * 4 + reg;
    #pragma unroll
    for (int ct = 0; ct < 8; ++ct) {
      int col = ct * 16 + r;
      float val = rsr * (acc[ct][reg] - mur * scb[col]) + scb[128 + col];
      q[((size_t)n * HW_ + t0 + row) * 128 + col] = f2bf_rne(val);
    }
  }
}

// ---------------------------------------------------------------------------
// final projection: bf16 input [t][128] contiguous -> direct A-frag loads,
// no LDS, no syncs. fp32 out + bias.
// ---------------------------------------------------------------------------
__global__ __launch_bounds__(256) void proj_mfma_kernel(
    const u16* __restrict__ x16, const u16* __restrict__ wh,
    const u16* __restrict__ wl, const float* __restrict__ b,
    float* __restrict__ out) {
  int tid = threadIdx.x;
  int r0 = blockIdx.x * 64;
  int wid = tid >> 6, lane = tid & 63, r = lane & 15, g = lane >> 4;
  const u16* xr = x16 + (size_t)(r0 + wid * 16 + r) * 128 + g * 8;
  bf16x8 af[4];
  #pragma unroll
  for (int kk = 0; kk < 4; ++kk)
    af[kk] = *(const bf16x8*)&xr[kk * 32];
  f32x4 acc[8] = {};
  #pragma unroll
  for (int kk = 0; kk < 4; ++kk) {
    #pragma unroll
    for (int ct = 0; ct < 8; ++ct) {
      int o = ct * 16 + r;
      bf16x8 bh = *(const bf16x8*)&wh[o * 128 + kk * 32 + g * 8];
      bf16x8 bl = *(const bf16x8*)&wl[o * 128 + kk * 32 + g * 8];
      acc[ct] = MFMA(af[kk], bh, acc[ct]);
      acc[ct] = MFMA(af[kk], bl, acc[ct]);
    }
  }
  #pragma unroll
  for (int ct = 0; ct < 8; ++ct) {
    int col = ct * 16 + r;
    #pragma unroll
    for (int reg = 0; reg < 4; ++reg) {
      int row = r0 + wid * 16 + g * 4 + reg;
      out[(size_t)row * 128 + col] = acc[ct][reg] + b[col];
    }
  }
}

// ---------------------------------------------------------------------------
// conv-as-GEMM v4: plain bf16, BM=128, per-lane DIRECT im2col A-frag gathers
// (no A LDS); weights LDS-staged (5 KB), prefetched. fp32 K-split partials.
// ---------------------------------------------------------------------------
template <int P, int NW, int SEG>
__device__ __forceinline__ void conv_body(
    int mblk, int seg, const u16* __restrict__ inph,
    const u16* __restrict__ wh, float* __restrict__ dst,
    u16* wsh) {
  constexpr int K    = 128 * P * P;
  constexpr int KSEG = K / SEG;              // 256 everywhere
  constexpr int NT   = KSEG / 32;            // 8
  constexpr int HWIN = H_ / NW;
  constexpr int G    = HWIN / P;
  constexpr int L    = G * G;
  constexpr int M    = 4 * NW * NW * L;
  constexpr int LGL  = (L == 256) ? 8 : 6;
  constexpr int LGG  = (G == 16) ? 4 : 3;
  constexpr int LGNW = (NW == 8) ? 3 : (NW == 4) ? 2 : (NW == 2) ? 1 : 0;
  constexpr int LGP  = (P == 8) ? 3 : (P == 4) ? 2 : 1;
  constexpr int LGP2 = 2 * LGP;
  int tid = threadIdx.x, wid = tid >> 6, lane = tid & 63;
  int r = lane & 15, g = lane >> 4;
  int t0 = mblk * 128;
  int kbase = seg * KSEG;

  // per-lane im2col base for its two MFMA rows
  size_t rbase[2];
  #pragma unroll
  for (int mrep = 0; mrep < 2; ++mrep) {
    int tglob = t0 + wid * 32 + mrep * 16 + r;
    int bwin = tglob >> LGL;
    int loc  = tglob & (L - 1);
    int n    = bwin >> (2 * LGNW);
    int wrem = bwin & (NW * NW - 1);
    int wy = wrem >> LGNW, wx = wrem & (NW - 1);
    int oh = loc >> LGG,   ow = loc & (G - 1);
    rbase[mrep] = (size_t)n * C_ * HW_ + (size_t)(wy * HWIN + oh * P) * W_ +
                  wx * HWIN + ow * P;
  }
  int wo = tid >> 2, wpart = tid & 3;
  const u16* wrowh = wh + (size_t)wo * K + kbase + wpart * 8;
  int wlo_ = wo * 40 + wpart * 8;

  f32x4 acc[2][4] = {};
  uint4 av[2];
  uint4 wvh;

  auto LOADA = [&](int kt) {
    int k0 = kbase + kt * 32 + g * 8;
    int ci = k0 >> LGP2;
    int wp = k0 & (P * P - 1);
    #pragma unroll
    for (int mrep = 0; mrep < 2; ++mrep) {
      if constexpr (P == 8) {
        av[mrep] = *(const uint4*)&inph[rbase[mrep] + (size_t)ci * HW_ +
                                        (wp >> 3) * W_];
      } else if constexpr (P == 4) {
        int kh = wp >> 2;
        size_t base = rbase[mrep] + (size_t)ci * HW_;
        uint2 lo2 = *(const uint2*)&inph[base + kh * W_];
        uint2 hi2 = *(const uint2*)&inph[base + (kh + 1) * W_];
        av[mrep] = make_uint4(lo2.x, lo2.y, hi2.x, hi2.y);
      } else {  // P == 2
        size_t base = rbase[mrep] + (size_t)ci * HW_;
        u32 a0 = *(const u32*)&inph[base];
        u32 a1 = *(const u32*)&inph[base + W_];
        u32 a2 = *(const u32*)&inph[base + HW_];
        u32 a3 = *(const u32*)&inph[base + HW_ + W_];
        av[mrep] = make_uint4(a0, a1, a2, a3);
      }
    }
    wvh = *(const uint4*)(wrowh + kt * 32);
  };

  LOADA(0);
  for (int kt = 0; kt < NT; ++kt) {
    __syncthreads();                    // prior MFMA phase done with wsh
    *(uint4*)&wsh[wlo_] = wvh;
    __syncthreads();
    union { uint4 u; bf16x8 b; } a0, a1;
    a0.u = av[0]; a1.u = av[1];
    if (kt + 1 < NT) LOADA(kt + 1);     // prefetch overlaps MFMA
    #pragma unroll
    for (int ct = 0; ct < 4; ++ct) {
      bf16x8 bh = *(const bf16x8*)&wsh[(ct * 16 + r) * 40 + g * 8];
      acc[0][ct] = MFMA(a0.b, bh, acc[0][ct]);
      acc[1][ct] = MFMA(a1.b, bh, acc[1][ct]);
    }
  }
  #pragma unroll
  for (int mrep = 0; mrep < 2; ++mrep) {
    #pragma unroll
    for (int ct = 0; ct < 4; ++ct) {
      int o = ct * 16 + r;
      #pragma unroll
      for (int reg = 0; reg < 4; ++reg) {
        int row = t0 + wid * 32 + mrep * 16 + g * 4 + reg;
        dst[((size_t)seg * M + row) * 64 + o] = acc[mrep][ct][reg];
      }
    }
  }
}

__global__ __launch_bounds__(256) void conv_mfma_kernel(
    const u16* __restrict__ inph, const u16* __restrict__ wsh_g,
    float* __restrict__ part) {
  __shared__ __align__(16) u16 wsh[64 * 40];
  int bid = blockIdx.x;
  if (bid < 256) {            // head1: 8 mblk x 32 seg
    conv_body<8, 1, 32>(bid >> 5, bid & 31, inph, wsh_g + OS1, part, wsh);
  } else if (bid < 512) {     // head2: 32 mblk x 8 seg
    int lb = bid - 256;
    conv_body<4, 2, 8>(lb >> 3, lb & 7, inph, wsh_g + OS2, part + 2097152, wsh);
  } else if (bid < 768) {     // head3: 32 mblk x 8 seg
    int lb = bid - 512;
    conv_body<4, 4, 8>(lb >> 3, lb & 7, inph, wsh_g + OS3, part + 4194304, wsh);
  } else {                    // head4: 128 mblk x 2 seg
    int lb = bid - 768;
    conv_body<2, 8, 2>(lb >> 1, lb & 1, inph, wsh_g + OS4, part + 6291456, wsh);
  }
}

// reduce K-split partials + conv bias, all heads -> y (25600 tokens)
__global__ __launch_bounds__(256) void reduce_kernel(
    const float* __restrict__ part, const float* __restrict__ b1,
    const float* __restrict__ b2, const float* __restrict__ b3,
    const float* __restrict__ b4, float* __restrict__ y) {
  int idx = blockIdx.x * 256 + threadIdx.x;   // grid exactly 1,638,400/256=6400
  int tg = idx >> 6, o = idx & 63;
  float s;
  if (tg < 1024) {
    s = b1[o];
    #pragma unroll
    for (int sg = 0; sg < 32; ++sg) s += part[((size_t)sg * 1024 + tg) * 64 + o];
  } else if (tg < 5120) {
    int t = tg - 1024;
    const float* p2 = part + 2097152;
    s = b2[o];
    #pragma unroll
    for (int sg = 0; sg < 8; ++sg) s += p2[((size_t)sg * 4096 + t) * 64 + o];
  } else if (tg < 9216) {
    int t = tg - 5120;
    const float* p3 = part + 4194304;
    s = b3[o];
    #pragma unroll
    for (int sg = 0; sg < 8; ++sg) s += p3[((size_t)sg * 4096 + t) * 64 + o];
  } else {
    int t = tg - 9216;
    const float* p4 = part + 6291456;
    s = b4[o] + p4[(size_t)t * 64 + o] + p4[((size_t)16384 + t) * 64 + o];
  }
  y[(size_t)tg * 64 + o] = s;
}

// ---------------------------------------------------------------------------
// fused LN(64) + exact GELU + KV projection (MFMA). 64 tokens/block, 400 blocks.
// K out bf16 [token][32]; V out bf16 window-transposed [d][k].
// ---------------------------------------------------------------------------
struct LnkvArgs { const float* lnw[4]; const float* lnb[4]; const float* kvb[4]; };

__global__ __launch_bounds__(256) void lnkv_mfma_kernel(
    const float* __restrict__ y, const u16* __restrict__ kvwh,
    const u16* __restrict__ kvwl, LnkvArgs a,
    u16* __restrict__ kb, u16* __restrict__ vbT) {
  __shared__ float ych[64 * 65];
  __shared__ __align__(16) u16 ash[8 * GS];
  __shared__ __align__(16) u16 asl[8 * GS];
  int bid = blockIdx.x, tid = threadIdx.x;
  int tb = bid * 64;
  int h  = (tb < 1024) ? 0 : (tb < 5120) ? 1 : (tb < 9216) ? 2 : 3;
  int hb = (h == 0) ? 0 : (h == 1) ? 1024 : (h == 2) ? 5120 : 9216;
  #pragma unroll
  for (int it = 0; it < 4; ++it) {
    int i4 = it * 256 + tid;            // 1024 float4s
    int row = i4 >> 4, cg = i4 & 15;
    float4 v = *(const float4*)&y[(size_t)(tb + row) * 64 + cg * 4];
    *(float4*)&ych[row * 65 + cg * 4] = v;
  }
  __syncthreads();
  {
    int tt = tid >> 2, p = tid & 3;
    const float* xr = &ych[tt * 65 + p * 16];
    float s = 0.f, s2 = 0.f;
    #pragma unroll
    for (int i = 0; i < 16; ++i) { float v = xr[i]; s += v; s2 += v * v; }
    s  += __shfl_xor(s, 1, 64);  s  += __shfl_xor(s, 2, 64);
    s2 += __shfl_xor(s2, 1, 64); s2 += __shfl_xor(s2, 2, 64);
    float mean = s * (1.0f / 64.0f);
    float var  = s2 * (1.0f / 64.0f) - mean * mean;
    float rstd = rsqrtf(var + 1e-5f);
    const float* lnw = a.lnw[h];
    const float* lnb = a.lnb[h];
    #pragma unroll
    for (int i = 0; i < 16; ++i) {
      int ch = p * 16 + i;
      float xn = (xr[i] - mean) * rstd * lnw[ch] + lnb[ch];
      float gg = 0.5f * xn * (1.0f + erff(xn * 0.70710678118654752f));
      u16 hh, ll; split2(gg, hh, ll);
      int o = (ch >> 3) * GS + tt * 8 + (ch & 7);
      ash[o] = hh; asl[o] = ll;
    }
  }
  __syncthreads();
  int wid = tid >> 6, lane = tid & 63, r = lane & 15, g = lane >> 4;
  const u16* wbh = kvwh + h * 4096;
  const u16* wbl = kvwl + h * 4096;
  f32x4 acc[4] = {};
  #pragma unroll
  for (int kk = 0; kk < 2; ++kk) {
    bf16x8 ah = *(const bf16x8*)&ash[(kk * 4 + g) * GS + (wid * 16 + r) * 8];
    bf16x8 al = *(const bf16x8*)&asl[(kk * 4 + g) * GS + (wid * 16 + r) * 8];
    #pragma unroll
    for (int ct = 0; ct < 4; ++ct) {
      bf16x8 bh = *(const bf16x8*)&wbh[(ct * 16 + r) * 64 + kk * 32 + g * 8];
      bf16x8 bl = *(const bf16x8*)&wbl[(ct * 16 + r) * 64 + kk * 32 + g * 8];
      acc[ct] = MFMA(ah, bh, acc[ct]);
      acc[ct] = MFMA(ah, bl, acc[ct]);
      acc[ct] = MFMA(al, bh, acc[ct]);
    }
  }
  const float* kvb = a.kvb[h];
  int lk = (h < 2) ? 256 : 64;
  #pragma unroll
  for (int ct = 0; ct < 4; ++ct) {
    int o = ct * 16 + r;
    float bias = kvb[o];
    #pragma unroll
    for (int reg = 0; reg < 4; ++reg) {
      int row = wid * 16 + g * 4 + reg;
      int tg  = tb + row;
      float v = acc[ct][reg] + bias;
      if (o < 32) {
        kb[(size_t)tg * 32 + o] = f2bf_rne(v);
      } else {
        int dd = o - 32;
        int kl = (tg - hb) & (lk - 1);
        int wstart = tg - kl;
        vbT[(size_t)wstart * 32 + dd * lk + kl] = f2bf_rne(v);
      }
    }
  }
}

// ---------------------------------------------------------------------------
// MFMA attention v3: block = 256 queries, K/V in LDS, bf16 output to cbuf16
// ---------------------------------------------------------------------------
template <int NW, int LK>
__device__ __forceinline__ void attn_v2_body(
    int bid, int head, int head_off, const u16* __restrict__ q,
    const u16* __restrict__ kb, const u16* __restrict__ vbT,
    u16* __restrict__ cbuf16) {
  constexpr int HWIN = H_ / NW;
  constexpr int LQ   = HWIN * HWIN;
  constexpr int BPW  = LQ / 256;          // blocks per window
  constexpr int NCT  = LK / 16;
  constexpr int NST  = LK / 32;
  constexpr int KS   = 40;                // K row stride (u16), 80B
  constexpr int VS   = LK + 8;            // V row stride (u16)
  extern __shared__ __align__(16) u16 alds[];
  u16* klds = alds;                       // [LK][KS]
  u16* vlds = alds + LK * KS;             // [32][VS]
  u16* plds = vlds + 32 * VS;             // 4 waves x 16 x KS (single buffer)
  int tid = threadIdx.x, wid = tid >> 6, lane = tid & 63;
  int g = lane >> 4, c = lane & 15;
  int win  = bid / BPW;
  int n = win / (NW * NW);
  int wrem = win % (NW * NW);
  int wy = wrem / NW, wx = wrem % NW;
  int kstart = head_off + win * LK;

  const u16* kgl = kb  + (size_t)kstart * 32;
  const u16* vgl = vbT + (size_t)kstart * 32;
  for (int ch = tid; ch < LK * 4; ch += 256) {
    int key = ch >> 2, gg = ch & 3;
    *(uint4*)&klds[key * KS + gg * 8] = *(const uint4*)&kgl[ch * 8];
  }
  for (int ch = tid; ch < LK * 4; ch += 256) {   // 32*LK/8 == LK*4
    int d = ch / (LK / 8), pos = ch % (LK / 8);
    *(uint4*)&vlds[d * VS + pos * 8] = *(const uint4*)&vgl[ch * 8];
  }
  __syncthreads();

  u16* pw0 = plds + wid * 16 * KS;
  f32x4 zero4 = {0.f, 0.f, 0.f, 0.f};

  #pragma unroll 1
  for (int tq = 0; tq < 4; ++tq) {
    int tIdx = (bid % BPW) * 16 + wid * 4 + tq;
    int j = tIdx * 16 + c;
    int ih = j / HWIN, iw = j % HWIN;
    int t = (wy * HWIN + ih) * W_ + wx * HWIN + iw;
    bf16x8 qa = *(const bf16x8*)&q[((size_t)n * HW_ + t) * 128 + head * 32 + g * 8];

    f32x4 sacc[NCT];
    #pragma unroll
    for (int ct = 0; ct < NCT; ++ct) {
      bf16x8 kf = *(const bf16x8*)&klds[(ct * 16 + c) * KS + g * 8];
      sacc[ct] = MFMA(qa, kf, zero4);
    }
    #pragma unroll
    for (int reg = 0; reg < 4; ++reg) {
      float mx = -1e30f;
      #pragma unroll
      for (int ct = 0; ct < NCT; ++ct) mx = fmaxf(mx, sacc[ct][reg]);
      mx = fmaxf(mx, __shfl_xor(mx, 1, 64));
      mx = fmaxf(mx, __shfl_xor(mx, 2, 64));
      mx = fmaxf(mx, __shfl_xor(mx, 4, 64));
      mx = fmaxf(mx, __shfl_xor(mx, 8, 64));
      float sm = 0.f;
      #pragma unroll
      for (int ct = 0; ct < NCT; ++ct) {
        float e = __expf((sacc[ct][reg] - mx) * SCALE_);
        sacc[ct][reg] = e;
        sm += e;
      }
      sm += __shfl_xor(sm, 1, 64);
      sm += __shfl_xor(sm, 2, 64);
      sm += __shfl_xor(sm, 4, 64);
      sm += __shfl_xor(sm, 8, 64);
      float inv = 1.0f / sm;
      #pragma unroll
      for (int ct = 0; ct < NCT; ++ct) sacc[ct][reg] *= inv;
    }
    f32x4 oacc[2] = {};
    #pragma unroll
    for (int st = 0; st < NST; ++st) {
      #pragma unroll
      for (int ct2 = 0; ct2 < 2; ++ct2) {
        int ct = st * 2 + ct2;
        #pragma unroll
        for (int reg = 0; reg < 4; ++reg)
          pw0[(g * 4 + reg) * KS + ct2 * 16 + c] = f2bf_rne(sacc[ct][reg]);
      }
      bf16x8 pa = *(const bf16x8*)&pw0[c * KS + g * 8];
      #pragma unroll
      for (int dt = 0; dt < 2; ++dt) {
        bf16x8 vf = *(const bf16x8*)&vlds[(dt * 16 + c) * VS + st * 32 + g * 8];
        oacc[dt] = MFMA(pa, vf, oacc[dt]);
      }
    }
    #pragma unroll
    for (int reg = 0; reg < 4; ++reg) {
      int jo = tIdx * 16 + g * 4 + reg;
      int iho = jo / HWIN, iwo = jo % HWIN;
      int to = (wy * HWIN + iho) * W_ + wx * HWIN + iwo;
      u16* op = cbuf16 + ((size_t)n * HW_ + to) * 128 + head * 32;
      op[c]      = f2bf_rne(oacc[0][reg]);
      op[16 + c] = f2bf_rne(oacc[1][reg]);
    }
  }
}

__global__ __launch_bounds__(256) void attn01_kernel(
    const u16* __restrict__ q, const u16* __restrict__ kb,
    const u16* __restrict__ vbT, u16* __restrict__ cbuf16) {
  int bid = blockIdx.x;
  if (bid < 256) attn_v2_body<1, 256>(bid,       0, 0,    q, kb, vbT, cbuf16);
  else           attn_v2_body<2, 256>(bid - 256, 1, 1024, q, kb, vbT, cbuf16);
}

__global__ __launch_bounds__(256) void attn23_kernel(
    const u16* __restrict__ q, const u16* __restrict__ kb,
    const u16* __restrict__ vbT, u16* __restrict__ cbuf16) {
  int bid = blockIdx.x;
  if (bid < 256) attn_v2_body<4, 64>(bid,       2, 5120, q, kb, vbT, cbuf16);
  else           attn_v2_body<8, 64>(bid - 256, 3, 9216, q, kb, vbT, cbuf16);
}

// ---------------------------------------------------------------------------
extern "C" void kernel_launch(void* const* d_in, const int* in_sizes, int n_in,
                              void* d_out, int out_size, void* d_ws, size_t ws_size,
                              hipStream_t stream) {
  const float* inp = (const float*)d_in[0];
  const float* nw  = (const float*)d_in[1];
  const float* nb  = (const float*)d_in[2];
  const float* qw  = (const float*)d_in[3];
  const float* qb  = (const float*)d_in[4];
  const float* pw  = (const float*)d_in[29];
  const float* pb  = (const float*)d_in[30];

  float* ws   = (float*)d_ws;
  u16*   qb16 = (u16*)(ws + QB_OFF);
  float* y    = ws + Y_OFF;
  u16*   kb   = (u16*)(ws + KB_OFF);
  u16*   vbT  = (u16*)(ws + VT_OFF);
  float* part = ws + PART_OFF;
  u16*   cbuf16 = (u16*)part;                 // aliases part (dead after reduce)
  u16*   wsp  = (u16*)(ws + WSP_OFF);
  u16*   whi  = wsp;
  u16*   wlo  = wsp + TOTW;
  u16*   inph = (u16*)(ws + INH_OFF);
  float* scb  = ws + SCB_OFF;

  // 0) prep: input -> bf16, weights -> bf16 hi/lo (qw pre-scaled by nw), S/cb
  prep_kernel<<<8192 + TOTW / 256 + 1, 256, 0, stream>>>(
      inp, qw, pw, (const float*)d_in[5], (const float*)d_in[11],
      (const float*)d_in[17], (const float*)d_in[23],
      (const float*)d_in[9], (const float*)d_in[15],
      (const float*)d_in[21], (const float*)d_in[27],
      nw, nb, qb, whi, wlo, inph, scb);

  // 1) LN-folded Q projection (MFMA, no LDS) -> bf16 q
  lnq_mfma_kernel<<<1024, 256, 0, stream>>>(inph, whi + OQW, wlo + OQW, scb,
                                            qb16);

  // 2) all 4 patch-embed convs, direct im2col A-frags (1024 blocks)
  conv_mfma_kernel<<<1024, 256, 0, stream>>>(inph, whi, part);

  // 3) wide reduce of K-split partials + bias -> y (all heads)
  reduce_kernel<<<6400, 256, 0, stream>>>(part, (const float*)d_in[6],
                                          (const float*)d_in[12],
                                          (const float*)d_in[18],
                                          (const float*)d_in[24], y);

  // 4) fused LN + GELU + KV projection (MFMA)
  LnkvArgs la;
  la.lnw[0] = (const float*)d_in[7];  la.lnb[0] = (const float*)d_in[8];
  la.kvb[0] = (const float*)d_in[10];
  la.lnw[1] = (const float*)d_in[13]; la.lnb[1] = (const float*)d_in[14];
  la.kvb[1] = (const float*)d_in[16];
  la.lnw[2] = (const float*)d_in[19]; la.lnb[2] = (const float*)d_in[20];
  la.kvb[2] = (const float*)d_in[22];
  la.lnw[3] = (const float*)d_in[25]; la.lnb[3] = (const float*)d_in[26];
  la.kvb[3] = (const float*)d_in[28];
  lnkv_mfma_kernel<<<400, 256, 0, stream>>>(y, whi + OKV, wlo + OKV, la, kb, vbT);

  // 5) MFMA attention -> bf16 cbuf16 (part region)
  attn01_kernel<<<512, 256, 42496, stream>>>(qb16, kb, vbT, cbuf16);
  attn23_kernel<<<512, 256, 14848, stream>>>(qb16, kb, vbT, cbuf16);

  // 6) final projection: bf16 in (direct frag loads), fp32 out to d_out
  proj_mfma_kernel<<<1024, 256, 0, stream>>>(cbuf16, whi + OPW, wlo + OPW, pb,
                                             (float*)d_out);
}

// Round 15
// 148.215 us; speedup vs baseline: 1.7461x; 1.0562x over previous
//
#include <hip/hip_runtime.h>
#include <math.h>

#define N_   4
#define C_   128
#define H_   128
#define W_   128
#define HW_  16384
#define SCALE_ 0.17677669529663687f   // 32^-0.5

typedef unsigned short u16;
typedef unsigned int   u32;
typedef __bf16 bf16x8 __attribute__((ext_vector_type(8)));
typedef float  f32x4  __attribute__((ext_vector_type(4)));

#define MFMA(a, b, c) __builtin_amdgcn_mfma_f32_16x16x32_bf16((a), (b), (c), 0, 0, 0)

// ---- ws float offsets -------------------------------------------------------
#define QB_OFF   0            // 4,194,304 floats (8,388,608 u16 bf16 q)
#define Y_OFF    4194304      // 1,638,400 (all heads, post-reduce + bias)
#define KB_OFF   5832704      //   409,600 floats (819,200 u16 bf16 K)
#define VT_OFF   6242304      //   409,600 floats (819,200 u16 bf16 V^T)
#define PART_OFF 6651904      // 8,388,608 (heads 1-3 partials); cbuf16 aliases
#define WSP_OFF  15040512     //   868,352 floats (2 x 868,352 u16 hi+lo)
#define INH_OFF  15908864     // 4,194,304 floats (8,388,608 u16 bf16 input)
#define SCB_OFF  20103168     //       256 floats (S[128], cb[128])
// total 20,103,424 floats = 80.4 MB

// split-weight region offsets (u16 units, within hi or lo half)
#define OQW 0
#define OPW 16384
#define OS1 32768
#define OS2 557056
#define OS3 688128
#define OS4 819200
#define OKV 851968
#define TOTW 868352

#define GS  520    // A-LDS kgroup stride (lnkv), u16

// ---------------------------------------------------------------------------
__device__ __forceinline__ u16 f2bf_rne(float x) {
  unsigned u = __float_as_uint(x);
  return (u16)((u + 0x7FFFu + ((u >> 16) & 1u)) >> 16);
}
__device__ __forceinline__ float bf2f(u16 x) {
  return __uint_as_float((u32)x << 16);
}
__device__ __forceinline__ void split2(float v, u16& h, u16& l) {
  unsigned u = __float_as_uint(v);
  unsigned hb = (u + 0x7FFFu + ((u >> 16) & 1u)) & 0xFFFF0000u;
  h = (u16)(hb >> 16);
  float lf = v - __uint_as_float(hb);
  l = f2bf_rne(lf);
}

// ---------------------------------------------------------------------------
// prep: [bid<8192]       input fp32 -> bf16 (hi only)
//       [8192..+3392)    weights fp32 -> bf16 hi/lo; qw region holds w'=nw*qw
//       [last block]     S[o] = sum_c w'[o][c]; cb[o] = nb.qw[o] + qb[o]
// ---------------------------------------------------------------------------
__global__ __launch_bounds__(256) void prep_kernel(
    const float* __restrict__ inp, const float* __restrict__ qw,
    const float* __restrict__ pw, const float* __restrict__ s1,
    const float* __restrict__ s2, const float* __restrict__ s3,
    const float* __restrict__ s4, const float* __restrict__ kv1,
    const float* __restrict__ kv2, const float* __restrict__ kv3,
    const float* __restrict__ kv4, const float* __restrict__ nw,
    const float* __restrict__ nb, const float* __restrict__ qb,
    u16* __restrict__ hi, u16* __restrict__ lo, u16* __restrict__ inph,
    float* __restrict__ scb) {
  int bid = blockIdx.x;
  if (bid < 8192) {
    int idx = bid * 256 + threadIdx.x;        // float4 units over 8,388,608 f
    float4 v = *(const float4*)&inp[(size_t)idx * 4];
    ushort4 h4;
    h4.x = f2bf_rne(v.x); h4.y = f2bf_rne(v.y);
    h4.z = f2bf_rne(v.z); h4.w = f2bf_rne(v.w);
    *(ushort4*)&inph[(size_t)idx * 4] = h4;
  } else if (bid < 8192 + TOTW / 256) {
    int idx = (bid - 8192) * 256 + threadIdx.x;   // < TOTW
    const float* src; int off;
    float mul = 1.0f;
    if      (idx < OPW)  { src = qw; off = idx; mul = nw[idx & 127]; }
    else if (idx < OS1)  { src = pw; off = idx - OPW; }
    else if (idx < OS2)  { src = s1; off = idx - OS1; }
    else if (idx < OS3)  { src = s2; off = idx - OS2; }
    else if (idx < OS4)  { src = s3; off = idx - OS3; }
    else if (idx < OKV)  { src = s4; off = idx - OS4; }
    else {
      int j = idx - OKV;
      int h = j >> 12; off = j & 4095;
      src = (h == 0) ? kv1 : (h == 1) ? kv2 : (h == 2) ? kv3 : kv4;
    }
    u16 h, l; split2(src[off] * mul, h, l);
    hi[idx] = h; lo[idx] = l;
  } else {
    int o = threadIdx.x;
    if (o < 128) {
      float S = 0.f, cbv = qb[o];
      const float* wr = qw + o * 128;
      for (int c = 0; c < 128; ++c) {
        float w = wr[c];
        S   += w * nw[c];
        cbv += w * nb[c];
      }
      scb[o]       = S;
      scb[128 + o] = cbv;
    }
  }
}

// ---------------------------------------------------------------------------
// LN-folded Q projection body (no LDS): q[t][o]=rs*(x.w' - mu*S[o])+cb[o]
// ---------------------------------------------------------------------------
__device__ __forceinline__ void lnq_body(
    int bid, const u16* __restrict__ inph, const u16* __restrict__ wh,
    const u16* __restrict__ wl, const float* __restrict__ scb,
    u16* __restrict__ q) {
  int tid = threadIdx.x;
  int n = bid >> 8, t0 = (bid & 255) * 64;
  int wid = tid >> 6, lane = tid & 63, r = lane & 15, g = lane >> 4;
  const u16* xb = inph + (size_t)n * C_ * HW_ + t0 + wid * 16 + r;

  bf16x8 af[4];
  float s = 0.f, s2 = 0.f;
  #pragma unroll
  for (int kk = 0; kk < 4; ++kk) {
    union { u16 e[8]; bf16x8 b; } cv;
    #pragma unroll
    for (int e = 0; e < 8; ++e) {
      int c = kk * 32 + g * 8 + e;
      u16 v = xb[(size_t)c * HW_];
      cv.e[e] = v;
      float f = bf2f(v);
      s += f; s2 += f * f;
    }
    af[kk] = cv.b;
  }
  s  += __shfl_xor(s, 16, 64);  s  += __shfl_xor(s, 32, 64);
  s2 += __shfl_xor(s2, 16, 64); s2 += __shfl_xor(s2, 32, 64);
  float mu = s * (1.0f / 128.0f);
  float var = s2 * (1.0f / 128.0f) - mu * mu;
  float rs = rsqrtf(var + 1e-5f);

  f32x4 acc[8] = {};
  #pragma unroll
  for (int kk = 0; kk < 4; ++kk) {
    #pragma unroll
    for (int ct = 0; ct < 8; ++ct) {
      int o = ct * 16 + r;
      bf16x8 bh = *(const bf16x8*)&wh[o * 128 + kk * 32 + g * 8];
      bf16x8 bl = *(const bf16x8*)&wl[o * 128 + kk * 32 + g * 8];
      acc[ct] = MFMA(af[kk], bh, acc[ct]);
      acc[ct] = MFMA(af[kk], bl, acc[ct]);
    }
  }
  #pragma unroll
  for (int reg = 0; reg < 4; ++reg) {
    float mur = __shfl(mu, g * 4 + reg, 64);
    float rsr = __shfl(rs, g * 4 + reg, 64);
    int row = wid * 16 + g * 4 + reg;
    #pragma unroll
    for (int ct = 0; ct < 8; ++ct) {
      int col = ct * 16 + r;
      float val = rsr * (acc[ct][reg] - mur * scb[col]) + scb[128 + col];
      q[((size_t)n * HW_ + t0 + row) * 128 + col] = f2bf_rne(val);
    }
  }
}

// ---------------------------------------------------------------------------
// conv-as-GEMM: BM=128, direct im2col A-frag gathers, weights LDS-staged,
// KSEG=512 (NT=16). SEG==1 -> direct y write with bias; else fp32 partials.
// ---------------------------------------------------------------------------
template <int P, int NW, int SEG>
__device__ __forceinline__ void conv_body(
    int mblk, int seg, const u16* __restrict__ inph,
    const u16* __restrict__ wh, float* __restrict__ dst,
    const float* __restrict__ bias, u16* wsh) {
  constexpr int K    = 128 * P * P;
  constexpr int KSEG = K / SEG;              // 512 everywhere
  constexpr int NT   = KSEG / 32;            // 16
  constexpr int HWIN = H_ / NW;
  constexpr int G    = HWIN / P;
  constexpr int L    = G * G;
  constexpr int M    = 4 * NW * NW * L;
  constexpr int LGL  = (L == 256) ? 8 : 6;
  constexpr int LGG  = (G == 16) ? 4 : 3;
  constexpr int LGNW = (NW == 8) ? 3 : (NW == 4) ? 2 : (NW == 2) ? 1 : 0;
  constexpr int LGP  = (P == 8) ? 3 : (P == 4) ? 2 : 1;
  constexpr int LGP2 = 2 * LGP;
  int tid = threadIdx.x, wid = tid >> 6, lane = tid & 63;
  int r = lane & 15, g = lane >> 4;
  int t0 = mblk * 128;
  int kbase = seg * KSEG;

  size_t rbase[2];
  #pragma unroll
  for (int mrep = 0; mrep < 2; ++mrep) {
    int tglob = t0 + wid * 32 + mrep * 16 + r;
    int bwin = tglob >> LGL;
    int loc  = tglob & (L - 1);
    int n    = bwin >> (2 * LGNW);
    int wrem = bwin & (NW * NW - 1);
    int wy = wrem >> LGNW, wx = wrem & (NW - 1);
    int oh = loc >> LGG,   ow = loc & (G - 1);
    rbase[mrep] = (size_t)n * C_ * HW_ + (size_t)(wy * HWIN + oh * P) * W_ +
                  wx * HWIN + ow * P;
  }
  int wo = tid >> 2, wpart = tid & 3;
  const u16* wrowh = wh + (size_t)wo * K + kbase + wpart * 8;
  int wlo_ = wo * 40 + wpart * 8;

  f32x4 acc[2][4] = {};
  uint4 av[2];
  uint4 wvh;

  auto LOADA = [&](int kt) {
    int k0 = kbase + kt * 32 + g * 8;
    int ci = k0 >> LGP2;
    int wp = k0 & (P * P - 1);
    #pragma unroll
    for (int mrep = 0; mrep < 2; ++mrep) {
      if constexpr (P == 8) {
        av[mrep] = *(const uint4*)&inph[rbase[mrep] + (size_t)ci * HW_ +
                                        (wp >> 3) * W_];
      } else if constexpr (P == 4) {
        int kh = wp >> 2;
        size_t base = rbase[mrep] + (size_t)ci * HW_;
        uint2 lo2 = *(const uint2*)&inph[base + kh * W_];
        uint2 hi2 = *(const uint2*)&inph[base + (kh + 1) * W_];
        av[mrep] = make_uint4(lo2.x, lo2.y, hi2.x, hi2.y);
      } else {  // P == 2
        size_t base = rbase[mrep] + (size_t)ci * HW_;
        u32 a0 = *(const u32*)&inph[base];
        u32 a1 = *(const u32*)&inph[base + W_];
        u32 a2 = *(const u32*)&inph[base + HW_];
        u32 a3 = *(const u32*)&inph[base + HW_ + W_];
        av[mrep] = make_uint4(a0, a1, a2, a3);
      }
    }
    wvh = *(const uint4*)(wrowh + kt * 32);
  };

  LOADA(0);
  for (int kt = 0; kt < NT; ++kt) {
    __syncthreads();                    // prior MFMA phase done with wsh
    *(uint4*)&wsh[wlo_] = wvh;
    __syncthreads();
    union { uint4 u; bf16x8 b; } a0, a1;
    a0.u = av[0]; a1.u = av[1];
    if (kt + 1 < NT) LOADA(kt + 1);     // prefetch overlaps MFMA
    #pragma unroll
    for (int ct = 0; ct < 4; ++ct) {
      bf16x8 bh = *(const bf16x8*)&wsh[(ct * 16 + r) * 40 + g * 8];
      acc[0][ct] = MFMA(a0.b, bh, acc[0][ct]);
      acc[1][ct] = MFMA(a1.b, bh, acc[1][ct]);
    }
  }
  #pragma unroll
  for (int mrep = 0; mrep < 2; ++mrep) {
    #pragma unroll
    for (int ct = 0; ct < 4; ++ct) {
      int o = ct * 16 + r;
      #pragma unroll
      for (int reg = 0; reg < 4; ++reg) {
        int row = t0 + wid * 32 + mrep * 16 + g * 4 + reg;
        if constexpr (SEG == 1)
          dst[(size_t)row * 64 + o] = acc[mrep][ct][reg] + bias[o];
        else
          dst[((size_t)seg * M + row) * 64 + o] = acc[mrep][ct][reg];
      }
    }
  }
}

// ---------------------------------------------------------------------------
// merged: [bid<512] convs (KSEG=512) ; [bid>=512] LN-folded Q projection
// ---------------------------------------------------------------------------
__global__ __launch_bounds__(256) void convlnq_kernel(
    const u16* __restrict__ inph, const u16* __restrict__ whi,
    const u16* __restrict__ wlo, const float* __restrict__ b4,
    const float* __restrict__ scb, float* __restrict__ part,
    float* __restrict__ y, u16* __restrict__ q) {
  __shared__ __align__(16) u16 wsh[64 * 40];
  int bid = blockIdx.x;
  if (bid < 128) {            // head1: 8 mblk x 16 seg
    conv_body<8, 1, 16>(bid >> 4, bid & 15, inph, whi + OS1, part, nullptr, wsh);
  } else if (bid < 256) {     // head2: 32 mblk x 4 seg
    int lb = bid - 128;
    conv_body<4, 2, 4>(lb >> 2, lb & 3, inph, whi + OS2, part + 2097152,
                       nullptr, wsh);
  } else if (bid < 384) {     // head3: 32 mblk x 4 seg
    int lb = bid - 256;
    conv_body<4, 4, 4>(lb >> 2, lb & 3, inph, whi + OS3, part + 4194304,
                       nullptr, wsh);
  } else if (bid < 512) {     // head4: 128 mblk, direct to y with bias
    conv_body<2, 8, 1>(bid - 384, 0, inph, whi + OS4,
                       y + (size_t)9216 * 64, b4, wsh);
  } else {                    // lnq: 1024 blocks
    lnq_body(bid - 512, inph, whi + OQW, wlo + OQW, scb, q);
  }
}

// reduce K-split partials + conv bias, heads 1-3 -> y (9216 tokens)
__global__ __launch_bounds__(256) void reduce_kernel(
    const float* __restrict__ part, const float* __restrict__ b1,
    const float* __restrict__ b2, const float* __restrict__ b3,
    float* __restrict__ y) {
  int idx = blockIdx.x * 256 + threadIdx.x;   // grid exactly 589824/256 = 2304
  int tg = idx >> 6, o = idx & 63;
  float s;
  if (tg < 1024) {
    s = b1[o];
    #pragma unroll
    for (int sg = 0; sg < 16; ++sg) s += part[((size_t)sg * 1024 + tg) * 64 + o];
  } else if (tg < 5120) {
    int t = tg - 1024;
    const float* p2 = part + 2097152;
    s = b2[o];
    #pragma unroll
    for (int sg = 0; sg < 4; ++sg) s += p2[((size_t)sg * 4096 + t) * 64 + o];
  } else {
    int t = tg - 5120;
    const float* p3 = part + 4194304;
    s = b3[o];
    #pragma unroll
    for (int sg = 0; sg < 4; ++sg) s += p3[((size_t)sg * 4096 + t) * 64 + o];
  }
  y[(size_t)tg * 64 + o] = s;
}

// ---------------------------------------------------------------------------
// fused LN(64) + exact GELU + KV projection (MFMA). 64 tokens/block, 400 blocks.
// K out bf16 [token][32]; V out bf16 window-transposed [d][k].
// ---------------------------------------------------------------------------
struct LnkvArgs { const float* lnw[4]; const float* lnb[4]; const float* kvb[4]; };

__global__ __launch_bounds__(256) void lnkv_mfma_kernel(
    const float* __restrict__ y, const u16* __restrict__ kvwh,
    const u16* __restrict__ kvwl, LnkvArgs a,
    u16* __restrict__ kb, u16* __restrict__ vbT) {
  __shared__ float ych[64 * 65];
  __shared__ __align__(16) u16 ash[8 * GS];
  __shared__ __align__(16) u16 asl[8 * GS];
  int bid = blockIdx.x, tid = threadIdx.x;
  int tb = bid * 64;
  int h  = (tb < 1024) ? 0 : (tb < 5120) ? 1 : (tb < 9216) ? 2 : 3;
  int hb = (h == 0) ? 0 : (h == 1) ? 1024 : (h == 2) ? 5120 : 9216;
  #pragma unroll
  for (int it = 0; it < 4; ++it) {
    int i4 = it * 256 + tid;            // 1024 float4s
    int row = i4 >> 4, cg = i4 & 15;
    float4 v = *(const float4*)&y[(size_t)(tb + row) * 64 + cg * 4];
    *(float4*)&ych[row * 65 + cg * 4] = v;
  }
  __syncthreads();
  {
    int tt = tid >> 2, p = tid & 3;
    const float* xr = &ych[tt * 65 + p * 16];
    float s = 0.f, s2 = 0.f;
    #pragma unroll
    for (int i = 0; i < 16; ++i) { float v = xr[i]; s += v; s2 += v * v; }
    s  += __shfl_xor(s, 1, 64);  s  += __shfl_xor(s, 2, 64);
    s2 += __shfl_xor(s2, 1, 64); s2 += __shfl_xor(s2, 2, 64);
    float mean = s * (1.0f / 64.0f);
    float var  = s2 * (1.0f / 64.0f) - mean * mean;
    float rstd = rsqrtf(var + 1e-5f);
    const float* lnw = a.lnw[h];
    const float* lnb = a.lnb[h];
    #pragma unroll
    for (int i = 0; i < 16; ++i) {
      int ch = p * 16 + i;
      float xn = (xr[i] - mean) * rstd * lnw[ch] + lnb[ch];
      float gg = 0.5f * xn * (1.0f + erff(xn * 0.70710678118654752f));
      u16 hh, ll; split2(gg, hh, ll);
      int o = (ch >> 3) * GS + tt * 8 + (ch & 7);
      ash[o] = hh; asl[o] = ll;
    }
  }
  __syncthreads();
  int wid = tid >> 6, lane = tid & 63, r = lane & 15, g = lane >> 4;
  const u16* wbh = kvwh + h * 4096;
  const u16* wbl = kvwl + h * 4096;
  f32x4 acc[4] = {};
  #pragma unroll
  for (int kk = 0; kk < 2; ++kk) {
    bf16x8 ah = *(const bf16x8*)&ash[(kk * 4 + g) * GS + (wid * 16 + r) * 8];
    bf16x8 al = *(const bf16x8*)&asl[(kk * 4 + g) * GS + (wid * 16 + r) * 8];
    #pragma unroll
    for (int ct = 0; ct < 4; ++ct) {
      bf16x8 bh = *(const bf16x8*)&wbh[(ct * 16 + r) * 64 + kk * 32 + g * 8];
      bf16x8 bl = *(const bf16x8*)&wbl[(ct * 16 + r) * 64 + kk * 32 + g * 8];
      acc[ct] = MFMA(ah, bh, acc[ct]);
      acc[ct] = MFMA(ah, bl, acc[ct]);
      acc[ct] = MFMA(al, bh, acc[ct]);
    }
  }
  const float* kvb = a.kvb[h];
  int lk = (h < 2) ? 256 : 64;
  #pragma unroll
  for (int ct = 0; ct < 4; ++ct) {
    int o = ct * 16 + r;
    float bias = kvb[o];
    #pragma unroll
    for (int reg = 0; reg < 4; ++reg) {
      int row = wid * 16 + g * 4 + reg;
      int tg  = tb + row;
      float v = acc[ct][reg] + bias;
      if (o < 32) {
        kb[(size_t)tg * 32 + o] = f2bf_rne(v);
      } else {
        int dd = o - 32;
        int kl = (tg - hb) & (lk - 1);
        int wstart = tg - kl;
        vbT[(size_t)wstart * 32 + dd * lk + kl] = f2bf_rne(v);
      }
    }
  }
}

// ---------------------------------------------------------------------------
// MFMA attention: block = 256 queries, K/V in LDS, bf16 output to cbuf16
// ---------------------------------------------------------------------------
template <int NW, int LK>
__device__ __forceinline__ void attn_v2_body(
    int bid, int head, int head_off, const u16* __restrict__ q,
    const u16* __restrict__ kb, const u16* __restrict__ vbT,
    u16* __restrict__ cbuf16) {
  constexpr int HWIN = H_ / NW;
  constexpr int LQ   = HWIN * HWIN;
  constexpr int BPW  = LQ / 256;          // blocks per window
  constexpr int NCT  = LK / 16;
  constexpr int NST  = LK / 32;
  constexpr int KS   = 40;                // K row stride (u16), 80B
  constexpr int VS   = LK + 8;            // V row stride (u16)
  extern __shared__ __align__(16) u16 alds[];
  u16* klds = alds;                       // [LK][KS]
  u16* vlds = alds + LK * KS;             // [32][VS]
  u16* plds = vlds + 32 * VS;             // 4 waves x 16 x KS (single buffer)
  int tid = threadIdx.x, wid = tid >> 6, lane = tid & 63;
  int g = lane >> 4, c = lane & 15;
  int win  = bid / BPW;
  int n = win / (NW * NW);
  int wrem = win % (NW * NW);
  int wy = wrem / NW, wx = wrem % NW;
  int kstart = head_off + win * LK;

  const u16* kgl = kb  + (size_t)kstart * 32;
  const u16* vgl = vbT + (size_t)kstart * 32;
  for (int ch = tid; ch < LK * 4; ch += 256) {
    int key = ch >> 2, gg = ch & 3;
    *(uint4*)&klds[key * KS + gg * 8] = *(const uint4*)&kgl[ch * 8];
  }
  for (int ch = tid; ch < LK * 4; ch += 256) {   // 32*LK/8 == LK*4
    int d = ch / (LK / 8), pos = ch % (LK / 8);
    *(uint4*)&vlds[d * VS + pos * 8] = *(const uint4*)&vgl[ch * 8];
  }
  __syncthreads();

  u16* pw0 = plds + wid * 16 * KS;
  f32x4 zero4 = {0.f, 0.f, 0.f, 0.f};

  #pragma unroll 1
  for (int tq = 0; tq < 4; ++tq) {
    int tIdx = (bid % BPW) * 16 + wid * 4 + tq;
    int j = tIdx * 16 + c;
    int ih = j / HWIN, iw = j % HWIN;
    int t = (wy * HWIN + ih) * W_ + wx * HWIN + iw;
    bf16x8 qa = *(const bf16x8*)&q[((size_t)n * HW_ + t) * 128 + head * 32 + g * 8];

    f32x4 sacc[NCT];
    #pragma unroll
    for (int ct = 0; ct < NCT; ++ct) {
      bf16x8 kf = *(const bf16x8*)&klds[(ct * 16 + c) * KS + g * 8];
      sacc[ct] = MFMA(qa, kf, zero4);
    }
    #pragma unroll
    for (int reg = 0; reg < 4; ++reg) {
      float mx = -1e30f;
      #pragma unroll
      for (int ct = 0; ct < NCT; ++ct) mx = fmaxf(mx, sacc[ct][reg]);
      mx = fmaxf(mx, __shfl_xor(mx, 1, 64));
      mx = fmaxf(mx, __shfl_xor(mx, 2, 64));
      mx = fmaxf(mx, __shfl_xor(mx, 4, 64));
      mx = fmaxf(mx, __shfl_xor(mx, 8, 64));
      float sm = 0.f;
      #pragma unroll
      for (int ct = 0; ct < NCT; ++ct) {
        float e = __expf((sacc[ct][reg] - mx) * SCALE_);
        sacc[ct][reg] = e;
        sm += e;
      }
      sm += __shfl_xor(sm, 1, 64);
      sm += __shfl_xor(sm, 2, 64);
      sm += __shfl_xor(sm, 4, 64);
      sm += __shfl_xor(sm, 8, 64);
      float inv = 1.0f / sm;
      #pragma unroll
      for (int ct = 0; ct < NCT; ++ct) sacc[ct][reg] *= inv;
    }
    f32x4 oacc[2] = {};
    #pragma unroll
    for (int st = 0; st < NST; ++st) {
      #pragma unroll
      for (int ct2 = 0; ct2 < 2; ++ct2) {
        int ct = st * 2 + ct2;
        #pragma unroll
        for (int reg = 0; reg < 4; ++reg)
          pw0[(g * 4 + reg) * KS + ct2 * 16 + c] = f2bf_rne(sacc[ct][reg]);
      }
      bf16x8 pa = *(const bf16x8*)&pw0[c * KS + g * 8];
      #pragma unroll
      for (int dt = 0; dt < 2; ++dt) {
        bf16x8 vf = *(const bf16x8*)&vlds[(dt * 16 + c) * VS + st * 32 + g * 8];
        oacc[dt] = MFMA(pa, vf, oacc[dt]);
      }
    }
    #pragma unroll
    for (int reg = 0; reg < 4; ++reg) {
      int jo = tIdx * 16 + g * 4 + reg;
      int iho = jo / HWIN, iwo = jo % HWIN;
      int to = (wy * HWIN + iho) * W_ + wx * HWIN + iwo;
      u16* op = cbuf16 + ((size_t)n * HW_ + to) * 128 + head * 32;
      op[c]      = f2bf_rne(oacc[0][reg]);
      op[16 + c] = f2bf_rne(oacc[1][reg]);
    }
  }
}

__global__ __launch_bounds__(256) void attn01_kernel(
    const u16* __restrict__ q, const u16* __restrict__ kb,
    const u16* __restrict__ vbT, u16* __restrict__ cbuf16) {
  int bid = blockIdx.x;
  if (bid < 256) attn_v2_body<1, 256>(bid,       0, 0,    q, kb, vbT, cbuf16);
  else           attn_v2_body<2, 256>(bid - 256, 1, 1024, q, kb, vbT, cbuf16);
}

__global__ __launch_bounds__(256) void attn23_kernel(
    const u16* __restrict__ q, const u16* __restrict__ kb,
    const u16* __restrict__ vbT, u16* __restrict__ cbuf16) {
  int bid = blockIdx.x;
  if (bid < 256) attn_v2_body<4, 64>(bid,       2, 5120, q, kb, vbT, cbuf16);
  else           attn_v2_body<8, 64>(bid - 256, 3, 9216, q, kb, vbT, cbuf16);
}

// ---------------------------------------------------------------------------
// final projection: bf16 input [t][128] contiguous -> direct A-frag loads,
// no LDS, no syncs. fp32 out + bias.
// ---------------------------------------------------------------------------
__global__ __launch_bounds__(256) void proj_mfma_kernel(
    const u16* __restrict__ x16, const u16* __restrict__ wh,
    const u16* __restrict__ wl, const float* __restrict__ b,
    float* __restrict__ out) {
  int tid = threadIdx.x;
  int r0 = blockIdx.x * 64;
  int wid = tid >> 6, lane = tid & 63, r = lane & 15, g = lane >> 4;
  const u16* xr = x16 + (size_t)(r0 + wid * 16 + r) * 128 + g * 8;
  bf16x8 af[4];
  #pragma unroll
  for (int kk = 0; kk < 4; ++kk)
    af[kk] = *(const bf16x8*)&xr[kk * 32];
  f32x4 acc[8] = {};
  #pragma unroll
  for (int kk = 0; kk < 4; ++kk) {
    #pragma unroll
    for (int ct = 0; ct < 8; ++ct) {
      int o = ct * 16 + r;
      bf16x8 bh = *(const bf16x8*)&wh[o * 128 + kk * 32 + g * 8];
      bf16x8 bl = *(const bf16x8*)&wl[o * 128 + kk * 32 + g * 8];
      acc[ct] = MFMA(af[kk], bh, acc[ct]);
      acc[ct] = MFMA(af[kk], bl, acc[ct]);
    }
  }
  #pragma unroll
  for (int ct = 0; ct < 8; ++ct) {
    int col = ct * 16 + r;
    #pragma unroll
    for (int reg = 0; reg < 4; ++reg) {
      int row = r0 + wid * 16 + g * 4 + reg;
      out[(size_t)row * 128 + col] = acc[ct][reg] + b[col];
    }
  }
}

// ---------------------------------------------------------------------------
extern "C" void kernel_launch(void* const* d_in, const int* in_sizes, int n_in,
                              void* d_out, int out_size, void* d_ws, size_t ws_size,
                              hipStream_t stream) {
  const float* inp = (const float*)d_in[0];
  const float* nw  = (const float*)d_in[1];
  const float* nb  = (const float*)d_in[2];
  const float* qw  = (const float*)d_in[3];
  const float* qb  = (const float*)d_in[4];
  const float* pw  = (const float*)d_in[29];
  const float* pb  = (const float*)d_in[30];

  float* ws   = (float*)d_ws;
  u16*   qb16 = (u16*)(ws + QB_OFF);
  float* y    = ws + Y_OFF;
  u16*   kb   = (u16*)(ws + KB_OFF);
  u16*   vbT  = (u16*)(ws + VT_OFF);
  float* part = ws + PART_OFF;
  u16*   cbuf16 = (u16*)part;                 // aliases part (dead after reduce)
  u16*   wsp  = (u16*)(ws + WSP_OFF);
  u16*   whi  = wsp;
  u16*   wlo  = wsp + TOTW;
  u16*   inph = (u16*)(ws + INH_OFF);
  float* scb  = ws + SCB_OFF;

  // 0) prep: input -> bf16, weights -> bf16 hi/lo (qw pre-scaled by nw), S/cb
  prep_kernel<<<8192 + TOTW / 256 + 1, 256, 0, stream>>>(
      inp, qw, pw, (const float*)d_in[5], (const float*)d_in[11],
      (const float*)d_in[17], (const float*)d_in[23],
      (const float*)d_in[9], (const float*)d_in[15],
      (const float*)d_in[21], (const float*)d_in[27],
      nw, nb, qb, whi, wlo, inph, scb);

  // 1) merged convs (KSEG=512, head4 direct) + LN-folded Q projection
  convlnq_kernel<<<1536, 256, 0, stream>>>(inph, whi, wlo,
                                           (const float*)d_in[24], scb,
                                           part, y, qb16);

  // 2) reduce K-split partials + bias -> y (heads 1-3)
  reduce_kernel<<<2304, 256, 0, stream>>>(part, (const float*)d_in[6],
                                          (const float*)d_in[12],
                                          (const float*)d_in[18], y);

  // 3) fused LN + GELU + KV projection (MFMA)
  LnkvArgs la;
  la.lnw[0] = (const float*)d_in[7];  la.lnb[0] = (const float*)d_in[8];
  la.kvb[0] = (const float*)d_in[10];
  la.lnw[1] = (const float*)d_in[13]; la.lnb[1] = (const float*)d_in[14];
  la.kvb[1] = (const float*)d_in[16];
  la.lnw[2] = (const float*)d_in[19]; la.lnb[2] = (const float*)d_in[20];
  la.kvb[2] = (const float*)d_in[22];
  la.lnw[3] = (const float*)d_in[25]; la.lnb[3] = (const float*)d_in[26];
  la.kvb[3] = (const float*)d_in[28];
  lnkv_mfma_kernel<<<400, 256, 0, stream>>>(y, whi + OKV, wlo + OKV, la, kb, vbT);

  // 4) MFMA attention -> bf16 cbuf16 (part region)
  attn01_kernel<<<512, 256, 42496, stream>>>(qb16, kb, vbT, cbuf16);
  attn23_kernel<<<512, 256, 14848, stream>>>(qb16, kb, vbT, cbuf16);

  // 5) final projection: bf16 in (direct frag loads), fp32 out to d_out
  proj_mfma_kernel<<<1024, 256, 0, stream>>>(cbuf16, whi + OPW, wlo + OPW, pb,
                                             (float*)d_out);
}